// Round 13
// baseline (370.777 us; speedup 1.0000x reference)
//
#include <hip/hip_runtime.h>
#include <hip/hip_bf16.h>
#include <math.h>

typedef unsigned short u16;
typedef __attribute__((ext_vector_type(8))) short bf16x8;
typedef __attribute__((ext_vector_type(4))) float f32x4;

// Problem constants (match reference)
constexpr int kF    = 32;    // nr_atom_basis
constexpr int kH    = 7;     // heads
constexpr int kC    = 224;   // F*H
constexpr int kRBF  = 50;
constexpr int kM    = 128;   // edges per xmix tile
constexpr int kStr  = 232;   // xmix LDS row stride (bf16; 464B, 16B-aligned)
constexpr int kEM   = 128;   // edges per edge-MFMA block
constexpr int kAStr = 136;   // edge A-tile stride (bf16; 272B, 16B-aligned)
constexpr int kBStr = 40;    // t1 tile stride (bf16; 80B, 16B-aligned)
constexpr float kCut = 5.0f;
constexpr float kEps = 1e-8f;

__device__ __forceinline__ float silu_f(float a) { return a / (1.f + __expf(-a)); }
__device__ __forceinline__ float tanh_f(float x) {
    float e = __expf(2.f * x);
    return 1.f - 2.f / (e + 1.f);
}
__device__ __forceinline__ float bf2f(u16 u) {
    union { unsigned int i; float f; } v; v.i = ((unsigned int)u) << 16; return v.f;
}
__device__ __forceinline__ u16 f2bf(float f) {
    union { float f; unsigned int i; } v; v.f = f;
    unsigned int x = v.i;
    unsigned int round = ((x >> 16) & 1u) + 0x7fffu;
    return (u16)((x + round) >> 16);
}
__device__ __forceinline__ unsigned pk2(float a, float b) {
    union { __hip_bfloat162 h; unsigned u; } v;
    v.h = __float22bfloat162_rn(make_float2(a, b));
    return v.u;
}

// ---------------------------------------------------------------------------
// K0: build wxT + edge-MLP B-matrices; histogram of idx_i (counts pre-zeroed
// by hipMemsetAsync before this kernel).
// ---------------------------------------------------------------------------
__global__ __launch_bounds__(256) void init_kernel(
    const float* __restrict__ wx, const float* __restrict__ w_in,
    const float* __restrict__ w_e1, const float* __restrict__ w_e2,
    const float* __restrict__ w_att, const float* __restrict__ b_e2,
    const float* __restrict__ b_att, const int* __restrict__ pl,
    u16* __restrict__ wxT, u16* __restrict__ W1T, u16* __restrict__ W2T,
    u16* __restrict__ W3T, u16* __restrict__ W24T, float* __restrict__ b24,
    int* __restrict__ counts, int E_)
{
    int idx = blockIdx.x * 256 + threadIdx.x;
    if (idx < kC * kC) {
        int c = idx / kC, k = idx - c * kC;      // wxT[c][k] = wx[k][c]
        wxT[idx] = f2bf(wx[k * kC + c]);
    }
    // histogram (grid-stride)
    for (int e = idx; e < E_; e += gridDim.x * 256) atomicAdd(&counts[pl[e]], 1);

    if (blockIdx.x == 0) {
        int t = threadIdx.x;
        for (int i = t; i < 64 * 64; i += 256) {
            int n = i >> 6, k = i & 63;
            W1T[i] = f2bf((n < kRBF) ? w_in[k * kRBF + n] : 0.f);
        }
        for (int i = t; i < 32 * 128; i += 256) {
            int n = i >> 7, k = i & 127;
            W2T[i] = f2bf((k < 115) ? w_e1[k * kF + n] : 0.f);
        }
        for (int i = t; i < 32 * 32; i += 256) {
            int n = i >> 5, k = i & 31;
            W3T[i] = f2bf(w_e2[k * kF + n]);
        }
        for (int i = t; i < 16 * 32; i += 256) {
            int n = i >> 5, k = i & 31;
            float a = 0.f;
            if (n < kH) for (int o = 0; o < kF; o++) a += w_e2[k * kF + o] * w_att[o * kH + n];
            W24T[i] = f2bf(a);
        }
        if (t < kH) {
            float a = b_att[t];
            for (int o = 0; o < kF; o++) a += b_e2[o] * w_att[o * kH + t];
            b24[t] = a;
        }
    }
}

// ---------------------------------------------------------------------------
// K2: exclusive scan, barrier-light
// ---------------------------------------------------------------------------
__global__ __launch_bounds__(1024) void scan_kernel(
    const int* __restrict__ counts, int* __restrict__ offsets, int n)
{
    __shared__ int buf[1024];
    int t = threadIdx.x;
    int chunk = (n + 1023) >> 10;
    int lo = t * chunk;
    int s = 0;
    for (int i = 0; i < chunk; i++) {
        int g = lo + i;
        if (g < n) s += counts[g];
    }
    buf[t] = s;
    __syncthreads();
    for (int off = 1; off < 1024; off <<= 1) {
        int v = (t >= off) ? buf[t - off] : 0;
        __syncthreads();
        buf[t] += v;
        __syncthreads();
    }
    int run = buf[t] - s;
    for (int i = 0; i < chunk; i++) {
        int g = lo + i;
        if (g < n) { offsets[g] = run; run += counts[g]; }
    }
    if (t == 1023) offsets[n] = buf[1023];
}

// ---------------------------------------------------------------------------
// K3: scatter -> rank (inverse permutation) + nid (node id per CSR position)
// ---------------------------------------------------------------------------
__global__ __launch_bounds__(256) void scatter_kernel(
    const int* __restrict__ pl, const int* __restrict__ offsets,
    int* __restrict__ cursor, int* __restrict__ rank, int* __restrict__ nid, int E_)
{
    int e = blockIdx.x * 256 + threadIdx.x;
    if (e < E_) {
        int i = pl[e];
        int p = atomicAdd(&cursor[i], 1);
        int pos = offsets[i] + p;
        rank[e] = pos;
        nid[pos] = i;
    }
}

// ---------------------------------------------------------------------------
// K4: MFMA edge kernel. Writes he/logit/dir at CSR position rank[e].
// ---------------------------------------------------------------------------
__global__ __launch_bounds__(256) void edge_kernel(
    const float* __restrict__ h, const float* __restrict__ x,
    const int* __restrict__ pl, const int* __restrict__ rank_g, int E_,
    const float* __restrict__ b_in, const float* __restrict__ b_e1,
    const float* __restrict__ b_e2,
    const u16* __restrict__ W1T, const u16* __restrict__ W2T,
    const u16* __restrict__ W3T, const u16* __restrict__ W24T,
    const float* __restrict__ b24,
    float* __restrict__ he_g, float* __restrict__ logit_g,
    float* __restrict__ dir_g)
{
    __shared__ __align__(16) u16 s_A[kEM][kAStr];
    __shared__ __align__(16) u16 s_t1[kEM][kBStr];
    __shared__ float s_d[kEM];
    __shared__ int   s_r[kEM];

    int t = threadIdx.x;
    int T0 = blockIdx.x * kEM;
    int w = t >> 6, lane = t & 63, quad = lane >> 4, l15 = lane & 15;

    {
        int e = t >> 1, half = t & 1;
        int ge = T0 + e;
        bool val = ge < E_;
        int i = 0, j = 0;
        if (val) { i = pl[ge]; j = pl[E_ + ge]; }
        const float4* pi = (const float4*)(h + (size_t)i * kF) + half * 4;
        const float4* pj = (const float4*)(h + (size_t)j * kF) + half * 4;
#pragma unroll
        for (int q = 0; q < 4; q++) {
            float4 a = val ? pi[q] : make_float4(0.f, 0.f, 0.f, 0.f);
            float4 b = val ? pj[q] : make_float4(0.f, 0.f, 0.f, 0.f);
            unsigned* di = (unsigned*)&s_A[e][half * 16 + 4 * q];
            di[0] = pk2(a.x, a.y); di[1] = pk2(a.z, a.w);
            unsigned* dj = (unsigned*)&s_A[e][kF + half * 16 + 4 * q];
            dj[0] = pk2(b.x, b.y); dj[1] = pk2(b.z, b.w);
        }
        if (half == 0) {
            float d = 0.f;
            int r = 0;
            if (val) {
                r = rank_g[ge];
                float r0 = x[j * 3 + 0] - x[i * 3 + 0];
                float r1 = x[j * 3 + 1] - x[i * 3 + 1];
                float r2 = x[j * 3 + 2] - x[i * 3 + 2];
                d = sqrtf(r0 * r0 + r1 * r1 + r2 * r2);
                float inv = 1.0f / (d + kEps);
                dir_g[(size_t)r * 3 + 0] = r0 * inv;
                dir_g[(size_t)r * 3 + 1] = r1 * inv;
                dir_g[(size_t)r * 3 + 2] = r2 * inv;
            }
            s_r[e] = r;
            s_d[e] = d;
            s_A[e][114] = f2bf(d);
            s_A[e][115] = 0;
            unsigned* z = (unsigned*)&s_A[e][116];
#pragma unroll
            for (int q = 0; q < 6; q++) z[q] = 0u;
        }
    }
    __syncthreads();

    const float invw = 49.0f / kCut;

    {   // GEMM1: h_cat @ w_in -> rbf -> filt
        bf16x8 a1[2][2];
#pragma unroll
        for (int rt = 0; rt < 2; rt++)
#pragma unroll
            for (int kt = 0; kt < 2; kt++)
                a1[rt][kt] = *(const bf16x8*)&s_A[32 * w + 16 * rt + l15][kt * 32 + quad * 8];
#pragma unroll
        for (int ct = 0; ct < 4; ct++) {
            int c = ct * 16 + l15;
            bf16x8 b0 = *(const bf16x8*)(W1T + (size_t)c * 64 + quad * 8);
            bf16x8 b1 = *(const bf16x8*)(W1T + (size_t)c * 64 + 32 + quad * 8);
            float bin = (c < kRBF) ? b_in[c] : 0.f;
#pragma unroll
            for (int rt = 0; rt < 2; rt++) {
                f32x4 acc = {0.f, 0.f, 0.f, 0.f};
                acc = __builtin_amdgcn_mfma_f32_16x16x32_bf16(a1[rt][0], b0, acc, 0, 0, 0);
                acc = __builtin_amdgcn_mfma_f32_16x16x32_bf16(a1[rt][1], b1, acc, 0, 0, 0);
                if (c < kRBF) {
#pragma unroll
                    for (int r = 0; r < 4; r++) {
                        int row = 32 * w + 16 * rt + quad * 4 + r;
                        float arg = s_d[row] * invw - (float)c;
                        float filt = __expf(-0.5f * arg * arg) * (acc[r] + bin);
                        s_A[row][64 + c] = f2bf(filt);
                    }
                }
            }
        }
    }

    {   // GEMM2: edge_in @ w_e1 -> silu -> t1
        bf16x8 a2[2][4];
#pragma unroll
        for (int rt = 0; rt < 2; rt++)
#pragma unroll
            for (int kt = 0; kt < 4; kt++)
                a2[rt][kt] = *(const bf16x8*)&s_A[32 * w + 16 * rt + l15][kt * 32 + quad * 8];
#pragma unroll
        for (int ct = 0; ct < 2; ct++) {
            int c = ct * 16 + l15;
            bf16x8 bb[4];
#pragma unroll
            for (int kt = 0; kt < 4; kt++)
                bb[kt] = *(const bf16x8*)(W2T + (size_t)c * 128 + kt * 32 + quad * 8);
            float be = b_e1[c];
#pragma unroll
            for (int rt = 0; rt < 2; rt++) {
                f32x4 acc = {0.f, 0.f, 0.f, 0.f};
#pragma unroll
                for (int kt = 0; kt < 4; kt++)
                    acc = __builtin_amdgcn_mfma_f32_16x16x32_bf16(a2[rt][kt], bb[kt], acc, 0, 0, 0);
#pragma unroll
                for (int r = 0; r < 4; r++) {
                    int row = 32 * w + 16 * rt + quad * 4 + r;
                    s_t1[row][c] = f2bf(silu_f(acc[r] + be));
                }
            }
        }
    }

    {   // GEMM3 (he) + GEMM4 (logits)
        bf16x8 a3[2];
#pragma unroll
        for (int rt = 0; rt < 2; rt++)
            a3[rt] = *(const bf16x8*)&s_t1[32 * w + 16 * rt + l15][quad * 8];

#pragma unroll
        for (int ct = 0; ct < 2; ct++) {
            int c = ct * 16 + l15;
            bf16x8 b3 = *(const bf16x8*)(W3T + (size_t)c * 32 + quad * 8);
            float be = b_e2[c];
#pragma unroll
            for (int rt = 0; rt < 2; rt++) {
                f32x4 acc = {0.f, 0.f, 0.f, 0.f};
                acc = __builtin_amdgcn_mfma_f32_16x16x32_bf16(a3[rt], b3, acc, 0, 0, 0);
#pragma unroll
                for (int r = 0; r < 4; r++) {
                    int row = 32 * w + 16 * rt + quad * 4 + r;
                    int ge = T0 + row;
                    if (ge < E_) he_g[(size_t)s_r[row] * kF + c] = acc[r] + be;
                }
            }
        }
        {
            bf16x8 b4 = *(const bf16x8*)(W24T + (size_t)l15 * 32 + quad * 8);
            float bb = (l15 < kH) ? b24[l15] : 0.f;
#pragma unroll
            for (int rt = 0; rt < 2; rt++) {
                f32x4 acc = {0.f, 0.f, 0.f, 0.f};
                acc = __builtin_amdgcn_mfma_f32_16x16x32_bf16(a3[rt], b4, acc, 0, 0, 0);
                if (l15 < kH) {
#pragma unroll
                    for (int r = 0; r < 4; r++) {
                        int row = 32 * w + 16 * rt + quad * 4 + r;
                        int ge = T0 + row;
                        if (ge < E_) {
                            float a = acc[r] + bb;
                            a = (a >= 0.f) ? a : 2.f * (__expf(0.5f * a) - 1.f);
                            float dd = s_d[row];
                            float cut = (dd < kCut)
                                ? 0.5f * (__cosf(0.62831853071795864f * dd) + 1.f) : 0.f;
                            logit_g[(size_t)s_r[row] * kH + l15] = a * cut;
                        }
                    }
                }
            }
        }
    }
}

// ---------------------------------------------------------------------------
// K5: per-node softmax stats (wave per node, contiguous CSR logit reads)
// ---------------------------------------------------------------------------
__global__ __launch_bounds__(256) void stats_kernel(
    const float* __restrict__ logit_g, const int* __restrict__ offsets,
    float* __restrict__ m_g, float* __restrict__ invs_g, int N_)
{
    int wave = threadIdx.x >> 6;
    int lane = threadIdx.x & 63;
    int node = blockIdx.x * 4 + wave;
    if (node >= N_) return;
    int base = offsets[node];
    int deg  = offsets[node + 1] - base;

    float m[kH], ss[kH];
#pragma unroll
    for (int hh = 0; hh < kH; hh++) { m[hh] = -1e30f; ss[hh] = 0.f; }
    for (int e = lane; e < deg; e += 64) {
        const float* lp = logit_g + (size_t)(base + e) * kH;
#pragma unroll
        for (int hh = 0; hh < kH; hh++) {
            float vv = lp[hh];
            if (vv > m[hh]) { ss[hh] *= __expf(m[hh] - vv); m[hh] = vv; }
            ss[hh] += __expf(vv - m[hh]);
        }
    }
#pragma unroll
    for (int hh = 0; hh < kH; hh++) {
        float mm = m[hh], s2 = ss[hh];
#pragma unroll
        for (int off = 32; off >= 1; off >>= 1) {
            float mo = __shfl_xor(mm, off);
            float so = __shfl_xor(s2, off);
            float mn = fmaxf(mm, mo);
            s2 = s2 * __expf(mm - mn) + so * __expf(mo - mn);
            mm = mn;
        }
        if (lane == 0) {
            m_g[(size_t)node * kH + hh] = mm;
            invs_g[(size_t)node * kH + hh] = (s2 > 0.f) ? 1.f / s2 : 0.f;
        }
    }
}

// ---------------------------------------------------------------------------
// K6: MFMA xmix, 512 threads: 8 waves x 16-row MFMA tiles; waves 0-3 run the
// four 32-edge-window walks (bpart/bid layout identical to r12).
// ---------------------------------------------------------------------------
__global__ __launch_bounds__(512, 4) void xmix_kernel(
    const float* __restrict__ he_g, const float* __restrict__ logit_g,
    const float* __restrict__ dir_g, const int* __restrict__ nid,
    const float* __restrict__ m_g, const float* __restrict__ invs_g,
    const u16* __restrict__ wxT, int E_,
    float* __restrict__ nodeacc, float* __restrict__ bpart, int* __restrict__ bid)
{
    __shared__ __align__(16) u16 s_buf[kM][kStr];   // sem, then T
    __shared__ float s_att[kM][kH];
    __shared__ __align__(16) float s_dir4[kM][4];
    __shared__ int   s_node[kM];
    __shared__ int   s_prev, s_next;

    int t = threadIdx.x;
    int T0 = blockIdx.x * kM;
    int cp = min(kM, E_ - T0);

    if (t < kM) s_node[t] = (T0 + t < E_) ? nid[T0 + t] : -1;
    if (t == 0) {
        s_prev = (T0 > 0) ? nid[T0 - 1] : -2;
        s_next = (T0 + cp < E_) ? nid[T0 + cp] : -2;
    }
    __syncthreads();

    int w    = t >> 6;     // 0..7
    int lane = t & 63;
    int quad = lane >> 4;
    int l15  = lane & 15;

    // ---- walk windows: waves 0-3 own 32-edge windows ----
    int ws = 32 * w;
    int we = min(ws + 32, cp);
    bool winvalid = (w < 4) && (ws < cp);
    bool contL = false, contR = false;
    if (winvalid) {
        int nfirst = s_node[ws], nlast = s_node[we - 1];
        contL = (w == 0) ? (s_prev == nfirst) : (s_node[ws - 1] == nfirst);
        contR = (we == cp) ? (s_next == nlast) : (s_node[we] == nlast);
    }
    if (w < 4 && lane == 0) {
        int b0 = -1, b1 = -1;
        if (winvalid) {
            int nfirst = s_node[ws], nlast = s_node[we - 1];
            b0 = contL ? nfirst : -1;
            if (contR && !(nfirst == nlast && contL)) b1 = nlast;
        }
        bid[8 * blockIdx.x + 2 * w + 0] = b0;
        bid[8 * blockIdx.x + 2 * w + 1] = b1;
    }
    bool active_w = winvalid && (lane < 56);
    int c0 = 4 * lane;

    for (int idx = t; idx < kM * kH; idx += 512) {
        int e = idx / kH, hh = idx - e * kH;
        float a = 0.f;
        if (T0 + e < E_) {
            int nd = s_node[e];
            a = __expf(logit_g[(size_t)(T0 + e) * kH + hh] - m_g[(size_t)nd * kH + hh])
                * invs_g[(size_t)nd * kH + hh];
        }
        s_att[e][hh] = a;
    }
    for (int idx = t; idx < cp * 3; idx += 512) {
        int e = idx / 3, xx = idx - e * 3;
        s_dir4[e][xx] = dir_g[(size_t)(T0 + e) * 3 + xx];
    }
    __syncthreads();

    // sem build (bf16, hw pack); he reads fully coalesced
#pragma unroll
    for (int p = 0; p < kM * kF / 512; p++) {   // 8 iters
        int idx = t + 512 * p;
        int e = idx >> 5, f = idx & 31;
        float hv = (T0 + e < E_) ? he_g[(size_t)(T0 + e) * kF + f] : 0.f;
        float sv[7];
#pragma unroll
        for (int hh = 0; hh < kH; hh++) sv[hh] = hv * s_att[e][hh];
        u16* dst = &s_buf[e][f * 7];
        if ((f & 1) == 0) {
            *(unsigned*)(dst)     = pk2(sv[0], sv[1]);
            *(unsigned*)(dst + 2) = pk2(sv[2], sv[3]);
            *(unsigned*)(dst + 4) = pk2(sv[4], sv[5]);
            dst[6] = f2bf(sv[6]);
        } else {
            dst[0] = f2bf(sv[0]);
            *(unsigned*)(dst + 1) = pk2(sv[1], sv[2]);
            *(unsigned*)(dst + 3) = pk2(sv[3], sv[4]);
            *(unsigned*)(dst + 5) = pk2(sv[5], sv[6]);
        }
    }
    __syncthreads();

    // hisem walk (waves 0-3; b64 column reads, float4 flush)
    if (active_w) {
        float hs0 = 0.f, hs1 = 0.f, hs2 = 0.f, hs3 = 0.f;
        int rs = ws;
        for (int e = ws; e < we; e++) {
            if (s_node[e] != s_node[rs]) {
                bool comp = (rs > ws) || !contL;
                float4 vv = make_float4(hs0, hs1, hs2, hs3);
                if (comp) *(float4*)&nodeacc[(size_t)s_node[rs] * 896 + 672 + c0] = vv;
                else *(float4*)&bpart[(size_t)(8 * blockIdx.x + 2 * w) * 896 + 672 + c0] = vv;
                hs0 = hs1 = hs2 = hs3 = 0.f; rs = e;
            }
            uint2 pv = *(const uint2*)&s_buf[e][c0];
            hs0 += bf2f((u16)pv.x); hs1 += bf2f((u16)(pv.x >> 16));
            hs2 += bf2f((u16)pv.y); hs3 += bf2f((u16)(pv.y >> 16));
        }
        bool t0 = (rs == ws);
        bool comp = ((!t0) || !contL) && !contR;
        float4 vv = make_float4(hs0, hs1, hs2, hs3);
        if (comp) *(float4*)&nodeacc[(size_t)s_node[rs] * 896 + 672 + c0] = vv;
        else {
            int slot = (t0 && contL) ? 0 : 1;
            *(float4*)&bpart[(size_t)(8 * blockIdx.x + 2 * w + slot) * 896 + 672 + c0] = vv;
        }
    }

    // MFMA fragments: wave w owns rows [16w, 16w+16)
    bf16x8 afr[7];
#pragma unroll
    for (int kt = 0; kt < 7; kt++)
        afr[kt] = *(const bf16x8*)&s_buf[16 * w + l15][kt * 32 + quad * 8];

    bf16x8 bA[7], bB[7];
    {
        const u16* bp = wxT + (size_t)l15 * kC + quad * 8;
#pragma unroll
        for (int kt = 0; kt < 7; kt++) bA[kt] = *(const bf16x8*)(bp + kt * 32);
    }
    __syncthreads();   // hisem walk + A-loads done before T write-back

    for (int ct = 0; ct < 14; ct++) {
        bf16x8* cur = (ct & 1) ? bB : bA;
        bf16x8* nxt = (ct & 1) ? bA : bB;
        if (ct < 13) {
            const u16* bp = wxT + (size_t)((ct + 1) * 16 + l15) * kC + quad * 8;
#pragma unroll
            for (int kt = 0; kt < 7; kt++) nxt[kt] = *(const bf16x8*)(bp + kt * 32);
        }
        f32x4 acc = {0.f, 0.f, 0.f, 0.f};
#pragma unroll
        for (int kt = 0; kt < 7; kt++)
            acc = __builtin_amdgcn_mfma_f32_16x16x32_bf16(afr[kt], cur[kt], acc, 0, 0, 0);
        int colg = ct * 16 + l15;
        int rbase = 16 * w + quad * 4;
        unsigned p01 = pk2(tanh_f(acc[0]), tanh_f(acc[1]));
        unsigned p23 = pk2(tanh_f(acc[2]), tanh_f(acc[3]));
        s_buf[rbase + 0][colg] = (u16)p01;
        s_buf[rbase + 1][colg] = (u16)(p01 >> 16);
        s_buf[rbase + 2][colg] = (u16)p23;
        s_buf[rbase + 3][colg] = (u16)(p23 >> 16);
    }
    __syncthreads();

    // comb walk (waves 0-3; b64 T reads, broadcast dir b128, float4 flushes)
    if (active_w) {
        float a0[4] = {0.f, 0.f, 0.f, 0.f};
        float a1[4] = {0.f, 0.f, 0.f, 0.f};
        float a2[4] = {0.f, 0.f, 0.f, 0.f};
        int rs = ws;
        for (int e = ws; e < we; e++) {
            if (s_node[e] != s_node[rs]) {
                bool comp = (rs > ws) || !contL;
                float* p = comp ? (nodeacc + (size_t)s_node[rs] * 896)
                                : (bpart + (size_t)(8 * blockIdx.x + 2 * w) * 896);
                *(float4*)&p[c0]       = make_float4(a0[0], a0[1], a0[2], a0[3]);
                *(float4*)&p[224 + c0] = make_float4(a1[0], a1[1], a1[2], a1[3]);
                *(float4*)&p[448 + c0] = make_float4(a2[0], a2[1], a2[2], a2[3]);
#pragma unroll
                for (int q = 0; q < 4; q++) { a0[q] = 0.f; a1[q] = 0.f; a2[q] = 0.f; }
                rs = e;
            }
            float4 dd = *(const float4*)&s_dir4[e][0];
            uint2 pv = *(const uint2*)&s_buf[e][c0];
            float Tv[4];
            Tv[0] = bf2f((u16)pv.x); Tv[1] = bf2f((u16)(pv.x >> 16));
            Tv[2] = bf2f((u16)pv.y); Tv[3] = bf2f((u16)(pv.y >> 16));
#pragma unroll
            for (int q = 0; q < 4; q++) {
                a0[q] += Tv[q] * dd.x;
                a1[q] += Tv[q] * dd.y;
                a2[q] += Tv[q] * dd.z;
            }
        }
        bool t0 = (rs == ws);
        bool comp = ((!t0) || !contL) && !contR;
        float* p;
        if (comp) p = nodeacc + (size_t)s_node[rs] * 896;
        else {
            int slot = (t0 && contL) ? 0 : 1;
            p = bpart + (size_t)(8 * blockIdx.x + 2 * w + slot) * 896;
        }
        *(float4*)&p[c0]       = make_float4(a0[0], a0[1], a0[2], a0[3]);
        *(float4*)&p[224 + c0] = make_float4(a1[0], a1[1], a1[2], a1[3]);
        *(float4*)&p[448 + c0] = make_float4(a2[0], a2[1], a2[2], a2[3]);
    }
}

// ---------------------------------------------------------------------------
// K7: node epilogue. 4 nodes/block; gather nodeacc/bpart (32-edge windows);
// MLPs with weight-value reuse across the 4 nodes.
// ---------------------------------------------------------------------------
__global__ __launch_bounds__(256) void node_kernel(
    const float* __restrict__ h, const float* __restrict__ x, const float* __restrict__ v,
    const float* __restrict__ nodeacc, const float* __restrict__ bpart,
    const int* __restrict__ bid, const int* __restrict__ offs,
    const float* __restrict__ w_n1, const float* __restrict__ b_n1,
    const float* __restrict__ w_n2, const float* __restrict__ b_n2,
    const float* __restrict__ w_pn1, const float* __restrict__ b_pn1,
    const float* __restrict__ w_pn2, const float* __restrict__ b_pn2,
    const float* __restrict__ w_v1, const float* __restrict__ b_v1,
    const float* __restrict__ w_v2, const float* __restrict__ w_vmix,
    float* __restrict__ out_h, float* __restrict__ out_x, float* __restrict__ out_v,
    int N_)
{
    __shared__ float s_cm[4][3][kC];
    __shared__ float s_cnsq[4][kC];
    __shared__ float s_ni[4][288];          // [h | hisem | spat]
    __shared__ float s_part[8][4][kF];
    __shared__ float s_hn[4][kF], s_sp1[4][kF], s_spat[4][kF], s_n1v[4][kF], s_g1[4][kF];
    __shared__ float s_pdv[4][3][8];
    __shared__ float s_gate[4], s_dv[4][3];

    int t = threadIdx.x;
    int n0 = blockIdx.x * 4;

    if (t < kC) {
        for (int nd = 0; nd < 4; nd++) {
            int node = n0 + nd;
            if (node >= N_) break;
            int base = offs[node], end = offs[node + 1];
            int deg = end - base;
            float a0 = 0.f, a1 = 0.f, a2 = 0.f, hh = 0.f;
            if (deg > 0) {
                int wlo = base >> 5, whi = (end - 1) >> 5;
                if (wlo == whi) {
                    const float* p = nodeacc + (size_t)node * 896;
                    a0 = p[t]; a1 = p[224 + t]; a2 = p[448 + t]; hh = p[672 + t];
                } else {
                    for (int W = wlo; W <= whi; W++) {
#pragma unroll
                        for (int s = 0; s < 2; s++) {
                            if (bid[2 * W + s] == node) {
                                const float* p = bpart + (size_t)(2 * W + s) * 896;
                                a0 += p[t]; a1 += p[224 + t]; a2 += p[448 + t]; hh += p[672 + t];
                            }
                        }
                    }
                }
            }
            float invc = 1.f / fmaxf((float)deg, 1.f);
            float m0 = a0 * invc, m1 = a1 * invc, m2 = a2 * invc;
            s_cm[nd][0][t] = m0; s_cm[nd][1][t] = m1; s_cm[nd][2][t] = m2;
            s_cnsq[nd][t] = m0 * m0 + m1 * m1 + m2 * m2;
            s_ni[nd][kF + t] = hh;
        }
    } else {
        int ln = t - 224;   // 0..31
        for (int nd = 0; nd < 4; nd++) {
            int node = n0 + nd;
            float hv = (node < N_) ? h[(size_t)node * kF + ln] : 0.f;
            s_hn[nd][ln] = hv;
            s_ni[nd][ln] = hv;
        }
    }
    __syncthreads();

    int o = t & 31, g = t >> 5;
    {   // pn1 partials, 4 nodes per weight load
        float acc[4] = {0.f, 0.f, 0.f, 0.f};
        int cb = g * 28;
        for (int i = 0; i < 28; i++) {
            float wv = w_pn1[(cb + i) * kF + o];
#pragma unroll
            for (int nd = 0; nd < 4; nd++) acc[nd] += s_cnsq[nd][cb + i] * wv;
        }
#pragma unroll
        for (int nd = 0; nd < 4; nd++) s_part[g][nd][o] = acc[nd];
    }
    __syncthreads();
    if (t < 128) {
        int nd = t >> 5;
        float a = b_pn1[o];
#pragma unroll
        for (int g2 = 0; g2 < 8; g2++) a += s_part[g2][nd][o];
        s_sp1[nd][o] = silu_f(a);
    } else {
        int nd = (t - 128) >> 5;
        float a = b_v1[o];
        for (int f = 0; f < kF; f++) a += s_hn[nd][f] * w_v1[f * kF + o];
        s_g1[nd][o] = silu_f(a);
    }
    __syncthreads();
    if (t < 128) {
        int nd = t >> 5;
        float a = b_pn2[o];
        for (int o2 = 0; o2 < kF; o2++) a += s_sp1[nd][o2] * w_pn2[o2 * kF + o];
        s_spat[nd][o] = silu_f(a);
    } else if (t < 132) {
        int nd = t - 128;
        float a = 0.f;
        for (int o2 = 0; o2 < kF; o2++) a += s_g1[nd][o2] * w_v2[o2];
        s_gate[nd] = 2.f / (1.f + __expf(-a));
    } else if (t >= 160) {   // 96 threads: dv partials
        int q = t - 160; int nd = q / 24; int r = q - nd * 24;
        int xx = r >> 3, ln = r & 7;
        float a = 0.f;
        for (int c = ln; c < kC; c += 8) a += w_vmix[c] * s_cm[nd][xx][c];
        s_pdv[nd][xx][ln] = a;
    }
    __syncthreads();
    if (t < 128) {
        int nd = t >> 5;
        s_ni[nd][kF + kC + o] = s_spat[nd][o];
    } else if (t < 140) {
        int q = t - 128; int nd = q / 3; int xx = q - nd * 3;
        float a = 0.f;
#pragma unroll
        for (int ln = 0; ln < 8; ln++) a += s_pdv[nd][xx][ln];
        s_dv[nd][xx] = a;
    }
    __syncthreads();
    {   // n1 partials: 8 groups x 36 rows
        float acc[4] = {0.f, 0.f, 0.f, 0.f};
        int rb = g * 36;
        for (int i = 0; i < 36; i++) {
            float wv = w_n1[(rb + i) * kF + o];
#pragma unroll
            for (int nd = 0; nd < 4; nd++) acc[nd] += s_ni[nd][rb + i] * wv;
        }
#pragma unroll
        for (int nd = 0; nd < 4; nd++) s_part[g][nd][o] = acc[nd];
    }
    __syncthreads();
    if (t < 128) {
        int nd = t >> 5;
        float a = b_n1[o];
#pragma unroll
        for (int g2 = 0; g2 < 8; g2++) a += s_part[g2][nd][o];
        s_n1v[nd][o] = silu_f(a);
    }
    __syncthreads();
    if (t < 128) {
        int nd = t >> 5; int node = n0 + nd;
        if (node < N_) {
            float a = b_n2[o];
            for (int o2 = 0; o2 < kF; o2++) a += s_n1v[nd][o2] * w_n2[o2 * kF + o];
            out_h[(size_t)node * kF + o] = s_hn[nd][o] + silu_f(a);
        }
    } else if (t < 140) {
        int q = t - 128; int nd = q / 3; int xx = q - nd * 3;
        int node = n0 + nd;
        if (node < N_) {
            float vv = v[(size_t)node * 3 + xx];
            float vu = s_gate[nd] * vv + s_dv[nd][xx];
            out_v[(size_t)node * 3 + xx] = vu;
            out_x[(size_t)node * 3 + xx] = x[(size_t)node * 3 + xx] + vu;
        }
    }
}

// ---------------------------------------------------------------------------
extern "C" void kernel_launch(void* const* d_in, const int* in_sizes, int n_in,
                              void* d_out, int out_size, void* d_ws, size_t ws_size,
                              hipStream_t stream)
{
    const float* h      = (const float*)d_in[0];
    const float* x      = (const float*)d_in[1];
    const float* v      = (const float*)d_in[2];
    const int*   pl     = (const int*)d_in[3];
    const float* w_in   = (const float*)d_in[4];
    const float* b_in   = (const float*)d_in[5];
    const float* w_e1   = (const float*)d_in[6];
    const float* b_e1   = (const float*)d_in[7];
    const float* w_e2   = (const float*)d_in[8];
    const float* b_e2   = (const float*)d_in[9];
    const float* w_att  = (const float*)d_in[10];
    const float* b_att  = (const float*)d_in[11];
    const float* w_n1   = (const float*)d_in[12];
    const float* b_n1   = (const float*)d_in[13];
    const float* w_n2   = (const float*)d_in[14];
    const float* b_n2   = (const float*)d_in[15];
    const float* w_pn1  = (const float*)d_in[16];
    const float* b_pn1  = (const float*)d_in[17];
    const float* w_pn2  = (const float*)d_in[18];
    const float* b_pn2  = (const float*)d_in[19];
    const float* w_v1   = (const float*)d_in[20];
    const float* b_v1   = (const float*)d_in[21];
    const float* w_v2   = (const float*)d_in[22];
    const float* w_xmix = (const float*)d_in[23];
    const float* w_vmix = (const float*)d_in[24];

    const int E_ = in_sizes[3] / 2;
    const int N_ = in_sizes[0] / kF;
    const int nblk = (E_ + kM - 1) / kM;

    // Workspace (~117 MB; 16B-aligned segments first)
    char* w = (char*)d_ws;
    u16*   wxT     = (u16*)w;   w += (size_t)kC * kC * 2;
    u16*   W1T     = (u16*)w;   w += (size_t)64 * 64 * 2;
    u16*   W2T     = (u16*)w;   w += (size_t)32 * 128 * 2;
    u16*   W3T     = (u16*)w;   w += (size_t)32 * 32 * 2;
    u16*   W24T    = (u16*)w;   w += (size_t)16 * 32 * 2;
    float* b24     = (float*)w; w += 8 * 4;
    float* he_g    = (float*)w; w += (size_t)E_ * kF * 4;
    float* logit_g = (float*)w; w += (size_t)E_ * kH * 4;
    float* dir_g   = (float*)w; w += (size_t)E_ * 3 * 4;
    float* m_g     = (float*)w; w += (size_t)N_ * kH * 4;
    float* invs_g  = (float*)w; w += (size_t)N_ * kH * 4;
    float* nodeacc = (float*)w; w += (size_t)N_ * 896 * 4;       // [N][4][224]
    float* bpart   = (float*)w; w += (size_t)8 * nblk * 896 * 4; // 4 win x 2 slots / blk
    int*   bid     = (int*)w;   w += (size_t)8 * nblk * 4;
    int* counts    = (int*)w;   w += (size_t)N_ * 4;
    int* offs      = (int*)w;   w += (size_t)(N_ + 1) * 4;
    int* cursor    = (int*)w;   w += (size_t)N_ * 4;
    int* rank_g    = (int*)w;   w += (size_t)E_ * 4;
    int* nid       = (int*)w;   w += (size_t)E_ * 4;

    float* out_h = (float*)d_out;
    float* out_x = out_h + (size_t)N_ * kF;
    float* out_v = out_x + (size_t)N_ * 3;

    // zero counts + cursor (adjacent after offs; two small memsets)
    hipMemsetAsync(counts, 0, (size_t)N_ * 4, stream);
    hipMemsetAsync(cursor, 0, (size_t)N_ * 4, stream);

    init_kernel<<<dim3((kC * kC + 255) / 256), dim3(256), 0, stream>>>(
        w_xmix, w_in, w_e1, w_e2, w_att, b_e2, b_att, pl,
        wxT, W1T, W2T, W3T, W24T, b24, counts, E_);

    scan_kernel<<<dim3(1), dim3(1024), 0, stream>>>(counts, offs, N_);

    scatter_kernel<<<dim3((E_ + 255) / 256), dim3(256), 0, stream>>>(
        pl, offs, cursor, rank_g, nid, E_);

    edge_kernel<<<dim3((E_ + kEM - 1) / kEM), dim3(256), 0, stream>>>(
        h, x, pl, rank_g, E_, b_in, b_e1, b_e2, W1T, W2T, W3T, W24T, b24,
        he_g, logit_g, dir_g);

    stats_kernel<<<dim3((N_ + 3) / 4), dim3(256), 0, stream>>>(
        logit_g, offs, m_g, invs_g, N_);

    xmix_kernel<<<dim3(nblk), dim3(512), 0, stream>>>(
        he_g, logit_g, dir_g, nid, m_g, invs_g, wxT, E_,
        nodeacc, bpart, bid);

    node_kernel<<<dim3((N_ + 3) / 4), dim3(256), 0, stream>>>(
        h, x, v, nodeacc, bpart, bid, offs,
        w_n1, b_n1, w_n2, b_n2, w_pn1, b_pn1, w_pn2, b_pn2,
        w_v1, b_v1, w_v2, w_vmix, out_h, out_x, out_v, N_);
}

// Round 14
// 348.441 us; speedup vs baseline: 1.0641x; 1.0641x over previous
//
#include <hip/hip_runtime.h>
#include <hip/hip_bf16.h>
#include <math.h>

typedef unsigned short u16;
typedef __attribute__((ext_vector_type(8))) short bf16x8;
typedef __attribute__((ext_vector_type(4))) float f32x4;

// Problem constants (match reference)
constexpr int kF    = 32;    // nr_atom_basis
constexpr int kH    = 7;     // heads
constexpr int kC    = 224;   // F*H
constexpr int kRBF  = 50;
constexpr int kM    = 128;   // edges per xmix tile
constexpr int kStr  = 232;   // xmix LDS row stride (bf16; 464B, 16B-aligned)
constexpr int kEM   = 128;   // edges per edge-MFMA block
constexpr int kAStr = 136;   // edge A-tile stride (bf16; 272B, 16B-aligned)
constexpr int kBStr = 40;    // t1 tile stride (bf16; 80B, 16B-aligned)
constexpr float kCut = 5.0f;
constexpr float kEps = 1e-8f;

__device__ __forceinline__ float silu_f(float a) { return a / (1.f + __expf(-a)); }
__device__ __forceinline__ float tanh_f(float x) {
    float e = __expf(2.f * x);
    return 1.f - 2.f / (e + 1.f);
}
__device__ __forceinline__ float bf2f(u16 u) {
    union { unsigned int i; float f; } v; v.i = ((unsigned int)u) << 16; return v.f;
}
__device__ __forceinline__ u16 f2bf(float f) {
    union { float f; unsigned int i; } v; v.f = f;
    unsigned int x = v.i;
    unsigned int round = ((x >> 16) & 1u) + 0x7fffu;
    return (u16)((x + round) >> 16);
}
__device__ __forceinline__ unsigned pk2(float a, float b) {
    union { __hip_bfloat162 h; unsigned u; } v;
    v.h = __float22bfloat162_rn(make_float2(a, b));
    return v.u;
}

// ---------------------------------------------------------------------------
// K0: build wxT + edge-MLP B-matrices; histogram of idx_i (counts pre-zeroed)
// ---------------------------------------------------------------------------
__global__ __launch_bounds__(256) void init_kernel(
    const float* __restrict__ wx, const float* __restrict__ w_in,
    const float* __restrict__ w_e1, const float* __restrict__ w_e2,
    const float* __restrict__ w_att, const float* __restrict__ b_e2,
    const float* __restrict__ b_att, const int* __restrict__ pl,
    u16* __restrict__ wxT, u16* __restrict__ W1T, u16* __restrict__ W2T,
    u16* __restrict__ W3T, u16* __restrict__ W24T, float* __restrict__ b24,
    int* __restrict__ counts, int E_)
{
    int idx = blockIdx.x * 256 + threadIdx.x;
    if (idx < kC * kC) {
        int c = idx / kC, k = idx - c * kC;      // wxT[c][k] = wx[k][c]
        wxT[idx] = f2bf(wx[k * kC + c]);
    }
    for (int e = idx; e < E_; e += gridDim.x * 256) atomicAdd(&counts[pl[e]], 1);

    if (blockIdx.x == 0) {
        int t = threadIdx.x;
        for (int i = t; i < 64 * 64; i += 256) {
            int n = i >> 6, k = i & 63;
            W1T[i] = f2bf((n < kRBF) ? w_in[k * kRBF + n] : 0.f);
        }
        for (int i = t; i < 32 * 128; i += 256) {
            int n = i >> 7, k = i & 127;
            W2T[i] = f2bf((k < 115) ? w_e1[k * kF + n] : 0.f);
        }
        for (int i = t; i < 32 * 32; i += 256) {
            int n = i >> 5, k = i & 31;
            W3T[i] = f2bf(w_e2[k * kF + n]);
        }
        for (int i = t; i < 16 * 32; i += 256) {
            int n = i >> 5, k = i & 31;
            float a = 0.f;
            if (n < kH) for (int o = 0; o < kF; o++) a += w_e2[k * kF + o] * w_att[o * kH + n];
            W24T[i] = f2bf(a);
        }
        if (t < kH) {
            float a = b_att[t];
            for (int o = 0; o < kF; o++) a += b_e2[o] * w_att[o * kH + t];
            b24[t] = a;
        }
    }
}

// ---------------------------------------------------------------------------
// K2: exclusive scan, barrier-light
// ---------------------------------------------------------------------------
__global__ __launch_bounds__(1024) void scan_kernel(
    const int* __restrict__ counts, int* __restrict__ offsets, int n)
{
    __shared__ int buf[1024];
    int t = threadIdx.x;
    int chunk = (n + 1023) >> 10;
    int lo = t * chunk;
    int s = 0;
    for (int i = 0; i < chunk; i++) {
        int g = lo + i;
        if (g < n) s += counts[g];
    }
    buf[t] = s;
    __syncthreads();
    for (int off = 1; off < 1024; off <<= 1) {
        int v = (t >= off) ? buf[t - off] : 0;
        __syncthreads();
        buf[t] += v;
        __syncthreads();
    }
    int run = buf[t] - s;
    for (int i = 0; i < chunk; i++) {
        int g = lo + i;
        if (g < n) { offsets[g] = run; run += counts[g]; }
    }
    if (t == 1023) offsets[n] = buf[1023];
}

// ---------------------------------------------------------------------------
// K3: scatter -> rank (inverse permutation) + nid (node id per CSR position)
// ---------------------------------------------------------------------------
__global__ __launch_bounds__(256) void scatter_kernel(
    const int* __restrict__ pl, const int* __restrict__ offsets,
    int* __restrict__ cursor, int* __restrict__ rank, int* __restrict__ nid, int E_)
{
    int e = blockIdx.x * 256 + threadIdx.x;
    if (e < E_) {
        int i = pl[e];
        int p = atomicAdd(&cursor[i], 1);
        int pos = offsets[i] + p;
        rank[e] = pos;
        nid[pos] = i;
    }
}

// ---------------------------------------------------------------------------
// K4: MFMA edge kernel. Writes he/logit/dir at CSR position rank[e].
// ---------------------------------------------------------------------------
__global__ __launch_bounds__(256) void edge_kernel(
    const float* __restrict__ h, const float* __restrict__ x,
    const int* __restrict__ pl, const int* __restrict__ rank_g, int E_,
    const float* __restrict__ b_in, const float* __restrict__ b_e1,
    const float* __restrict__ b_e2,
    const u16* __restrict__ W1T, const u16* __restrict__ W2T,
    const u16* __restrict__ W3T, const u16* __restrict__ W24T,
    const float* __restrict__ b24,
    float* __restrict__ he_g, float* __restrict__ logit_g,
    float* __restrict__ dir_g)
{
    __shared__ __align__(16) u16 s_A[kEM][kAStr];
    __shared__ __align__(16) u16 s_t1[kEM][kBStr];
    __shared__ float s_d[kEM];
    __shared__ int   s_r[kEM];

    int t = threadIdx.x;
    int T0 = blockIdx.x * kEM;
    int w = t >> 6, lane = t & 63, quad = lane >> 4, l15 = lane & 15;

    {
        int e = t >> 1, half = t & 1;
        int ge = T0 + e;
        bool val = ge < E_;
        int i = 0, j = 0;
        if (val) { i = pl[ge]; j = pl[E_ + ge]; }
        const float4* pi = (const float4*)(h + (size_t)i * kF) + half * 4;
        const float4* pj = (const float4*)(h + (size_t)j * kF) + half * 4;
#pragma unroll
        for (int q = 0; q < 4; q++) {
            float4 a = val ? pi[q] : make_float4(0.f, 0.f, 0.f, 0.f);
            float4 b = val ? pj[q] : make_float4(0.f, 0.f, 0.f, 0.f);
            unsigned* di = (unsigned*)&s_A[e][half * 16 + 4 * q];
            di[0] = pk2(a.x, a.y); di[1] = pk2(a.z, a.w);
            unsigned* dj = (unsigned*)&s_A[e][kF + half * 16 + 4 * q];
            dj[0] = pk2(b.x, b.y); dj[1] = pk2(b.z, b.w);
        }
        if (half == 0) {
            float d = 0.f;
            int r = 0;
            if (val) {
                r = rank_g[ge];
                float r0 = x[j * 3 + 0] - x[i * 3 + 0];
                float r1 = x[j * 3 + 1] - x[i * 3 + 1];
                float r2 = x[j * 3 + 2] - x[i * 3 + 2];
                d = sqrtf(r0 * r0 + r1 * r1 + r2 * r2);
                float inv = 1.0f / (d + kEps);
                dir_g[(size_t)r * 3 + 0] = r0 * inv;
                dir_g[(size_t)r * 3 + 1] = r1 * inv;
                dir_g[(size_t)r * 3 + 2] = r2 * inv;
            }
            s_r[e] = r;
            s_d[e] = d;
            s_A[e][114] = f2bf(d);
            s_A[e][115] = 0;
            unsigned* z = (unsigned*)&s_A[e][116];
#pragma unroll
            for (int q = 0; q < 6; q++) z[q] = 0u;
        }
    }
    __syncthreads();

    const float invw = 49.0f / kCut;

    {   // GEMM1: h_cat @ w_in -> rbf -> filt
        bf16x8 a1[2][2];
#pragma unroll
        for (int rt = 0; rt < 2; rt++)
#pragma unroll
            for (int kt = 0; kt < 2; kt++)
                a1[rt][kt] = *(const bf16x8*)&s_A[32 * w + 16 * rt + l15][kt * 32 + quad * 8];
#pragma unroll
        for (int ct = 0; ct < 4; ct++) {
            int c = ct * 16 + l15;
            bf16x8 b0 = *(const bf16x8*)(W1T + (size_t)c * 64 + quad * 8);
            bf16x8 b1 = *(const bf16x8*)(W1T + (size_t)c * 64 + 32 + quad * 8);
            float bin = (c < kRBF) ? b_in[c] : 0.f;
#pragma unroll
            for (int rt = 0; rt < 2; rt++) {
                f32x4 acc = {0.f, 0.f, 0.f, 0.f};
                acc = __builtin_amdgcn_mfma_f32_16x16x32_bf16(a1[rt][0], b0, acc, 0, 0, 0);
                acc = __builtin_amdgcn_mfma_f32_16x16x32_bf16(a1[rt][1], b1, acc, 0, 0, 0);
                if (c < kRBF) {
#pragma unroll
                    for (int r = 0; r < 4; r++) {
                        int row = 32 * w + 16 * rt + quad * 4 + r;
                        float arg = s_d[row] * invw - (float)c;
                        float filt = __expf(-0.5f * arg * arg) * (acc[r] + bin);
                        s_A[row][64 + c] = f2bf(filt);
                    }
                }
            }
        }
    }

    {   // GEMM2: edge_in @ w_e1 -> silu -> t1
        bf16x8 a2[2][4];
#pragma unroll
        for (int rt = 0; rt < 2; rt++)
#pragma unroll
            for (int kt = 0; kt < 4; kt++)
                a2[rt][kt] = *(const bf16x8*)&s_A[32 * w + 16 * rt + l15][kt * 32 + quad * 8];
#pragma unroll
        for (int ct = 0; ct < 2; ct++) {
            int c = ct * 16 + l15;
            bf16x8 bb[4];
#pragma unroll
            for (int kt = 0; kt < 4; kt++)
                bb[kt] = *(const bf16x8*)(W2T + (size_t)c * 128 + kt * 32 + quad * 8);
            float be = b_e1[c];
#pragma unroll
            for (int rt = 0; rt < 2; rt++) {
                f32x4 acc = {0.f, 0.f, 0.f, 0.f};
#pragma unroll
                for (int kt = 0; kt < 4; kt++)
                    acc = __builtin_amdgcn_mfma_f32_16x16x32_bf16(a2[rt][kt], bb[kt], acc, 0, 0, 0);
#pragma unroll
                for (int r = 0; r < 4; r++) {
                    int row = 32 * w + 16 * rt + quad * 4 + r;
                    s_t1[row][c] = f2bf(silu_f(acc[r] + be));
                }
            }
        }
    }

    {   // GEMM3 (he) + GEMM4 (logits)
        bf16x8 a3[2];
#pragma unroll
        for (int rt = 0; rt < 2; rt++)
            a3[rt] = *(const bf16x8*)&s_t1[32 * w + 16 * rt + l15][quad * 8];

#pragma unroll
        for (int ct = 0; ct < 2; ct++) {
            int c = ct * 16 + l15;
            bf16x8 b3 = *(const bf16x8*)(W3T + (size_t)c * 32 + quad * 8);
            float be = b_e2[c];
#pragma unroll
            for (int rt = 0; rt < 2; rt++) {
                f32x4 acc = {0.f, 0.f, 0.f, 0.f};
                acc = __builtin_amdgcn_mfma_f32_16x16x32_bf16(a3[rt], b3, acc, 0, 0, 0);
#pragma unroll
                for (int r = 0; r < 4; r++) {
                    int row = 32 * w + 16 * rt + quad * 4 + r;
                    int ge = T0 + row;
                    if (ge < E_) he_g[(size_t)s_r[row] * kF + c] = acc[r] + be;
                }
            }
        }
        {
            bf16x8 b4 = *(const bf16x8*)(W24T + (size_t)l15 * 32 + quad * 8);
            float bb = (l15 < kH) ? b24[l15] : 0.f;
#pragma unroll
            for (int rt = 0; rt < 2; rt++) {
                f32x4 acc = {0.f, 0.f, 0.f, 0.f};
                acc = __builtin_amdgcn_mfma_f32_16x16x32_bf16(a3[rt], b4, acc, 0, 0, 0);
                if (l15 < kH) {
#pragma unroll
                    for (int r = 0; r < 4; r++) {
                        int row = 32 * w + 16 * rt + quad * 4 + r;
                        int ge = T0 + row;
                        if (ge < E_) {
                            float a = acc[r] + bb;
                            a = (a >= 0.f) ? a : 2.f * (__expf(0.5f * a) - 1.f);
                            float dd = s_d[row];
                            float cut = (dd < kCut)
                                ? 0.5f * (__cosf(0.62831853071795864f * dd) + 1.f) : 0.f;
                            logit_g[(size_t)s_r[row] * kH + l15] = a * cut;
                        }
                    }
                }
            }
        }
    }
}

// ---------------------------------------------------------------------------
// K5: per-node softmax stats (wave per node, contiguous CSR logit reads)
// ---------------------------------------------------------------------------
__global__ __launch_bounds__(256) void stats_kernel(
    const float* __restrict__ logit_g, const int* __restrict__ offsets,
    float* __restrict__ m_g, float* __restrict__ invs_g, int N_)
{
    int wave = threadIdx.x >> 6;
    int lane = threadIdx.x & 63;
    int node = blockIdx.x * 4 + wave;
    if (node >= N_) return;
    int base = offsets[node];
    int deg  = offsets[node + 1] - base;

    float m[kH], ss[kH];
#pragma unroll
    for (int hh = 0; hh < kH; hh++) { m[hh] = -1e30f; ss[hh] = 0.f; }
    for (int e = lane; e < deg; e += 64) {
        const float* lp = logit_g + (size_t)(base + e) * kH;
#pragma unroll
        for (int hh = 0; hh < kH; hh++) {
            float vv = lp[hh];
            if (vv > m[hh]) { ss[hh] *= __expf(m[hh] - vv); m[hh] = vv; }
            ss[hh] += __expf(vv - m[hh]);
        }
    }
#pragma unroll
    for (int hh = 0; hh < kH; hh++) {
        float mm = m[hh], s2 = ss[hh];
#pragma unroll
        for (int off = 32; off >= 1; off >>= 1) {
            float mo = __shfl_xor(mm, off);
            float so = __shfl_xor(s2, off);
            float mn = fmaxf(mm, mo);
            s2 = s2 * __expf(mm - mn) + so * __expf(mo - mn);
            mm = mn;
        }
        if (lane == 0) {
            m_g[(size_t)node * kH + hh] = mm;
            invs_g[(size_t)node * kH + hh] = (s2 > 0.f) ? 1.f / s2 : 0.f;
        }
    }
}

// ---------------------------------------------------------------------------
// K6: MFMA xmix (r12 shape: 256 thr, kM=128, 4 windows) + triple-buffered
// wxT B prefetch (depth 2) to hide L2 latency.
// ---------------------------------------------------------------------------
__global__ __launch_bounds__(256) void xmix_kernel(
    const float* __restrict__ he_g, const float* __restrict__ logit_g,
    const float* __restrict__ dir_g, const int* __restrict__ nid,
    const float* __restrict__ m_g, const float* __restrict__ invs_g,
    const u16* __restrict__ wxT, int E_,
    float* __restrict__ nodeacc, float* __restrict__ bpart, int* __restrict__ bid)
{
    __shared__ __align__(16) u16 s_buf[kM][kStr];   // sem, then T
    __shared__ float s_att[kM][kH];
    __shared__ __align__(16) float s_dir4[kM][4];
    __shared__ int   s_node[kM];
    __shared__ int   s_prev, s_next;

    int t = threadIdx.x;
    int T0 = blockIdx.x * kM;
    int cp = min(kM, E_ - T0);

    if (t < kM) s_node[t] = (T0 + t < E_) ? nid[T0 + t] : -1;
    if (t == 0) {
        s_prev = (T0 > 0) ? nid[T0 - 1] : -2;
        s_next = (T0 + cp < E_) ? nid[T0 + cp] : -2;
    }
    __syncthreads();

    int w    = t >> 6;
    int lane = t & 63;
    int quad = lane >> 4;
    int l15  = lane & 15;

    // ---- per-wave window params ----
    int ws = 32 * w;
    int we = min(ws + 32, cp);
    bool winvalid = (ws < cp);
    bool contL = false, contR = false;
    if (winvalid) {
        int nfirst = s_node[ws], nlast = s_node[we - 1];
        contL = (w == 0) ? (s_prev == nfirst) : (s_node[ws - 1] == nfirst);
        contR = (we == cp) ? (s_next == nlast) : (s_node[we] == nlast);
    }
    if (lane == 0) {
        int b0 = -1, b1 = -1;
        if (winvalid) {
            int nfirst = s_node[ws], nlast = s_node[we - 1];
            b0 = contL ? nfirst : -1;
            if (contR && !(nfirst == nlast && contL)) b1 = nlast;
        }
        bid[8 * blockIdx.x + 2 * w + 0] = b0;
        bid[8 * blockIdx.x + 2 * w + 1] = b1;
    }
    bool active_w = winvalid && (lane < 56);
    int c0 = 4 * lane;

    for (int idx = t; idx < kM * kH; idx += 256) {
        int e = idx / kH, hh = idx - e * kH;
        float a = 0.f;
        if (T0 + e < E_) {
            int nd = s_node[e];
            a = __expf(logit_g[(size_t)(T0 + e) * kH + hh] - m_g[(size_t)nd * kH + hh])
                * invs_g[(size_t)nd * kH + hh];
        }
        s_att[e][hh] = a;
    }
    for (int idx = t; idx < cp * 3; idx += 256) {
        int e = idx / 3, xx = idx - e * 3;
        s_dir4[e][xx] = dir_g[(size_t)(T0 + e) * 3 + xx];
    }
    __syncthreads();

    // sem build (bf16, hw pack); he reads fully coalesced
#pragma unroll
    for (int p = 0; p < kM * kF / 256; p++) {
        int idx = t + 256 * p;
        int e = idx >> 5, f = idx & 31;
        float hv = (T0 + e < E_) ? he_g[(size_t)(T0 + e) * kF + f] : 0.f;
        float sv[7];
#pragma unroll
        for (int hh = 0; hh < kH; hh++) sv[hh] = hv * s_att[e][hh];
        u16* dst = &s_buf[e][f * 7];
        if ((f & 1) == 0) {
            *(unsigned*)(dst)     = pk2(sv[0], sv[1]);
            *(unsigned*)(dst + 2) = pk2(sv[2], sv[3]);
            *(unsigned*)(dst + 4) = pk2(sv[4], sv[5]);
            dst[6] = f2bf(sv[6]);
        } else {
            dst[0] = f2bf(sv[0]);
            *(unsigned*)(dst + 1) = pk2(sv[1], sv[2]);
            *(unsigned*)(dst + 3) = pk2(sv[3], sv[4]);
            *(unsigned*)(dst + 5) = pk2(sv[5], sv[6]);
        }
    }
    __syncthreads();

    // hisem walk (windowed, b64 column reads, float4 flush)
    if (active_w) {
        float hs0 = 0.f, hs1 = 0.f, hs2 = 0.f, hs3 = 0.f;
        int rs = ws;
        for (int e = ws; e < we; e++) {
            if (s_node[e] != s_node[rs]) {
                bool comp = (rs > ws) || !contL;
                float4 vv = make_float4(hs0, hs1, hs2, hs3);
                if (comp) *(float4*)&nodeacc[(size_t)s_node[rs] * 896 + 672 + c0] = vv;
                else *(float4*)&bpart[(size_t)(8 * blockIdx.x + 2 * w) * 896 + 672 + c0] = vv;
                hs0 = hs1 = hs2 = hs3 = 0.f; rs = e;
            }
            uint2 pv = *(const uint2*)&s_buf[e][c0];
            hs0 += bf2f((u16)pv.x); hs1 += bf2f((u16)(pv.x >> 16));
            hs2 += bf2f((u16)pv.y); hs3 += bf2f((u16)(pv.y >> 16));
        }
        bool t0 = (rs == ws);
        bool comp = ((!t0) || !contL) && !contR;
        float4 vv = make_float4(hs0, hs1, hs2, hs3);
        if (comp) *(float4*)&nodeacc[(size_t)s_node[rs] * 896 + 672 + c0] = vv;
        else {
            int slot = (t0 && contL) ? 0 : 1;
            *(float4*)&bpart[(size_t)(8 * blockIdx.x + 2 * w + slot) * 896 + 672 + c0] = vv;
        }
    }

    // MFMA fragments: wave w owns rows [32w, 32w+32)
    bf16x8 afr[2][7];
#pragma unroll
    for (int rt = 0; rt < 2; rt++)
#pragma unroll
        for (int kt = 0; kt < 7; kt++)
            afr[rt][kt] = *(const bf16x8*)&s_buf[32 * w + 16 * rt + l15][kt * 32 + quad * 8];

    // triple-buffered B prefetch (depth 2) — issued before the barrier so
    // the L2 latency overlaps the walk/A-load drain
    bf16x8 bb[3][7];
#pragma unroll
    for (int kt = 0; kt < 7; kt++)
        bb[0][kt] = *(const bf16x8*)(wxT + (size_t)l15 * kC + kt * 32 + quad * 8);
#pragma unroll
    for (int kt = 0; kt < 7; kt++)
        bb[1][kt] = *(const bf16x8*)(wxT + (size_t)(16 + l15) * kC + kt * 32 + quad * 8);
    __syncthreads();   // hisem walk + A-loads done before T write-back

#pragma unroll
    for (int ct = 0; ct < 14; ct++) {
        const int cur = ct % 3;
        const int nxt = (ct + 2) % 3;
        if (ct < 12) {
            const u16* bp = wxT + (size_t)((ct + 2) * 16 + l15) * kC + quad * 8;
#pragma unroll
            for (int kt = 0; kt < 7; kt++) bb[nxt][kt] = *(const bf16x8*)(bp + kt * 32);
        }
        f32x4 acc0 = {0.f, 0.f, 0.f, 0.f};
        f32x4 acc1 = {0.f, 0.f, 0.f, 0.f};
#pragma unroll
        for (int kt = 0; kt < 7; kt++) {
            acc0 = __builtin_amdgcn_mfma_f32_16x16x32_bf16(afr[0][kt], bb[cur][kt], acc0, 0, 0, 0);
            acc1 = __builtin_amdgcn_mfma_f32_16x16x32_bf16(afr[1][kt], bb[cur][kt], acc1, 0, 0, 0);
        }
        int colg = ct * 16 + l15;
#pragma unroll
        for (int s = 0; s < 2; s++) {
            f32x4 ac = s ? acc1 : acc0;
            int rbase = 32 * w + 16 * s + quad * 4;
            unsigned p01 = pk2(tanh_f(ac[0]), tanh_f(ac[1]));
            unsigned p23 = pk2(tanh_f(ac[2]), tanh_f(ac[3]));
            s_buf[rbase + 0][colg] = (u16)p01;
            s_buf[rbase + 1][colg] = (u16)(p01 >> 16);
            s_buf[rbase + 2][colg] = (u16)p23;
            s_buf[rbase + 3][colg] = (u16)(p23 >> 16);
        }
    }
    __syncthreads();

    // comb walk (windowed, b64 T reads, broadcast dir b128, float4 flushes)
    if (active_w) {
        float a0[4] = {0.f, 0.f, 0.f, 0.f};
        float a1[4] = {0.f, 0.f, 0.f, 0.f};
        float a2[4] = {0.f, 0.f, 0.f, 0.f};
        int rs = ws;
        for (int e = ws; e < we; e++) {
            if (s_node[e] != s_node[rs]) {
                bool comp = (rs > ws) || !contL;
                float* p = comp ? (nodeacc + (size_t)s_node[rs] * 896)
                                : (bpart + (size_t)(8 * blockIdx.x + 2 * w) * 896);
                *(float4*)&p[c0]       = make_float4(a0[0], a0[1], a0[2], a0[3]);
                *(float4*)&p[224 + c0] = make_float4(a1[0], a1[1], a1[2], a1[3]);
                *(float4*)&p[448 + c0] = make_float4(a2[0], a2[1], a2[2], a2[3]);
#pragma unroll
                for (int q = 0; q < 4; q++) { a0[q] = 0.f; a1[q] = 0.f; a2[q] = 0.f; }
                rs = e;
            }
            float4 dd = *(const float4*)&s_dir4[e][0];
            uint2 pv = *(const uint2*)&s_buf[e][c0];
            float Tv[4];
            Tv[0] = bf2f((u16)pv.x); Tv[1] = bf2f((u16)(pv.x >> 16));
            Tv[2] = bf2f((u16)pv.y); Tv[3] = bf2f((u16)(pv.y >> 16));
#pragma unroll
            for (int q = 0; q < 4; q++) {
                a0[q] += Tv[q] * dd.x;
                a1[q] += Tv[q] * dd.y;
                a2[q] += Tv[q] * dd.z;
            }
        }
        bool t0 = (rs == ws);
        bool comp = ((!t0) || !contL) && !contR;
        float* p;
        if (comp) p = nodeacc + (size_t)s_node[rs] * 896;
        else {
            int slot = (t0 && contL) ? 0 : 1;
            p = bpart + (size_t)(8 * blockIdx.x + 2 * w + slot) * 896;
        }
        *(float4*)&p[c0]       = make_float4(a0[0], a0[1], a0[2], a0[3]);
        *(float4*)&p[224 + c0] = make_float4(a1[0], a1[1], a1[2], a1[3]);
        *(float4*)&p[448 + c0] = make_float4(a2[0], a2[1], a2[2], a2[3]);
    }
}

// ---------------------------------------------------------------------------
// K7: node epilogue. 4 nodes/block; gather nodeacc/bpart (32-edge windows);
// MLPs with weight-value reuse across the 4 nodes.
// ---------------------------------------------------------------------------
__global__ __launch_bounds__(256) void node_kernel(
    const float* __restrict__ h, const float* __restrict__ x, const float* __restrict__ v,
    const float* __restrict__ nodeacc, const float* __restrict__ bpart,
    const int* __restrict__ bid, const int* __restrict__ offs,
    const float* __restrict__ w_n1, const float* __restrict__ b_n1,
    const float* __restrict__ w_n2, const float* __restrict__ b_n2,
    const float* __restrict__ w_pn1, const float* __restrict__ b_pn1,
    const float* __restrict__ w_pn2, const float* __restrict__ b_pn2,
    const float* __restrict__ w_v1, const float* __restrict__ b_v1,
    const float* __restrict__ w_v2, const float* __restrict__ w_vmix,
    float* __restrict__ out_h, float* __restrict__ out_x, float* __restrict__ out_v,
    int N_)
{
    __shared__ float s_cm[4][3][kC];
    __shared__ float s_cnsq[4][kC];
    __shared__ float s_ni[4][288];          // [h | hisem | spat]
    __shared__ float s_part[8][4][kF];
    __shared__ float s_hn[4][kF], s_sp1[4][kF], s_spat[4][kF], s_n1v[4][kF], s_g1[4][kF];
    __shared__ float s_pdv[4][3][8];
    __shared__ float s_gate[4], s_dv[4][3];

    int t = threadIdx.x;
    int n0 = blockIdx.x * 4;

    if (t < kC) {
        for (int nd = 0; nd < 4; nd++) {
            int node = n0 + nd;
            if (node >= N_) break;
            int base = offs[node], end = offs[node + 1];
            int deg = end - base;
            float a0 = 0.f, a1 = 0.f, a2 = 0.f, hh = 0.f;
            if (deg > 0) {
                int wlo = base >> 5, whi = (end - 1) >> 5;
                if (wlo == whi) {
                    const float* p = nodeacc + (size_t)node * 896;
                    a0 = p[t]; a1 = p[224 + t]; a2 = p[448 + t]; hh = p[672 + t];
                } else {
                    for (int W = wlo; W <= whi; W++) {
#pragma unroll
                        for (int s = 0; s < 2; s++) {
                            if (bid[2 * W + s] == node) {
                                const float* p = bpart + (size_t)(2 * W + s) * 896;
                                a0 += p[t]; a1 += p[224 + t]; a2 += p[448 + t]; hh += p[672 + t];
                            }
                        }
                    }
                }
            }
            float invc = 1.f / fmaxf((float)deg, 1.f);
            float m0 = a0 * invc, m1 = a1 * invc, m2 = a2 * invc;
            s_cm[nd][0][t] = m0; s_cm[nd][1][t] = m1; s_cm[nd][2][t] = m2;
            s_cnsq[nd][t] = m0 * m0 + m1 * m1 + m2 * m2;
            s_ni[nd][kF + t] = hh;
        }
    } else {
        int ln = t - 224;   // 0..31
        for (int nd = 0; nd < 4; nd++) {
            int node = n0 + nd;
            float hv = (node < N_) ? h[(size_t)node * kF + ln] : 0.f;
            s_hn[nd][ln] = hv;
            s_ni[nd][ln] = hv;
        }
    }
    __syncthreads();

    int o = t & 31, g = t >> 5;
    {   // pn1 partials, 4 nodes per weight load
        float acc[4] = {0.f, 0.f, 0.f, 0.f};
        int cb = g * 28;
        for (int i = 0; i < 28; i++) {
            float wv = w_pn1[(cb + i) * kF + o];
#pragma unroll
            for (int nd = 0; nd < 4; nd++) acc[nd] += s_cnsq[nd][cb + i] * wv;
        }
#pragma unroll
        for (int nd = 0; nd < 4; nd++) s_part[g][nd][o] = acc[nd];
    }
    __syncthreads();
    if (t < 128) {
        int nd = t >> 5;
        float a = b_pn1[o];
#pragma unroll
        for (int g2 = 0; g2 < 8; g2++) a += s_part[g2][nd][o];
        s_sp1[nd][o] = silu_f(a);
    } else {
        int nd = (t - 128) >> 5;
        float a = b_v1[o];
        for (int f = 0; f < kF; f++) a += s_hn[nd][f] * w_v1[f * kF + o];
        s_g1[nd][o] = silu_f(a);
    }
    __syncthreads();
    if (t < 128) {
        int nd = t >> 5;
        float a = b_pn2[o];
        for (int o2 = 0; o2 < kF; o2++) a += s_sp1[nd][o2] * w_pn2[o2 * kF + o];
        s_spat[nd][o] = silu_f(a);
    } else if (t < 132) {
        int nd = t - 128;
        float a = 0.f;
        for (int o2 = 0; o2 < kF; o2++) a += s_g1[nd][o2] * w_v2[o2];
        s_gate[nd] = 2.f / (1.f + __expf(-a));
    } else if (t >= 160) {   // 96 threads: dv partials
        int q = t - 160; int nd = q / 24; int r = q - nd * 24;
        int xx = r >> 3, ln = r & 7;
        float a = 0.f;
        for (int c = ln; c < kC; c += 8) a += w_vmix[c] * s_cm[nd][xx][c];
        s_pdv[nd][xx][ln] = a;
    }
    __syncthreads();
    if (t < 128) {
        int nd = t >> 5;
        s_ni[nd][kF + kC + o] = s_spat[nd][o];
    } else if (t < 140) {
        int q = t - 128; int nd = q / 3; int xx = q - nd * 3;
        float a = 0.f;
#pragma unroll
        for (int ln = 0; ln < 8; ln++) a += s_pdv[nd][xx][ln];
        s_dv[nd][xx] = a;
    }
    __syncthreads();
    {   // n1 partials: 8 groups x 36 rows
        float acc[4] = {0.f, 0.f, 0.f, 0.f};
        int rb = g * 36;
        for (int i = 0; i < 36; i++) {
            float wv = w_n1[(rb + i) * kF + o];
#pragma unroll
            for (int nd = 0; nd < 4; nd++) acc[nd] += s_ni[nd][rb + i] * wv;
        }
#pragma unroll
        for (int nd = 0; nd < 4; nd++) s_part[g][nd][o] = acc[nd];
    }
    __syncthreads();
    if (t < 128) {
        int nd = t >> 5;
        float a = b_n1[o];
#pragma unroll
        for (int g2 = 0; g2 < 8; g2++) a += s_part[g2][nd][o];
        s_n1v[nd][o] = silu_f(a);
    }
    __syncthreads();
    if (t < 128) {
        int nd = t >> 5; int node = n0 + nd;
        if (node < N_) {
            float a = b_n2[o];
            for (int o2 = 0; o2 < kF; o2++) a += s_n1v[nd][o2] * w_n2[o2 * kF + o];
            out_h[(size_t)node * kF + o] = s_hn[nd][o] + silu_f(a);
        }
    } else if (t < 140) {
        int q = t - 128; int nd = q / 3; int xx = q - nd * 3;
        int node = n0 + nd;
        if (node < N_) {
            float vv = v[(size_t)node * 3 + xx];
            float vu = s_gate[nd] * vv + s_dv[nd][xx];
            out_v[(size_t)node * 3 + xx] = vu;
            out_x[(size_t)node * 3 + xx] = x[(size_t)node * 3 + xx] + vu;
        }
    }
}

// ---------------------------------------------------------------------------
extern "C" void kernel_launch(void* const* d_in, const int* in_sizes, int n_in,
                              void* d_out, int out_size, void* d_ws, size_t ws_size,
                              hipStream_t stream)
{
    const float* h      = (const float*)d_in[0];
    const float* x      = (const float*)d_in[1];
    const float* v      = (const float*)d_in[2];
    const int*   pl     = (const int*)d_in[3];
    const float* w_in   = (const float*)d_in[4];
    const float* b_in   = (const float*)d_in[5];
    const float* w_e1   = (const float*)d_in[6];
    const float* b_e1   = (const float*)d_in[7];
    const float* w_e2   = (const float*)d_in[8];
    const float* b_e2   = (const float*)d_in[9];
    const float* w_att  = (const float*)d_in[10];
    const float* b_att  = (const float*)d_in[11];
    const float* w_n1   = (const float*)d_in[12];
    const float* b_n1   = (const float*)d_in[13];
    const float* w_n2   = (const float*)d_in[14];
    const float* b_n2   = (const float*)d_in[15];
    const float* w_pn1  = (const float*)d_in[16];
    const float* b_pn1  = (const float*)d_in[17];
    const float* w_pn2  = (const float*)d_in[18];
    const float* b_pn2  = (const float*)d_in[19];
    const float* w_v1   = (const float*)d_in[20];
    const float* b_v1   = (const float*)d_in[21];
    const float* w_v2   = (const float*)d_in[22];
    const float* w_xmix = (const float*)d_in[23];
    const float* w_vmix = (const float*)d_in[24];

    const int E_ = in_sizes[3] / 2;
    const int N_ = in_sizes[0] / kF;
    const int nblk = (E_ + kM - 1) / kM;

    // Workspace (~117 MB; 16B-aligned segments first)
    char* w = (char*)d_ws;
    u16*   wxT     = (u16*)w;   w += (size_t)kC * kC * 2;
    u16*   W1T     = (u16*)w;   w += (size_t)64 * 64 * 2;
    u16*   W2T     = (u16*)w;   w += (size_t)32 * 128 * 2;
    u16*   W3T     = (u16*)w;   w += (size_t)32 * 32 * 2;
    u16*   W24T    = (u16*)w;   w += (size_t)16 * 32 * 2;
    float* b24     = (float*)w; w += 8 * 4;
    float* he_g    = (float*)w; w += (size_t)E_ * kF * 4;
    float* logit_g = (float*)w; w += (size_t)E_ * kH * 4;
    float* dir_g   = (float*)w; w += (size_t)E_ * 3 * 4;
    float* m_g     = (float*)w; w += (size_t)N_ * kH * 4;
    float* invs_g  = (float*)w; w += (size_t)N_ * kH * 4;
    float* nodeacc = (float*)w; w += (size_t)N_ * 896 * 4;       // [N][4][224]
    float* bpart   = (float*)w; w += (size_t)8 * nblk * 896 * 4; // 4 win x 2 slots / blk
    int*   bid     = (int*)w;   w += (size_t)8 * nblk * 4;
    int* counts    = (int*)w;   w += (size_t)N_ * 4;
    int* offs      = (int*)w;   w += (size_t)(N_ + 1) * 4;
    int* cursor    = (int*)w;   w += (size_t)N_ * 4;
    int* rank_g    = (int*)w;   w += (size_t)E_ * 4;
    int* nid       = (int*)w;   w += (size_t)E_ * 4;

    float* out_h = (float*)d_out;
    float* out_x = out_h + (size_t)N_ * kF;
    float* out_v = out_x + (size_t)N_ * 3;

    hipMemsetAsync(counts, 0, (size_t)N_ * 4, stream);
    hipMemsetAsync(cursor, 0, (size_t)N_ * 4, stream);

    init_kernel<<<dim3((kC * kC + 255) / 256), dim3(256), 0, stream>>>(
        w_xmix, w_in, w_e1, w_e2, w_att, b_e2, b_att, pl,
        wxT, W1T, W2T, W3T, W24T, b24, counts, E_);

    scan_kernel<<<dim3(1), dim3(1024), 0, stream>>>(counts, offs, N_);

    scatter_kernel<<<dim3((E_ + 255) / 256), dim3(256), 0, stream>>>(
        pl, offs, cursor, rank_g, nid, E_);

    edge_kernel<<<dim3((E_ + kEM - 1) / kEM), dim3(256), 0, stream>>>(
        h, x, pl, rank_g, E_, b_in, b_e1, b_e2, W1T, W2T, W3T, W24T, b24,
        he_g, logit_g, dir_g);

    stats_kernel<<<dim3((N_ + 3) / 4), dim3(256), 0, stream>>>(
        logit_g, offs, m_g, invs_g, N_);

    xmix_kernel<<<dim3(nblk), dim3(256), 0, stream>>>(
        he_g, logit_g, dir_g, nid, m_g, invs_g, wxT, E_,
        nodeacc, bpart, bid);

    node_kernel<<<dim3((N_ + 3) / 4), dim3(256), 0, stream>>>(
        h, x, v, nodeacc, bpart, bid, offs,
        w_n1, b_n1, w_n2, b_n2, w_pn1, b_pn1, w_pn2, b_pn2,
        w_v1, b_v1, w_v2, w_vmix, out_h, out_x, out_v, N_);
}

// Round 15
// 334.720 us; speedup vs baseline: 1.1077x; 1.0410x over previous
//
#include <hip/hip_runtime.h>
#include <hip/hip_bf16.h>
#include <math.h>

typedef unsigned short u16;
typedef __attribute__((ext_vector_type(8))) short bf16x8;
typedef __attribute__((ext_vector_type(4))) float f32x4;

// Problem constants (match reference)
constexpr int kF    = 32;    // nr_atom_basis
constexpr int kH    = 7;     // heads
constexpr int kC    = 224;   // F*H
constexpr int kRBF  = 50;
constexpr int kM    = 128;   // edges per xmix tile
constexpr int kStr  = 232;   // xmix LDS row stride (bf16; 464B, 16B-aligned)
constexpr int kEM   = 128;   // edges per edge-MFMA block
constexpr int kAStr = 136;   // edge A-tile stride (bf16; 272B, 16B-aligned)
constexpr int kBStr = 40;    // t1 tile stride (bf16; 80B, 16B-aligned)
constexpr float kCut = 5.0f;
constexpr float kEps = 1e-8f;

__device__ __forceinline__ float silu_f(float a) { return a / (1.f + __expf(-a)); }
__device__ __forceinline__ float tanh_f(float x) {
    float e = __expf(2.f * x);
    return 1.f - 2.f / (e + 1.f);
}
__device__ __forceinline__ float bf2f(u16 u) {
    union { unsigned int i; float f; } v; v.i = ((unsigned int)u) << 16; return v.f;
}
__device__ __forceinline__ u16 f2bf(float f) {
    union { float f; unsigned int i; } v; v.f = f;
    unsigned int x = v.i;
    unsigned int round = ((x >> 16) & 1u) + 0x7fffu;
    return (u16)((x + round) >> 16);
}
__device__ __forceinline__ unsigned pk2(float a, float b) {
    union { __hip_bfloat162 h; unsigned u; } v;
    v.h = __float22bfloat162_rn(make_float2(a, b));
    return v.u;
}

// ---------------------------------------------------------------------------
// K0: build wxT + edge-MLP B-matrices; histogram of idx_i (counts pre-zeroed)
// ---------------------------------------------------------------------------
__global__ __launch_bounds__(256) void init_kernel(
    const float* __restrict__ wx, const float* __restrict__ w_in,
    const float* __restrict__ w_e1, const float* __restrict__ w_e2,
    const float* __restrict__ w_att, const float* __restrict__ b_e2,
    const float* __restrict__ b_att, const int* __restrict__ pl,
    u16* __restrict__ wxT, u16* __restrict__ W1T, u16* __restrict__ W2T,
    u16* __restrict__ W3T, u16* __restrict__ W24T, float* __restrict__ b24,
    int* __restrict__ counts, int E_)
{
    int idx = blockIdx.x * 256 + threadIdx.x;
    if (idx < kC * kC) {
        int c = idx / kC, k = idx - c * kC;      // wxT[c][k] = wx[k][c]
        wxT[idx] = f2bf(wx[k * kC + c]);
    }
    for (int e = idx; e < E_; e += gridDim.x * 256) atomicAdd(&counts[pl[e]], 1);

    if (blockIdx.x == 0) {
        int t = threadIdx.x;
        for (int i = t; i < 64 * 64; i += 256) {
            int n = i >> 6, k = i & 63;
            W1T[i] = f2bf((n < kRBF) ? w_in[k * kRBF + n] : 0.f);
        }
        for (int i = t; i < 32 * 128; i += 256) {
            int n = i >> 7, k = i & 127;
            W2T[i] = f2bf((k < 115) ? w_e1[k * kF + n] : 0.f);
        }
        for (int i = t; i < 32 * 32; i += 256) {
            int n = i >> 5, k = i & 31;
            W3T[i] = f2bf(w_e2[k * kF + n]);
        }
        for (int i = t; i < 16 * 32; i += 256) {
            int n = i >> 5, k = i & 31;
            float a = 0.f;
            if (n < kH) for (int o = 0; o < kF; o++) a += w_e2[k * kF + o] * w_att[o * kH + n];
            W24T[i] = f2bf(a);
        }
        if (t < kH) {
            float a = b_att[t];
            for (int o = 0; o < kF; o++) a += b_e2[o] * w_att[o * kH + t];
            b24[t] = a;
        }
    }
}

// ---------------------------------------------------------------------------
// K1: exclusive scan, barrier-light
// ---------------------------------------------------------------------------
__global__ __launch_bounds__(1024) void scan_kernel(
    const int* __restrict__ counts, int* __restrict__ offsets, int n)
{
    __shared__ int buf[1024];
    int t = threadIdx.x;
    int chunk = (n + 1023) >> 10;
    int lo = t * chunk;
    int s = 0;
    for (int i = 0; i < chunk; i++) {
        int g = lo + i;
        if (g < n) s += counts[g];
    }
    buf[t] = s;
    __syncthreads();
    for (int off = 1; off < 1024; off <<= 1) {
        int v = (t >= off) ? buf[t - off] : 0;
        __syncthreads();
        buf[t] += v;
        __syncthreads();
    }
    int run = buf[t] - s;
    for (int i = 0; i < chunk; i++) {
        int g = lo + i;
        if (g < n) { offsets[g] = run; run += counts[g]; }
    }
    if (t == 1023) offsets[n] = buf[1023];
}

// ---------------------------------------------------------------------------
// K2: MFMA edge kernel; does the CSR scatter itself (cursor atomic -> pos),
// writes nid + he(bf16)/logit/dir at CSR position.
// ---------------------------------------------------------------------------
__global__ __launch_bounds__(256) void edge_kernel(
    const float* __restrict__ h, const float* __restrict__ x,
    const int* __restrict__ pl, const int* __restrict__ offs,
    int* __restrict__ cursor, int* __restrict__ nid, int E_,
    const float* __restrict__ b_in, const float* __restrict__ b_e1,
    const float* __restrict__ b_e2,
    const u16* __restrict__ W1T, const u16* __restrict__ W2T,
    const u16* __restrict__ W3T, const u16* __restrict__ W24T,
    const float* __restrict__ b24,
    u16* __restrict__ he_g, float* __restrict__ logit_g,
    float* __restrict__ dir_g)
{
    __shared__ __align__(16) u16 s_A[kEM][kAStr];
    __shared__ __align__(16) u16 s_t1[kEM][kBStr];
    __shared__ float s_d[kEM];
    __shared__ int   s_r[kEM];

    int t = threadIdx.x;
    int T0 = blockIdx.x * kEM;
    int w = t >> 6, lane = t & 63, quad = lane >> 4, l15 = lane & 15;

    {
        int e = t >> 1, half = t & 1;
        int ge = T0 + e;
        bool val = ge < E_;
        int i = 0, j = 0;
        if (val) { i = pl[ge]; j = pl[E_ + ge]; }
        const float4* pi = (const float4*)(h + (size_t)i * kF) + half * 4;
        const float4* pj = (const float4*)(h + (size_t)j * kF) + half * 4;
#pragma unroll
        for (int q = 0; q < 4; q++) {
            float4 a = val ? pi[q] : make_float4(0.f, 0.f, 0.f, 0.f);
            float4 b = val ? pj[q] : make_float4(0.f, 0.f, 0.f, 0.f);
            unsigned* di = (unsigned*)&s_A[e][half * 16 + 4 * q];
            di[0] = pk2(a.x, a.y); di[1] = pk2(a.z, a.w);
            unsigned* dj = (unsigned*)&s_A[e][kF + half * 16 + 4 * q];
            dj[0] = pk2(b.x, b.y); dj[1] = pk2(b.z, b.w);
        }
        if (half == 0) {
            float d = 0.f;
            int r = 0;
            if (val) {
                int p = atomicAdd(&cursor[i], 1);
                r = offs[i] + p;
                nid[r] = i;
                float r0 = x[j * 3 + 0] - x[i * 3 + 0];
                float r1 = x[j * 3 + 1] - x[i * 3 + 1];
                float r2 = x[j * 3 + 2] - x[i * 3 + 2];
                d = sqrtf(r0 * r0 + r1 * r1 + r2 * r2);
                float inv = 1.0f / (d + kEps);
                dir_g[(size_t)r * 3 + 0] = r0 * inv;
                dir_g[(size_t)r * 3 + 1] = r1 * inv;
                dir_g[(size_t)r * 3 + 2] = r2 * inv;
            }
            s_r[e] = r;
            s_d[e] = d;
            s_A[e][114] = f2bf(d);
            s_A[e][115] = 0;
            unsigned* z = (unsigned*)&s_A[e][116];
#pragma unroll
            for (int q = 0; q < 6; q++) z[q] = 0u;
        }
    }
    __syncthreads();

    const float invw = 49.0f / kCut;

    {   // GEMM1: h_cat @ w_in -> rbf -> filt
        bf16x8 a1[2][2];
#pragma unroll
        for (int rt = 0; rt < 2; rt++)
#pragma unroll
            for (int kt = 0; kt < 2; kt++)
                a1[rt][kt] = *(const bf16x8*)&s_A[32 * w + 16 * rt + l15][kt * 32 + quad * 8];
#pragma unroll
        for (int ct = 0; ct < 4; ct++) {
            int c = ct * 16 + l15;
            bf16x8 b0 = *(const bf16x8*)(W1T + (size_t)c * 64 + quad * 8);
            bf16x8 b1 = *(const bf16x8*)(W1T + (size_t)c * 64 + 32 + quad * 8);
            float bin = (c < kRBF) ? b_in[c] : 0.f;
#pragma unroll
            for (int rt = 0; rt < 2; rt++) {
                f32x4 acc = {0.f, 0.f, 0.f, 0.f};
                acc = __builtin_amdgcn_mfma_f32_16x16x32_bf16(a1[rt][0], b0, acc, 0, 0, 0);
                acc = __builtin_amdgcn_mfma_f32_16x16x32_bf16(a1[rt][1], b1, acc, 0, 0, 0);
                if (c < kRBF) {
#pragma unroll
                    for (int r = 0; r < 4; r++) {
                        int row = 32 * w + 16 * rt + quad * 4 + r;
                        float arg = s_d[row] * invw - (float)c;
                        float filt = __expf(-0.5f * arg * arg) * (acc[r] + bin);
                        s_A[row][64 + c] = f2bf(filt);
                    }
                }
            }
        }
    }

    {   // GEMM2: edge_in @ w_e1 -> silu -> t1
        bf16x8 a2[2][4];
#pragma unroll
        for (int rt = 0; rt < 2; rt++)
#pragma unroll
            for (int kt = 0; kt < 4; kt++)
                a2[rt][kt] = *(const bf16x8*)&s_A[32 * w + 16 * rt + l15][kt * 32 + quad * 8];
#pragma unroll
        for (int ct = 0; ct < 2; ct++) {
            int c = ct * 16 + l15;
            bf16x8 bb[4];
#pragma unroll
            for (int kt = 0; kt < 4; kt++)
                bb[kt] = *(const bf16x8*)(W2T + (size_t)c * 128 + kt * 32 + quad * 8);
            float be = b_e1[c];
#pragma unroll
            for (int rt = 0; rt < 2; rt++) {
                f32x4 acc = {0.f, 0.f, 0.f, 0.f};
#pragma unroll
                for (int kt = 0; kt < 4; kt++)
                    acc = __builtin_amdgcn_mfma_f32_16x16x32_bf16(a2[rt][kt], bb[kt], acc, 0, 0, 0);
#pragma unroll
                for (int r = 0; r < 4; r++) {
                    int row = 32 * w + 16 * rt + quad * 4 + r;
                    s_t1[row][c] = f2bf(silu_f(acc[r] + be));
                }
            }
        }
    }

    {   // GEMM3 (he, bf16 out) + GEMM4 (logits)
        bf16x8 a3[2];
#pragma unroll
        for (int rt = 0; rt < 2; rt++)
            a3[rt] = *(const bf16x8*)&s_t1[32 * w + 16 * rt + l15][quad * 8];

#pragma unroll
        for (int ct = 0; ct < 2; ct++) {
            int c = ct * 16 + l15;
            bf16x8 b3 = *(const bf16x8*)(W3T + (size_t)c * 32 + quad * 8);
            float be = b_e2[c];
#pragma unroll
            for (int rt = 0; rt < 2; rt++) {
                f32x4 acc = {0.f, 0.f, 0.f, 0.f};
                acc = __builtin_amdgcn_mfma_f32_16x16x32_bf16(a3[rt], b3, acc, 0, 0, 0);
#pragma unroll
                for (int r = 0; r < 4; r++) {
                    int row = 32 * w + 16 * rt + quad * 4 + r;
                    int ge = T0 + row;
                    if (ge < E_) he_g[(size_t)s_r[row] * kF + c] = f2bf(acc[r] + be);
                }
            }
        }
        {
            bf16x8 b4 = *(const bf16x8*)(W24T + (size_t)l15 * 32 + quad * 8);
            float bb = (l15 < kH) ? b24[l15] : 0.f;
#pragma unroll
            for (int rt = 0; rt < 2; rt++) {
                f32x4 acc = {0.f, 0.f, 0.f, 0.f};
                acc = __builtin_amdgcn_mfma_f32_16x16x32_bf16(a3[rt], b4, acc, 0, 0, 0);
                if (l15 < kH) {
#pragma unroll
                    for (int r = 0; r < 4; r++) {
                        int row = 32 * w + 16 * rt + quad * 4 + r;
                        int ge = T0 + row;
                        if (ge < E_) {
                            float a = acc[r] + bb;
                            a = (a >= 0.f) ? a : 2.f * (__expf(0.5f * a) - 1.f);
                            float dd = s_d[row];
                            float cut = (dd < kCut)
                                ? 0.5f * (__cosf(0.62831853071795864f * dd) + 1.f) : 0.f;
                            logit_g[(size_t)s_r[row] * kH + l15] = a * cut;
                        }
                    }
                }
            }
        }
    }
}

// ---------------------------------------------------------------------------
// K3: per-node softmax stats (32-lane group per node, 8 nodes/block)
// ---------------------------------------------------------------------------
__global__ __launch_bounds__(256) void stats_kernel(
    const float* __restrict__ logit_g, const int* __restrict__ offsets,
    float* __restrict__ m_g, float* __restrict__ invs_g, int N_)
{
    int grp  = threadIdx.x >> 5;
    int lane = threadIdx.x & 31;
    int node = blockIdx.x * 8 + grp;
    if (node >= N_) return;
    int base = offsets[node];
    int deg  = offsets[node + 1] - base;

    float m[kH], ss[kH];
#pragma unroll
    for (int hh = 0; hh < kH; hh++) { m[hh] = -1e30f; ss[hh] = 0.f; }
    for (int e = lane; e < deg; e += 32) {
        const float* lp = logit_g + (size_t)(base + e) * kH;
#pragma unroll
        for (int hh = 0; hh < kH; hh++) {
            float vv = lp[hh];
            if (vv > m[hh]) { ss[hh] *= __expf(m[hh] - vv); m[hh] = vv; }
            ss[hh] += __expf(vv - m[hh]);
        }
    }
#pragma unroll
    for (int hh = 0; hh < kH; hh++) {
        float mm = m[hh], s2 = ss[hh];
#pragma unroll
        for (int off = 16; off >= 1; off >>= 1) {   // stays within 32-lane group
            float mo = __shfl_xor(mm, off);
            float so = __shfl_xor(s2, off);
            float mn = fmaxf(mm, mo);
            s2 = s2 * __expf(mm - mn) + so * __expf(mo - mn);
            mm = mn;
        }
        if (lane == 0) {
            m_g[(size_t)node * kH + hh] = mm;
            invs_g[(size_t)node * kH + hh] = (s2 > 0.f) ? 1.f / s2 : 0.f;
        }
    }
}

// ---------------------------------------------------------------------------
// K4: MFMA xmix (256 thr, kM=128, 4 windows) + quad-buffered wxT B prefetch
// ---------------------------------------------------------------------------
__global__ __launch_bounds__(256) void xmix_kernel(
    const u16* __restrict__ he_g, const float* __restrict__ logit_g,
    const float* __restrict__ dir_g, const int* __restrict__ nid,
    const float* __restrict__ m_g, const float* __restrict__ invs_g,
    const u16* __restrict__ wxT, int E_,
    float* __restrict__ nodeacc, float* __restrict__ bpart, int* __restrict__ bid)
{
    __shared__ __align__(16) u16 s_buf[kM][kStr];   // sem, then T
    __shared__ float s_att[kM][kH];
    __shared__ __align__(16) float s_dir4[kM][4];
    __shared__ int   s_node[kM];
    __shared__ int   s_prev, s_next;

    int t = threadIdx.x;
    int T0 = blockIdx.x * kM;
    int cp = min(kM, E_ - T0);

    if (t < kM) s_node[t] = (T0 + t < E_) ? nid[T0 + t] : -1;
    if (t == 0) {
        s_prev = (T0 > 0) ? nid[T0 - 1] : -2;
        s_next = (T0 + cp < E_) ? nid[T0 + cp] : -2;
    }
    __syncthreads();

    int w    = t >> 6;
    int lane = t & 63;
    int quad = lane >> 4;
    int l15  = lane & 15;

    // ---- per-wave window params ----
    int ws = 32 * w;
    int we = min(ws + 32, cp);
    bool winvalid = (ws < cp);
    bool contL = false, contR = false;
    if (winvalid) {
        int nfirst = s_node[ws], nlast = s_node[we - 1];
        contL = (w == 0) ? (s_prev == nfirst) : (s_node[ws - 1] == nfirst);
        contR = (we == cp) ? (s_next == nlast) : (s_node[we] == nlast);
    }
    if (lane == 0) {
        int b0 = -1, b1 = -1;
        if (winvalid) {
            int nfirst = s_node[ws], nlast = s_node[we - 1];
            b0 = contL ? nfirst : -1;
            if (contR && !(nfirst == nlast && contL)) b1 = nlast;
        }
        bid[8 * blockIdx.x + 2 * w + 0] = b0;
        bid[8 * blockIdx.x + 2 * w + 1] = b1;
    }
    bool active_w = winvalid && (lane < 56);
    int c0 = 4 * lane;

    for (int idx = t; idx < kM * kH; idx += 256) {
        int e = idx / kH, hh = idx - e * kH;
        float a = 0.f;
        if (T0 + e < E_) {
            int nd = s_node[e];
            a = __expf(logit_g[(size_t)(T0 + e) * kH + hh] - m_g[(size_t)nd * kH + hh])
                * invs_g[(size_t)nd * kH + hh];
        }
        s_att[e][hh] = a;
    }
    for (int idx = t; idx < cp * 3; idx += 256) {
        int e = idx / 3, xx = idx - e * 3;
        s_dir4[e][xx] = dir_g[(size_t)(T0 + e) * 3 + xx];
    }
    __syncthreads();

    // sem build (bf16, hw pack); he reads coalesced (bf16)
#pragma unroll
    for (int p = 0; p < kM * kF / 256; p++) {
        int idx = t + 256 * p;
        int e = idx >> 5, f = idx & 31;
        float hv = (T0 + e < E_) ? bf2f(he_g[(size_t)(T0 + e) * kF + f]) : 0.f;
        float sv[7];
#pragma unroll
        for (int hh = 0; hh < kH; hh++) sv[hh] = hv * s_att[e][hh];
        u16* dst = &s_buf[e][f * 7];
        if ((f & 1) == 0) {
            *(unsigned*)(dst)     = pk2(sv[0], sv[1]);
            *(unsigned*)(dst + 2) = pk2(sv[2], sv[3]);
            *(unsigned*)(dst + 4) = pk2(sv[4], sv[5]);
            dst[6] = f2bf(sv[6]);
        } else {
            dst[0] = f2bf(sv[0]);
            *(unsigned*)(dst + 1) = pk2(sv[1], sv[2]);
            *(unsigned*)(dst + 3) = pk2(sv[3], sv[4]);
            *(unsigned*)(dst + 5) = pk2(sv[5], sv[6]);
        }
    }
    __syncthreads();

    // hisem walk (windowed, b64 column reads, float4 flush)
    if (active_w) {
        float hs0 = 0.f, hs1 = 0.f, hs2 = 0.f, hs3 = 0.f;
        int rs = ws;
        for (int e = ws; e < we; e++) {
            if (s_node[e] != s_node[rs]) {
                bool comp = (rs > ws) || !contL;
                float4 vv = make_float4(hs0, hs1, hs2, hs3);
                if (comp) *(float4*)&nodeacc[(size_t)s_node[rs] * 896 + 672 + c0] = vv;
                else *(float4*)&bpart[(size_t)(8 * blockIdx.x + 2 * w) * 896 + 672 + c0] = vv;
                hs0 = hs1 = hs2 = hs3 = 0.f; rs = e;
            }
            uint2 pv = *(const uint2*)&s_buf[e][c0];
            hs0 += bf2f((u16)pv.x); hs1 += bf2f((u16)(pv.x >> 16));
            hs2 += bf2f((u16)pv.y); hs3 += bf2f((u16)(pv.y >> 16));
        }
        bool t0 = (rs == ws);
        bool comp = ((!t0) || !contL) && !contR;
        float4 vv = make_float4(hs0, hs1, hs2, hs3);
        if (comp) *(float4*)&nodeacc[(size_t)s_node[rs] * 896 + 672 + c0] = vv;
        else {
            int slot = (t0 && contL) ? 0 : 1;
            *(float4*)&bpart[(size_t)(8 * blockIdx.x + 2 * w + slot) * 896 + 672 + c0] = vv;
        }
    }

    // MFMA fragments: wave w owns rows [32w, 32w+32)
    bf16x8 afr[2][7];
#pragma unroll
    for (int rt = 0; rt < 2; rt++)
#pragma unroll
        for (int kt = 0; kt < 7; kt++)
            afr[rt][kt] = *(const bf16x8*)&s_buf[32 * w + 16 * rt + l15][kt * 32 + quad * 8];

    // quad-buffered B prefetch (depth 3)
    bf16x8 bb[4][7];
#pragma unroll
    for (int b = 0; b < 3; b++)
#pragma unroll
        for (int kt = 0; kt < 7; kt++)
            bb[b][kt] = *(const bf16x8*)(wxT + (size_t)(16 * b + l15) * kC + kt * 32 + quad * 8);
    __syncthreads();   // hisem walk + A-loads done before T write-back

#pragma unroll
    for (int ct = 0; ct < 14; ct++) {
        const int cur = ct & 3;
        const int nxt = (ct + 3) & 3;
        if (ct < 11) {
            const u16* bp = wxT + (size_t)((ct + 3) * 16 + l15) * kC + quad * 8;
#pragma unroll
            for (int kt = 0; kt < 7; kt++) bb[nxt][kt] = *(const bf16x8*)(bp + kt * 32);
        }
        f32x4 acc0 = {0.f, 0.f, 0.f, 0.f};
        f32x4 acc1 = {0.f, 0.f, 0.f, 0.f};
#pragma unroll
        for (int kt = 0; kt < 7; kt++) {
            acc0 = __builtin_amdgcn_mfma_f32_16x16x32_bf16(afr[0][kt], bb[cur][kt], acc0, 0, 0, 0);
            acc1 = __builtin_amdgcn_mfma_f32_16x16x32_bf16(afr[1][kt], bb[cur][kt], acc1, 0, 0, 0);
        }
        int colg = ct * 16 + l15;
#pragma unroll
        for (int s = 0; s < 2; s++) {
            f32x4 ac = s ? acc1 : acc0;
            int rbase = 32 * w + 16 * s + quad * 4;
            unsigned p01 = pk2(tanh_f(ac[0]), tanh_f(ac[1]));
            unsigned p23 = pk2(tanh_f(ac[2]), tanh_f(ac[3]));
            s_buf[rbase + 0][colg] = (u16)p01;
            s_buf[rbase + 1][colg] = (u16)(p01 >> 16);
            s_buf[rbase + 2][colg] = (u16)p23;
            s_buf[rbase + 3][colg] = (u16)(p23 >> 16);
        }
    }
    __syncthreads();

    // comb walk (windowed, b64 T reads, broadcast dir b128, float4 flushes)
    if (active_w) {
        float a0[4] = {0.f, 0.f, 0.f, 0.f};
        float a1[4] = {0.f, 0.f, 0.f, 0.f};
        float a2[4] = {0.f, 0.f, 0.f, 0.f};
        int rs = ws;
        for (int e = ws; e < we; e++) {
            if (s_node[e] != s_node[rs]) {
                bool comp = (rs > ws) || !contL;
                float* p = comp ? (nodeacc + (size_t)s_node[rs] * 896)
                                : (bpart + (size_t)(8 * blockIdx.x + 2 * w) * 896);
                *(float4*)&p[c0]       = make_float4(a0[0], a0[1], a0[2], a0[3]);
                *(float4*)&p[224 + c0] = make_float4(a1[0], a1[1], a1[2], a1[3]);
                *(float4*)&p[448 + c0] = make_float4(a2[0], a2[1], a2[2], a2[3]);
#pragma unroll
                for (int q = 0; q < 4; q++) { a0[q] = 0.f; a1[q] = 0.f; a2[q] = 0.f; }
                rs = e;
            }
            float4 dd = *(const float4*)&s_dir4[e][0];
            uint2 pv = *(const uint2*)&s_buf[e][c0];
            float Tv[4];
            Tv[0] = bf2f((u16)pv.x); Tv[1] = bf2f((u16)(pv.x >> 16));
            Tv[2] = bf2f((u16)pv.y); Tv[3] = bf2f((u16)(pv.y >> 16));
#pragma unroll
            for (int q = 0; q < 4; q++) {
                a0[q] += Tv[q] * dd.x;
                a1[q] += Tv[q] * dd.y;
                a2[q] += Tv[q] * dd.z;
            }
        }
        bool t0 = (rs == ws);
        bool comp = ((!t0) || !contL) && !contR;
        float* p;
        if (comp) p = nodeacc + (size_t)s_node[rs] * 896;
        else {
            int slot = (t0 && contL) ? 0 : 1;
            p = bpart + (size_t)(8 * blockIdx.x + 2 * w + slot) * 896;
        }
        *(float4*)&p[c0]       = make_float4(a0[0], a0[1], a0[2], a0[3]);
        *(float4*)&p[224 + c0] = make_float4(a1[0], a1[1], a1[2], a1[3]);
        *(float4*)&p[448 + c0] = make_float4(a2[0], a2[1], a2[2], a2[3]);
    }
}

// ---------------------------------------------------------------------------
// K5: node epilogue. 4 nodes/block; gather nodeacc/bpart (32-edge windows);
// MLPs with weight-value reuse across the 4 nodes.
// ---------------------------------------------------------------------------
__global__ __launch_bounds__(256) void node_kernel(
    const float* __restrict__ h, const float* __restrict__ x, const float* __restrict__ v,
    const float* __restrict__ nodeacc, const float* __restrict__ bpart,
    const int* __restrict__ bid, const int* __restrict__ offs,
    const float* __restrict__ w_n1, const float* __restrict__ b_n1,
    const float* __restrict__ w_n2, const float* __restrict__ b_n2,
    const float* __restrict__ w_pn1, const float* __restrict__ b_pn1,
    const float* __restrict__ w_pn2, const float* __restrict__ b_pn2,
    const float* __restrict__ w_v1, const float* __restrict__ b_v1,
    const float* __restrict__ w_v2, const float* __restrict__ w_vmix,
    float* __restrict__ out_h, float* __restrict__ out_x, float* __restrict__ out_v,
    int N_)
{
    __shared__ float s_cm[4][3][kC];
    __shared__ float s_cnsq[4][kC];
    __shared__ float s_ni[4][288];          // [h | hisem | spat]
    __shared__ float s_part[8][4][kF];
    __shared__ float s_hn[4][kF], s_sp1[4][kF], s_spat[4][kF], s_n1v[4][kF], s_g1[4][kF];
    __shared__ float s_pdv[4][3][8];
    __shared__ float s_gate[4], s_dv[4][3];

    int t = threadIdx.x;
    int n0 = blockIdx.x * 4;

    if (t < kC) {
        for (int nd = 0; nd < 4; nd++) {
            int node = n0 + nd;
            if (node >= N_) break;
            int base = offs[node], end = offs[node + 1];
            int deg = end - base;
            float a0 = 0.f, a1 = 0.f, a2 = 0.f, hh = 0.f;
            if (deg > 0) {
                int wlo = base >> 5, whi = (end - 1) >> 5;
                if (wlo == whi) {
                    const float* p = nodeacc + (size_t)node * 896;
                    a0 = p[t]; a1 = p[224 + t]; a2 = p[448 + t]; hh = p[672 + t];
                } else {
                    for (int W = wlo; W <= whi; W++) {
#pragma unroll
                        for (int s = 0; s < 2; s++) {
                            if (bid[2 * W + s] == node) {
                                const float* p = bpart + (size_t)(2 * W + s) * 896;
                                a0 += p[t]; a1 += p[224 + t]; a2 += p[448 + t]; hh += p[672 + t];
                            }
                        }
                    }
                }
            }
            float invc = 1.f / fmaxf((float)deg, 1.f);
            float m0 = a0 * invc, m1 = a1 * invc, m2 = a2 * invc;
            s_cm[nd][0][t] = m0; s_cm[nd][1][t] = m1; s_cm[nd][2][t] = m2;
            s_cnsq[nd][t] = m0 * m0 + m1 * m1 + m2 * m2;
            s_ni[nd][kF + t] = hh;
        }
    } else {
        int ln = t - 224;   // 0..31
        for (int nd = 0; nd < 4; nd++) {
            int node = n0 + nd;
            float hv = (node < N_) ? h[(size_t)node * kF + ln] : 0.f;
            s_hn[nd][ln] = hv;
            s_ni[nd][ln] = hv;
        }
    }
    __syncthreads();

    int o = t & 31, g = t >> 5;
    {   // pn1 partials, 4 nodes per weight load
        float acc[4] = {0.f, 0.f, 0.f, 0.f};
        int cb = g * 28;
        for (int i = 0; i < 28; i++) {
            float wv = w_pn1[(cb + i) * kF + o];
#pragma unroll
            for (int nd = 0; nd < 4; nd++) acc[nd] += s_cnsq[nd][cb + i] * wv;
        }
#pragma unroll
        for (int nd = 0; nd < 4; nd++) s_part[g][nd][o] = acc[nd];
    }
    __syncthreads();
    if (t < 128) {
        int nd = t >> 5;
        float a = b_pn1[o];
#pragma unroll
        for (int g2 = 0; g2 < 8; g2++) a += s_part[g2][nd][o];
        s_sp1[nd][o] = silu_f(a);
    } else {
        int nd = (t - 128) >> 5;
        float a = b_v1[o];
        for (int f = 0; f < kF; f++) a += s_hn[nd][f] * w_v1[f * kF + o];
        s_g1[nd][o] = silu_f(a);
    }
    __syncthreads();
    if (t < 128) {
        int nd = t >> 5;
        float a = b_pn2[o];
        for (int o2 = 0; o2 < kF; o2++) a += s_sp1[nd][o2] * w_pn2[o2 * kF + o];
        s_spat[nd][o] = silu_f(a);
    } else if (t < 132) {
        int nd = t - 128;
        float a = 0.f;
        for (int o2 = 0; o2 < kF; o2++) a += s_g1[nd][o2] * w_v2[o2];
        s_gate[nd] = 2.f / (1.f + __expf(-a));
    } else if (t >= 160) {   // 96 threads: dv partials
        int q = t - 160; int nd = q / 24; int r = q - nd * 24;
        int xx = r >> 3, ln = r & 7;
        float a = 0.f;
        for (int c = ln; c < kC; c += 8) a += w_vmix[c] * s_cm[nd][xx][c];
        s_pdv[nd][xx][ln] = a;
    }
    __syncthreads();
    if (t < 128) {
        int nd = t >> 5;
        s_ni[nd][kF + kC + o] = s_spat[nd][o];
    } else if (t < 140) {
        int q = t - 128; int nd = q / 3; int xx = q - nd * 3;
        float a = 0.f;
#pragma unroll
        for (int ln = 0; ln < 8; ln++) a += s_pdv[nd][xx][ln];
        s_dv[nd][xx] = a;
    }
    __syncthreads();
    {   // n1 partials: 8 groups x 36 rows
        float acc[4] = {0.f, 0.f, 0.f, 0.f};
        int rb = g * 36;
        for (int i = 0; i < 36; i++) {
            float wv = w_n1[(rb + i) * kF + o];
#pragma unroll
            for (int nd = 0; nd < 4; nd++) acc[nd] += s_ni[nd][rb + i] * wv;
        }
#pragma unroll
        for (int nd = 0; nd < 4; nd++) s_part[g][nd][o] = acc[nd];
    }
    __syncthreads();
    if (t < 128) {
        int nd = t >> 5;
        float a = b_n1[o];
#pragma unroll
        for (int g2 = 0; g2 < 8; g2++) a += s_part[g2][nd][o];
        s_n1v[nd][o] = silu_f(a);
    }
    __syncthreads();
    if (t < 128) {
        int nd = t >> 5; int node = n0 + nd;
        if (node < N_) {
            float a = b_n2[o];
            for (int o2 = 0; o2 < kF; o2++) a += s_n1v[nd][o2] * w_n2[o2 * kF + o];
            out_h[(size_t)node * kF + o] = s_hn[nd][o] + silu_f(a);
        }
    } else if (t < 140) {
        int q = t - 128; int nd = q / 3; int xx = q - nd * 3;
        int node = n0 + nd;
        if (node < N_) {
            float vv = v[(size_t)node * 3 + xx];
            float vu = s_gate[nd] * vv + s_dv[nd][xx];
            out_v[(size_t)node * 3 + xx] = vu;
            out_x[(size_t)node * 3 + xx] = x[(size_t)node * 3 + xx] + vu;
        }
    }
}

// ---------------------------------------------------------------------------
extern "C" void kernel_launch(void* const* d_in, const int* in_sizes, int n_in,
                              void* d_out, int out_size, void* d_ws, size_t ws_size,
                              hipStream_t stream)
{
    const float* h      = (const float*)d_in[0];
    const float* x      = (const float*)d_in[1];
    const float* v      = (const float*)d_in[2];
    const int*   pl     = (const int*)d_in[3];
    const float* w_in   = (const float*)d_in[4];
    const float* b_in   = (const float*)d_in[5];
    const float* w_e1   = (const float*)d_in[6];
    const float* b_e1   = (const float*)d_in[7];
    const float* w_e2   = (const float*)d_in[8];
    const float* b_e2   = (const float*)d_in[9];
    const float* w_att  = (const float*)d_in[10];
    const float* b_att  = (const float*)d_in[11];
    const float* w_n1   = (const float*)d_in[12];
    const float* b_n1   = (const float*)d_in[13];
    const float* w_n2   = (const float*)d_in[14];
    const float* b_n2   = (const float*)d_in[15];
    const float* w_pn1  = (const float*)d_in[16];
    const float* b_pn1  = (const float*)d_in[17];
    const float* w_pn2  = (const float*)d_in[18];
    const float* b_pn2  = (const float*)d_in[19];
    const float* w_v1   = (const float*)d_in[20];
    const float* b_v1   = (const float*)d_in[21];
    const float* w_v2   = (const float*)d_in[22];
    const float* w_xmix = (const float*)d_in[23];
    const float* w_vmix = (const float*)d_in[24];

    const int E_ = in_sizes[3] / 2;
    const int N_ = in_sizes[0] / kF;
    const int nblk = (E_ + kM - 1) / kM;

    // Workspace (~104 MB; 16B-aligned segments first)
    char* w = (char*)d_ws;
    u16*   wxT     = (u16*)w;   w += (size_t)kC * kC * 2;
    u16*   W1T     = (u16*)w;   w += (size_t)64 * 64 * 2;
    u16*   W2T     = (u16*)w;   w += (size_t)32 * 128 * 2;
    u16*   W3T     = (u16*)w;   w += (size_t)32 * 32 * 2;
    u16*   W24T    = (u16*)w;   w += (size_t)16 * 32 * 2;
    float* b24     = (float*)w; w += 8 * 4;
    u16*   he_g    = (u16*)w;   w += (size_t)E_ * kF * 2;
    float* logit_g = (float*)w; w += (size_t)E_ * kH * 4;
    float* dir_g   = (float*)w; w += (size_t)E_ * 3 * 4;
    float* m_g     = (float*)w; w += (size_t)N_ * kH * 4;
    float* invs_g  = (float*)w; w += (size_t)N_ * kH * 4;
    float* nodeacc = (float*)w; w += (size_t)N_ * 896 * 4;       // [N][4][224]
    float* bpart   = (float*)w; w += (size_t)8 * nblk * 896 * 4; // 4 win x 2 slots / blk
    int*   bid     = (int*)w;   w += (size_t)8 * nblk * 4;
    int* counts    = (int*)w;   w += (size_t)N_ * 4;
    int* offs      = (int*)w;   w += (size_t)(N_ + 1) * 4;
    int* cursor    = (int*)w;   w += (size_t)N_ * 4;
    int* nid       = (int*)w;   w += (size_t)E_ * 4;

    float* out_h = (float*)d_out;
    float* out_x = out_h + (size_t)N_ * kF;
    float* out_v = out_x + (size_t)N_ * 3;

    hipMemsetAsync(counts, 0, (size_t)N_ * 4, stream);
    hipMemsetAsync(cursor, 0, (size_t)N_ * 4, stream);

    init_kernel<<<dim3((kC * kC + 255) / 256), dim3(256), 0, stream>>>(
        w_xmix, w_in, w_e1, w_e2, w_att, b_e2, b_att, pl,
        wxT, W1T, W2T, W3T, W24T, b24, counts, E_);

    scan_kernel<<<dim3(1), dim3(1024), 0, stream>>>(counts, offs, N_);

    edge_kernel<<<dim3((E_ + kEM - 1) / kEM), dim3(256), 0, stream>>>(
        h, x, pl, offs, cursor, nid, E_, b_in, b_e1, b_e2,
        W1T, W2T, W3T, W24T, b24, he_g, logit_g, dir_g);

    stats_kernel<<<dim3((N_ + 7) / 8), dim3(256), 0, stream>>>(
        logit_g, offs, m_g, invs_g, N_);

    xmix_kernel<<<dim3(nblk), dim3(256), 0, stream>>>(
        he_g, logit_g, dir_g, nid, m_g, invs_g, wxT, E_,
        nodeacc, bpart, bid);

    node_kernel<<<dim3((N_ + 3) / 4), dim3(256), 0, stream>>>(
        h, x, v, nodeacc, bpart, bid, offs,
        w_n1, b_n1, w_n2, b_n2, w_pn1, b_pn1, w_pn2, b_pn2,
        w_v1, b_v1, w_v2, w_vmix, out_h, out_x, out_v, N_);
}

// Round 16
// 321.224 us; speedup vs baseline: 1.1543x; 1.0420x over previous
//
#include <hip/hip_runtime.h>
#include <hip/hip_bf16.h>
#include <math.h>

typedef unsigned short u16;
typedef __attribute__((ext_vector_type(8))) short bf16x8;
typedef __attribute__((ext_vector_type(4))) float f32x4;

// Problem constants (match reference)
constexpr int kF    = 32;    // nr_atom_basis
constexpr int kH    = 7;     // heads
constexpr int kC    = 224;   // F*H
constexpr int kRBF  = 50;
constexpr int kM    = 128;   // edges per xmix tile
constexpr int kStr  = 232;   // xmix LDS row stride (bf16; 464B, 16B-aligned)
constexpr int kUSt  = 36;    // U LDS row stride (u16; 72B, 8B-aligned)
constexpr int kEM   = 128;   // edges per edge-MFMA block
constexpr int kAStr = 136;   // edge A-tile stride (bf16; 272B, 16B-aligned)
constexpr int kBStr = 40;    // t1 tile stride (bf16; 80B, 16B-aligned)
constexpr float kCut = 5.0f;
constexpr float kEps = 1e-8f;

__device__ __forceinline__ float silu_f(float a) { return a / (1.f + __expf(-a)); }
__device__ __forceinline__ float tanh_f(float x) {
    float e = __expf(2.f * x);
    return 1.f - 2.f / (e + 1.f);
}
__device__ __forceinline__ float bf2f(u16 u) {
    union { unsigned int i; float f; } v; v.i = ((unsigned int)u) << 16; return v.f;
}
__device__ __forceinline__ u16 f2bf(float f) {
    union { float f; unsigned int i; } v; v.f = f;
    unsigned int x = v.i;
    unsigned int round = ((x >> 16) & 1u) + 0x7fffu;
    return (u16)((x + round) >> 16);
}
__device__ __forceinline__ unsigned pk2(float a, float b) {
    union { __hip_bfloat162 h; unsigned u; } v;
    v.h = __float22bfloat162_rn(make_float2(a, b));
    return v.u;
}

// ---------------------------------------------------------------------------
// K0: build wxT + edge-MLP B-matrices + Wn1hT; histogram of idx_i
// ---------------------------------------------------------------------------
__global__ __launch_bounds__(256) void init_kernel(
    const float* __restrict__ wx, const float* __restrict__ w_in,
    const float* __restrict__ w_e1, const float* __restrict__ w_e2,
    const float* __restrict__ w_att, const float* __restrict__ b_e2,
    const float* __restrict__ b_att, const float* __restrict__ w_n1,
    const int* __restrict__ pl,
    u16* __restrict__ wxT, u16* __restrict__ W1T, u16* __restrict__ W2T,
    u16* __restrict__ W3T, u16* __restrict__ W24T, u16* __restrict__ Wn1hT,
    float* __restrict__ b24, int* __restrict__ counts, int E_)
{
    int idx = blockIdx.x * 256 + threadIdx.x;
    if (idx < kC * kC) {
        int c = idx / kC, k = idx - c * kC;      // wxT[c][k] = wx[k][c]
        wxT[idx] = f2bf(wx[k * kC + c]);
    }
    for (int e = idx; e < E_; e += gridDim.x * 256) atomicAdd(&counts[pl[e]], 1);

    if (blockIdx.x == 0) {
        int t = threadIdx.x;
        for (int i = t; i < 64 * 64; i += 256) {
            int n = i >> 6, k = i & 63;
            W1T[i] = f2bf((n < kRBF) ? w_in[k * kRBF + n] : 0.f);
        }
        for (int i = t; i < 32 * 128; i += 256) {
            int n = i >> 7, k = i & 127;
            W2T[i] = f2bf((k < 115) ? w_e1[k * kF + n] : 0.f);
        }
        for (int i = t; i < 32 * 32; i += 256) {
            int n = i >> 5, k = i & 31;
            W3T[i] = f2bf(w_e2[k * kF + n]);
        }
        for (int i = t; i < 16 * 32; i += 256) {
            int n = i >> 5, k = i & 31;
            float a = 0.f;
            if (n < kH) for (int o = 0; o < kF; o++) a += w_e2[k * kF + o] * w_att[o * kH + n];
            W24T[i] = f2bf(a);
        }
        if (t < kH) {
            float a = b_att[t];
            for (int o = 0; o < kF; o++) a += b_e2[o] * w_att[o * kH + t];
            b24[t] = a;
        }
    }
    if (blockIdx.x == 1) {
        int t = threadIdx.x;
        for (int i = t; i < 32 * kC; i += 256) {   // Wn1hT[o][k] = w_n1[(kF+k)*kF+o]
            int o = i / kC, k = i - o * kC;
            Wn1hT[i] = f2bf(w_n1[(kF + k) * kF + o]);
        }
    }
}

// ---------------------------------------------------------------------------
// K1: exclusive scan, barrier-light
// ---------------------------------------------------------------------------
__global__ __launch_bounds__(1024) void scan_kernel(
    const int* __restrict__ counts, int* __restrict__ offsets, int n)
{
    __shared__ int buf[1024];
    int t = threadIdx.x;
    int chunk = (n + 1023) >> 10;
    int lo = t * chunk;
    int s = 0;
    for (int i = 0; i < chunk; i++) {
        int g = lo + i;
        if (g < n) s += counts[g];
    }
    buf[t] = s;
    __syncthreads();
    for (int off = 1; off < 1024; off <<= 1) {
        int v = (t >= off) ? buf[t - off] : 0;
        __syncthreads();
        buf[t] += v;
        __syncthreads();
    }
    int run = buf[t] - s;
    for (int i = 0; i < chunk; i++) {
        int g = lo + i;
        if (g < n) { offsets[g] = run; run += counts[g]; }
    }
    if (t == 1023) offsets[n] = buf[1023];
}

// ---------------------------------------------------------------------------
// K2: MFMA edge kernel; does the CSR scatter itself (cursor atomic -> pos),
// writes nid + he(bf16)/logit/dir at CSR position.
// ---------------------------------------------------------------------------
__global__ __launch_bounds__(256) void edge_kernel(
    const float* __restrict__ h, const float* __restrict__ x,
    const int* __restrict__ pl, const int* __restrict__ offs,
    int* __restrict__ cursor, int* __restrict__ nid, int E_,
    const float* __restrict__ b_in, const float* __restrict__ b_e1,
    const float* __restrict__ b_e2,
    const u16* __restrict__ W1T, const u16* __restrict__ W2T,
    const u16* __restrict__ W3T, const u16* __restrict__ W24T,
    const float* __restrict__ b24,
    u16* __restrict__ he_g, float* __restrict__ logit_g,
    float* __restrict__ dir_g)
{
    __shared__ __align__(16) u16 s_A[kEM][kAStr];
    __shared__ __align__(16) u16 s_t1[kEM][kBStr];
    __shared__ float s_d[kEM];
    __shared__ int   s_r[kEM];

    int t = threadIdx.x;
    int T0 = blockIdx.x * kEM;
    int w = t >> 6, lane = t & 63, quad = lane >> 4, l15 = lane & 15;

    {
        int e = t >> 1, half = t & 1;
        int ge = T0 + e;
        bool val = ge < E_;
        int i = 0, j = 0;
        if (val) { i = pl[ge]; j = pl[E_ + ge]; }
        const float4* pi = (const float4*)(h + (size_t)i * kF) + half * 4;
        const float4* pj = (const float4*)(h + (size_t)j * kF) + half * 4;
#pragma unroll
        for (int q = 0; q < 4; q++) {
            float4 a = val ? pi[q] : make_float4(0.f, 0.f, 0.f, 0.f);
            float4 b = val ? pj[q] : make_float4(0.f, 0.f, 0.f, 0.f);
            unsigned* di = (unsigned*)&s_A[e][half * 16 + 4 * q];
            di[0] = pk2(a.x, a.y); di[1] = pk2(a.z, a.w);
            unsigned* dj = (unsigned*)&s_A[e][kF + half * 16 + 4 * q];
            dj[0] = pk2(b.x, b.y); dj[1] = pk2(b.z, b.w);
        }
        if (half == 0) {
            float d = 0.f;
            int r = 0;
            if (val) {
                int p = atomicAdd(&cursor[i], 1);
                r = offs[i] + p;
                nid[r] = i;
                float r0 = x[j * 3 + 0] - x[i * 3 + 0];
                float r1 = x[j * 3 + 1] - x[i * 3 + 1];
                float r2 = x[j * 3 + 2] - x[i * 3 + 2];
                d = sqrtf(r0 * r0 + r1 * r1 + r2 * r2);
                float inv = 1.0f / (d + kEps);
                dir_g[(size_t)r * 3 + 0] = r0 * inv;
                dir_g[(size_t)r * 3 + 1] = r1 * inv;
                dir_g[(size_t)r * 3 + 2] = r2 * inv;
            }
            s_r[e] = r;
            s_d[e] = d;
            s_A[e][114] = f2bf(d);
            s_A[e][115] = 0;
            unsigned* z = (unsigned*)&s_A[e][116];
#pragma unroll
            for (int q = 0; q < 6; q++) z[q] = 0u;
        }
    }
    __syncthreads();

    const float invw = 49.0f / kCut;

    {   // GEMM1: h_cat @ w_in -> rbf -> filt
        bf16x8 a1[2][2];
#pragma unroll
        for (int rt = 0; rt < 2; rt++)
#pragma unroll
            for (int kt = 0; kt < 2; kt++)
                a1[rt][kt] = *(const bf16x8*)&s_A[32 * w + 16 * rt + l15][kt * 32 + quad * 8];
#pragma unroll
        for (int ct = 0; ct < 4; ct++) {
            int c = ct * 16 + l15;
            bf16x8 b0 = *(const bf16x8*)(W1T + (size_t)c * 64 + quad * 8);
            bf16x8 b1 = *(const bf16x8*)(W1T + (size_t)c * 64 + 32 + quad * 8);
            float bin = (c < kRBF) ? b_in[c] : 0.f;
#pragma unroll
            for (int rt = 0; rt < 2; rt++) {
                f32x4 acc = {0.f, 0.f, 0.f, 0.f};
                acc = __builtin_amdgcn_mfma_f32_16x16x32_bf16(a1[rt][0], b0, acc, 0, 0, 0);
                acc = __builtin_amdgcn_mfma_f32_16x16x32_bf16(a1[rt][1], b1, acc, 0, 0, 0);
                if (c < kRBF) {
#pragma unroll
                    for (int r = 0; r < 4; r++) {
                        int row = 32 * w + 16 * rt + quad * 4 + r;
                        float arg = s_d[row] * invw - (float)c;
                        float filt = __expf(-0.5f * arg * arg) * (acc[r] + bin);
                        s_A[row][64 + c] = f2bf(filt);
                    }
                }
            }
        }
    }

    {   // GEMM2: edge_in @ w_e1 -> silu -> t1
        bf16x8 a2[2][4];
#pragma unroll
        for (int rt = 0; rt < 2; rt++)
#pragma unroll
            for (int kt = 0; kt < 4; kt++)
                a2[rt][kt] = *(const bf16x8*)&s_A[32 * w + 16 * rt + l15][kt * 32 + quad * 8];
#pragma unroll
        for (int ct = 0; ct < 2; ct++) {
            int c = ct * 16 + l15;
            bf16x8 bb[4];
#pragma unroll
            for (int kt = 0; kt < 4; kt++)
                bb[kt] = *(const bf16x8*)(W2T + (size_t)c * 128 + kt * 32 + quad * 8);
            float be = b_e1[c];
#pragma unroll
            for (int rt = 0; rt < 2; rt++) {
                f32x4 acc = {0.f, 0.f, 0.f, 0.f};
#pragma unroll
                for (int kt = 0; kt < 4; kt++)
                    acc = __builtin_amdgcn_mfma_f32_16x16x32_bf16(a2[rt][kt], bb[kt], acc, 0, 0, 0);
#pragma unroll
                for (int r = 0; r < 4; r++) {
                    int row = 32 * w + 16 * rt + quad * 4 + r;
                    s_t1[row][c] = f2bf(silu_f(acc[r] + be));
                }
            }
        }
    }

    {   // GEMM3 (he, bf16 out) + GEMM4 (logits)
        bf16x8 a3[2];
#pragma unroll
        for (int rt = 0; rt < 2; rt++)
            a3[rt] = *(const bf16x8*)&s_t1[32 * w + 16 * rt + l15][quad * 8];

#pragma unroll
        for (int ct = 0; ct < 2; ct++) {
            int c = ct * 16 + l15;
            bf16x8 b3 = *(const bf16x8*)(W3T + (size_t)c * 32 + quad * 8);
            float be = b_e2[c];
#pragma unroll
            for (int rt = 0; rt < 2; rt++) {
                f32x4 acc = {0.f, 0.f, 0.f, 0.f};
                acc = __builtin_amdgcn_mfma_f32_16x16x32_bf16(a3[rt], b3, acc, 0, 0, 0);
#pragma unroll
                for (int r = 0; r < 4; r++) {
                    int row = 32 * w + 16 * rt + quad * 4 + r;
                    int ge = T0 + row;
                    if (ge < E_) he_g[(size_t)s_r[row] * kF + c] = f2bf(acc[r] + be);
                }
            }
        }
        {
            bf16x8 b4 = *(const bf16x8*)(W24T + (size_t)l15 * 32 + quad * 8);
            float bb = (l15 < kH) ? b24[l15] : 0.f;
#pragma unroll
            for (int rt = 0; rt < 2; rt++) {
                f32x4 acc = {0.f, 0.f, 0.f, 0.f};
                acc = __builtin_amdgcn_mfma_f32_16x16x32_bf16(a3[rt], b4, acc, 0, 0, 0);
                if (l15 < kH) {
#pragma unroll
                    for (int r = 0; r < 4; r++) {
                        int row = 32 * w + 16 * rt + quad * 4 + r;
                        int ge = T0 + row;
                        if (ge < E_) {
                            float a = acc[r] + bb;
                            a = (a >= 0.f) ? a : 2.f * (__expf(0.5f * a) - 1.f);
                            float dd = s_d[row];
                            float cut = (dd < kCut)
                                ? 0.5f * (__cosf(0.62831853071795864f * dd) + 1.f) : 0.f;
                            logit_g[(size_t)s_r[row] * kH + l15] = a * cut;
                        }
                    }
                }
            }
        }
    }
}

// ---------------------------------------------------------------------------
// K3: per-node softmax stats (32-lane group per node, 8 nodes/block)
// ---------------------------------------------------------------------------
__global__ __launch_bounds__(256) void stats_kernel(
    const float* __restrict__ logit_g, const int* __restrict__ offsets,
    float* __restrict__ m_g, float* __restrict__ invs_g, int N_)
{
    int grp  = threadIdx.x >> 5;
    int lane = threadIdx.x & 31;
    int node = blockIdx.x * 8 + grp;
    if (node >= N_) return;
    int base = offsets[node];
    int deg  = offsets[node + 1] - base;

    float m[kH], ss[kH];
#pragma unroll
    for (int hh = 0; hh < kH; hh++) { m[hh] = -1e30f; ss[hh] = 0.f; }
    for (int e = lane; e < deg; e += 32) {
        const float* lp = logit_g + (size_t)(base + e) * kH;
#pragma unroll
        for (int hh = 0; hh < kH; hh++) {
            float vv = lp[hh];
            if (vv > m[hh]) { ss[hh] *= __expf(m[hh] - vv); m[hh] = vv; }
            ss[hh] += __expf(vv - m[hh]);
        }
    }
#pragma unroll
    for (int hh = 0; hh < kH; hh++) {
        float mm = m[hh], s2 = ss[hh];
#pragma unroll
        for (int off = 16; off >= 1; off >>= 1) {
            float mo = __shfl_xor(mm, off);
            float so = __shfl_xor(s2, off);
            float mn = fmaxf(mm, mo);
            s2 = s2 * __expf(mm - mn) + so * __expf(mo - mn);
            mm = mn;
        }
        if (lane == 0) {
            m_g[(size_t)node * kH + hh] = mm;
            invs_g[(size_t)node * kH + hh] = (s2 > 0.f) ? 1.f / s2 : 0.f;
        }
    }
}

// ---------------------------------------------------------------------------
// K4: MFMA xmix. T = tanh(sem@wx) AND U = sem@Wn1h (hisem folded into MFMA).
// Depth-2 B prefetch; barriers minimized (post-sem s_buf rows are wave-private).
// Merged comb+U walk; boundary runs -> bpart (layout unchanged).
// ---------------------------------------------------------------------------
__global__ __launch_bounds__(256) void xmix_kernel(
    const u16* __restrict__ he_g, const float* __restrict__ logit_g,
    const float* __restrict__ dir_g, const int* __restrict__ nid,
    const float* __restrict__ m_g, const float* __restrict__ invs_g,
    const u16* __restrict__ wxT, const u16* __restrict__ Wn1hT, int E_,
    float* __restrict__ nodeacc, float* __restrict__ bpart, int* __restrict__ bid)
{
    __shared__ __align__(16) u16 s_buf[kM][kStr];   // sem, then T
    __shared__ __align__(8)  u16 s_U[kM][kUSt];     // U (bf16), 9216 B
    __shared__ float s_att[kM][kH];
    __shared__ __align__(16) float s_dir4[kM][4];
    __shared__ int   s_node[kM];
    __shared__ int   s_prev, s_next;

    int t = threadIdx.x;
    int T0 = blockIdx.x * kM;
    int cp = min(kM, E_ - T0);

    if (t < kM) s_node[t] = (T0 + t < E_) ? nid[T0 + t] : -1;
    if (t == 0) {
        s_prev = (T0 > 0) ? nid[T0 - 1] : -2;
        s_next = (T0 + cp < E_) ? nid[T0 + cp] : -2;
    }
    __syncthreads();

    int w    = t >> 6;
    int lane = t & 63;
    int quad = lane >> 4;
    int l15  = lane & 15;

    // ---- per-wave window params ----
    int ws = 32 * w;
    int we = min(ws + 32, cp);
    bool winvalid = (ws < cp);
    bool contL = false, contR = false;
    if (winvalid) {
        int nfirst = s_node[ws], nlast = s_node[we - 1];
        contL = (w == 0) ? (s_prev == nfirst) : (s_node[ws - 1] == nfirst);
        contR = (we == cp) ? (s_next == nlast) : (s_node[we] == nlast);
    }
    if (lane == 0) {
        int b0 = -1, b1 = -1;
        if (winvalid) {
            int nfirst = s_node[ws], nlast = s_node[we - 1];
            b0 = contL ? nfirst : -1;
            if (contR && !(nfirst == nlast && contL)) b1 = nlast;
        }
        bid[8 * blockIdx.x + 2 * w + 0] = b0;
        bid[8 * blockIdx.x + 2 * w + 1] = b1;
    }
    bool active_w = winvalid && (lane < 56);
    int c0 = 4 * lane;

    for (int idx = t; idx < kM * kH; idx += 256) {
        int e = idx / kH, hh = idx - e * kH;
        float a = 0.f;
        if (T0 + e < E_) {
            int nd = s_node[e];
            a = __expf(logit_g[(size_t)(T0 + e) * kH + hh] - m_g[(size_t)nd * kH + hh])
                * invs_g[(size_t)nd * kH + hh];
        }
        s_att[e][hh] = a;
    }
    for (int idx = t; idx < cp * 3; idx += 256) {
        int e = idx / 3, xx = idx - e * 3;
        s_dir4[e][xx] = dir_g[(size_t)(T0 + e) * 3 + xx];
    }
    __syncthreads();

    // sem build (bf16, hw pack); he reads coalesced (bf16)
#pragma unroll
    for (int p = 0; p < kM * kF / 256; p++) {
        int idx = t + 256 * p;
        int e = idx >> 5, f = idx & 31;
        float hv = (T0 + e < E_) ? bf2f(he_g[(size_t)(T0 + e) * kF + f]) : 0.f;
        float sv[7];
#pragma unroll
        for (int hh = 0; hh < kH; hh++) sv[hh] = hv * s_att[e][hh];
        u16* dst = &s_buf[e][f * 7];
        if ((f & 1) == 0) {
            *(unsigned*)(dst)     = pk2(sv[0], sv[1]);
            *(unsigned*)(dst + 2) = pk2(sv[2], sv[3]);
            *(unsigned*)(dst + 4) = pk2(sv[4], sv[5]);
            dst[6] = f2bf(sv[6]);
        } else {
            dst[0] = f2bf(sv[0]);
            *(unsigned*)(dst + 1) = pk2(sv[1], sv[2]);
            *(unsigned*)(dst + 3) = pk2(sv[3], sv[4]);
            *(unsigned*)(dst + 5) = pk2(sv[5], sv[6]);
        }
    }
    __syncthreads();
    // After this barrier all s_buf/s_U traffic is wave-private (rows 32w..32w+32).

    // MFMA fragments: wave w owns rows [32w, 32w+32)
    bf16x8 afr[2][7];
#pragma unroll
    for (int rt = 0; rt < 2; rt++)
#pragma unroll
        for (int kt = 0; kt < 7; kt++)
            afr[rt][kt] = *(const bf16x8*)&s_buf[32 * w + 16 * rt + l15][kt * 32 + quad * 8];

    // triple-buffered B prefetch (depth 2) — r14-proven
    bf16x8 bb[3][7];
#pragma unroll
    for (int kt = 0; kt < 7; kt++)
        bb[0][kt] = *(const bf16x8*)(wxT + (size_t)l15 * kC + kt * 32 + quad * 8);
#pragma unroll
    for (int kt = 0; kt < 7; kt++)
        bb[1][kt] = *(const bf16x8*)(wxT + (size_t)(16 + l15) * kC + kt * 32 + quad * 8);

#pragma unroll
    for (int ct = 0; ct < 14; ct++) {
        const int cur = ct % 3;
        const int nxt = (ct + 2) % 3;
        if (ct < 12) {
            const u16* bp = wxT + (size_t)((ct + 2) * 16 + l15) * kC + quad * 8;
#pragma unroll
            for (int kt = 0; kt < 7; kt++) bb[nxt][kt] = *(const bf16x8*)(bp + kt * 32);
        }
        f32x4 acc0 = {0.f, 0.f, 0.f, 0.f};
        f32x4 acc1 = {0.f, 0.f, 0.f, 0.f};
#pragma unroll
        for (int kt = 0; kt < 7; kt++) {
            acc0 = __builtin_amdgcn_mfma_f32_16x16x32_bf16(afr[0][kt], bb[cur][kt], acc0, 0, 0, 0);
            acc1 = __builtin_amdgcn_mfma_f32_16x16x32_bf16(afr[1][kt], bb[cur][kt], acc1, 0, 0, 0);
        }
        int colg = ct * 16 + l15;
#pragma unroll
        for (int s = 0; s < 2; s++) {
            f32x4 ac = s ? acc1 : acc0;
            int rbase = 32 * w + 16 * s + quad * 4;
            unsigned p01 = pk2(tanh_f(ac[0]), tanh_f(ac[1]));
            unsigned p23 = pk2(tanh_f(ac[2]), tanh_f(ac[3]));
            s_buf[rbase + 0][colg] = (u16)p01;
            s_buf[rbase + 1][colg] = (u16)(p01 >> 16);
            s_buf[rbase + 2][colg] = (u16)p23;
            s_buf[rbase + 3][colg] = (u16)(p23 >> 16);
        }
    }

    // U = sem @ Wn1h  (2 col-tiles, no tanh) -> s_U (wave-private rows)
#pragma unroll
    for (int ut = 0; ut < 2; ut++) {
        bf16x8 ub[7];
        const u16* bp = Wn1hT + (size_t)(ut * 16 + l15) * kC + quad * 8;
#pragma unroll
        for (int kt = 0; kt < 7; kt++) ub[kt] = *(const bf16x8*)(bp + kt * 32);
        f32x4 acc0 = {0.f, 0.f, 0.f, 0.f};
        f32x4 acc1 = {0.f, 0.f, 0.f, 0.f};
#pragma unroll
        for (int kt = 0; kt < 7; kt++) {
            acc0 = __builtin_amdgcn_mfma_f32_16x16x32_bf16(afr[0][kt], ub[kt], acc0, 0, 0, 0);
            acc1 = __builtin_amdgcn_mfma_f32_16x16x32_bf16(afr[1][kt], ub[kt], acc1, 0, 0, 0);
        }
        int ucol = ut * 16 + l15;
#pragma unroll
        for (int s = 0; s < 2; s++) {
            f32x4 ac = s ? acc1 : acc0;
            int rbase = 32 * w + 16 * s + quad * 4;
#pragma unroll
            for (int r = 0; r < 4; r++) s_U[rbase + r][ucol] = f2bf(ac[r]);
        }
    }
    // No barrier needed: walk below reads only this wave's rows.

    // merged comb + U walk (windowed; b64 T reads, b64 U reads on lanes 0-7)
    if (active_w) {
        bool uact = (lane < 8);
        float a0[4] = {0.f, 0.f, 0.f, 0.f};
        float a1[4] = {0.f, 0.f, 0.f, 0.f};
        float a2[4] = {0.f, 0.f, 0.f, 0.f};
        float uu[4] = {0.f, 0.f, 0.f, 0.f};
        int rs = ws;
        for (int e = ws; e < we; e++) {
            if (s_node[e] != s_node[rs]) {
                bool comp = (rs > ws) || !contL;
                float* p = comp ? (nodeacc + (size_t)s_node[rs] * 896)
                                : (bpart + (size_t)(8 * blockIdx.x + 2 * w) * 896);
                *(float4*)&p[c0]       = make_float4(a0[0], a0[1], a0[2], a0[3]);
                *(float4*)&p[224 + c0] = make_float4(a1[0], a1[1], a1[2], a1[3]);
                *(float4*)&p[448 + c0] = make_float4(a2[0], a2[1], a2[2], a2[3]);
                if (uact) *(float4*)&p[672 + c0] = make_float4(uu[0], uu[1], uu[2], uu[3]);
#pragma unroll
                for (int q = 0; q < 4; q++) { a0[q] = 0.f; a1[q] = 0.f; a2[q] = 0.f; uu[q] = 0.f; }
                rs = e;
            }
            float4 dd = *(const float4*)&s_dir4[e][0];
            uint2 pv = *(const uint2*)&s_buf[e][c0];
            float Tv[4];
            Tv[0] = bf2f((u16)pv.x); Tv[1] = bf2f((u16)(pv.x >> 16));
            Tv[2] = bf2f((u16)pv.y); Tv[3] = bf2f((u16)(pv.y >> 16));
#pragma unroll
            for (int q = 0; q < 4; q++) {
                a0[q] += Tv[q] * dd.x;
                a1[q] += Tv[q] * dd.y;
                a2[q] += Tv[q] * dd.z;
            }
            if (uact) {
                uint2 uv = *(const uint2*)&s_U[e][c0];
                uu[0] += bf2f((u16)uv.x); uu[1] += bf2f((u16)(uv.x >> 16));
                uu[2] += bf2f((u16)uv.y); uu[3] += bf2f((u16)(uv.y >> 16));
            }
        }
        bool t0 = (rs == ws);
        bool comp = ((!t0) || !contL) && !contR;
        float* p;
        if (comp) p = nodeacc + (size_t)s_node[rs] * 896;
        else {
            int slot = (t0 && contL) ? 0 : 1;
            p = bpart + (size_t)(8 * blockIdx.x + 2 * w + slot) * 896;
        }
        *(float4*)&p[c0]       = make_float4(a0[0], a0[1], a0[2], a0[3]);
        *(float4*)&p[224 + c0] = make_float4(a1[0], a1[1], a1[2], a1[3]);
        *(float4*)&p[448 + c0] = make_float4(a2[0], a2[1], a2[2], a2[3]);
        if (uact) *(float4*)&p[672 + c0] = make_float4(uu[0], uu[1], uu[2], uu[3]);
    }
}

// ---------------------------------------------------------------------------
// K5: node epilogue. 4 nodes/block; gather nodeacc/bpart; MLPs with
// weight-value reuse; n1 uses folded U (32-wide) instead of hisem (224).
// ---------------------------------------------------------------------------
__global__ __launch_bounds__(256) void node_kernel(
    const float* __restrict__ h, const float* __restrict__ x, const float* __restrict__ v,
    const float* __restrict__ nodeacc, const float* __restrict__ bpart,
    const int* __restrict__ bid, const int* __restrict__ offs,
    const float* __restrict__ w_n1, const float* __restrict__ b_n1,
    const float* __restrict__ w_n2, const float* __restrict__ b_n2,
    const float* __restrict__ w_pn1, const float* __restrict__ b_pn1,
    const float* __restrict__ w_pn2, const float* __restrict__ b_pn2,
    const float* __restrict__ w_v1, const float* __restrict__ b_v1,
    const float* __restrict__ w_v2, const float* __restrict__ w_vmix,
    float* __restrict__ out_h, float* __restrict__ out_x, float* __restrict__ out_v,
    int N_)
{
    __shared__ float s_cm[4][3][kC];
    __shared__ float s_cnsq[4][kC];
    __shared__ float s_ni[4][64];           // [h | spat]
    __shared__ float s_usum[4][kF];
    __shared__ float s_part[8][4][kF];
    __shared__ float s_hn[4][kF], s_sp1[4][kF], s_spat[4][kF], s_n1v[4][kF], s_g1[4][kF];
    __shared__ float s_pdv[4][3][8];
    __shared__ float s_gate[4], s_dv[4][3];

    int t = threadIdx.x;
    int n0 = blockIdx.x * 4;

    if (t < kC) {
        for (int nd = 0; nd < 4; nd++) {
            int node = n0 + nd;
            if (node >= N_) break;
            int base = offs[node], end = offs[node + 1];
            int deg = end - base;
            float a0 = 0.f, a1 = 0.f, a2 = 0.f, hh = 0.f;
            if (deg > 0) {
                int wlo = base >> 5, whi = (end - 1) >> 5;
                if (wlo == whi) {
                    const float* p = nodeacc + (size_t)node * 896;
                    a0 = p[t]; a1 = p[224 + t]; a2 = p[448 + t];
                    if (t < kF) hh = p[672 + t];
                } else {
                    for (int W = wlo; W <= whi; W++) {
#pragma unroll
                        for (int s = 0; s < 2; s++) {
                            if (bid[2 * W + s] == node) {
                                const float* p = bpart + (size_t)(2 * W + s) * 896;
                                a0 += p[t]; a1 += p[224 + t]; a2 += p[448 + t];
                                if (t < kF) hh += p[672 + t];
                            }
                        }
                    }
                }
            }
            float invc = 1.f / fmaxf((float)deg, 1.f);
            float m0 = a0 * invc, m1 = a1 * invc, m2 = a2 * invc;
            s_cm[nd][0][t] = m0; s_cm[nd][1][t] = m1; s_cm[nd][2][t] = m2;
            s_cnsq[nd][t] = m0 * m0 + m1 * m1 + m2 * m2;
            if (t < kF) s_usum[nd][t] = hh;
        }
    } else {
        int ln = t - 224;   // 0..31
        for (int nd = 0; nd < 4; nd++) {
            int node = n0 + nd;
            float hv = (node < N_) ? h[(size_t)node * kF + ln] : 0.f;
            s_hn[nd][ln] = hv;
            s_ni[nd][ln] = hv;
        }
    }
    __syncthreads();

    int o = t & 31, g = t >> 5;
    {   // pn1 partials, 4 nodes per weight load
        float acc[4] = {0.f, 0.f, 0.f, 0.f};
        int cb = g * 28;
        for (int i = 0; i < 28; i++) {
            float wv = w_pn1[(cb + i) * kF + o];
#pragma unroll
            for (int nd = 0; nd < 4; nd++) acc[nd] += s_cnsq[nd][cb + i] * wv;
        }
#pragma unroll
        for (int nd = 0; nd < 4; nd++) s_part[g][nd][o] = acc[nd];
    }
    __syncthreads();
    if (t < 128) {
        int nd = t >> 5;
        float a = b_pn1[o];
#pragma unroll
        for (int g2 = 0; g2 < 8; g2++) a += s_part[g2][nd][o];
        s_sp1[nd][o] = silu_f(a);
    } else {
        int nd = (t - 128) >> 5;
        float a = b_v1[o];
        for (int f = 0; f < kF; f++) a += s_hn[nd][f] * w_v1[f * kF + o];
        s_g1[nd][o] = silu_f(a);
    }
    __syncthreads();
    if (t < 128) {
        int nd = t >> 5;
        float a = b_pn2[o];
        for (int o2 = 0; o2 < kF; o2++) a += s_sp1[nd][o2] * w_pn2[o2 * kF + o];
        s_spat[nd][o] = silu_f(a);
    } else if (t < 132) {
        int nd = t - 128;
        float a = 0.f;
        for (int o2 = 0; o2 < kF; o2++) a += s_g1[nd][o2] * w_v2[o2];
        s_gate[nd] = 2.f / (1.f + __expf(-a));
    } else if (t >= 160) {   // 96 threads: dv partials
        int q = t - 160; int nd = q / 24; int r = q - nd * 24;
        int xx = r >> 3, ln = r & 7;
        float a = 0.f;
        for (int c = ln; c < kC; c += 8) a += w_vmix[c] * s_cm[nd][xx][c];
        s_pdv[nd][xx][ln] = a;
    }
    __syncthreads();
    if (t < 128) {
        int nd = t >> 5;
        s_ni[nd][kF + o] = s_spat[nd][o];
    } else if (t < 140) {
        int q = t - 128; int nd = q / 3; int xx = q - nd * 3;
        float a = 0.f;
#pragma unroll
        for (int ln = 0; ln < 8; ln++) a += s_pdv[nd][xx][ln];
        s_dv[nd][xx] = a;
    }
    __syncthreads();
    {   // n1 partials: 8 groups x 8 rows over [h | spat] (w_n1 rows 0..31, 256..287)
        float acc[4] = {0.f, 0.f, 0.f, 0.f};
        int rb = g * 8;
        for (int i = 0; i < 8; i++) {
            int r = rb + i;
            int wr = (r < kF) ? r : (r + kC);
            float wv = w_n1[wr * kF + o];
#pragma unroll
            for (int nd = 0; nd < 4; nd++) acc[nd] += s_ni[nd][r] * wv;
        }
#pragma unroll
        for (int nd = 0; nd < 4; nd++) s_part[g][nd][o] = acc[nd];
    }
    __syncthreads();
    if (t < 128) {
        int nd = t >> 5;
        float a = b_n1[o] + s_usum[nd][o];
#pragma unroll
        for (int g2 = 0; g2 < 8; g2++) a += s_part[g2][nd][o];
        s_n1v[nd][o] = silu_f(a);
    }
    __syncthreads();
    if (t < 128) {
        int nd = t >> 5; int node = n0 + nd;
        if (node < N_) {
            float a = b_n2[o];
            for (int o2 = 0; o2 < kF; o2++) a += s_n1v[nd][o2] * w_n2[o2 * kF + o];
            out_h[(size_t)node * kF + o] = s_hn[nd][o] + silu_f(a);
        }
    } else if (t < 140) {
        int q = t - 128; int nd = q / 3; int xx = q - nd * 3;
        int node = n0 + nd;
        if (node < N_) {
            float vv = v[(size_t)node * 3 + xx];
            float vu = s_gate[nd] * vv + s_dv[nd][xx];
            out_v[(size_t)node * 3 + xx] = vu;
            out_x[(size_t)node * 3 + xx] = x[(size_t)node * 3 + xx] + vu;
        }
    }
}

// ---------------------------------------------------------------------------
extern "C" void kernel_launch(void* const* d_in, const int* in_sizes, int n_in,
                              void* d_out, int out_size, void* d_ws, size_t ws_size,
                              hipStream_t stream)
{
    const float* h      = (const float*)d_in[0];
    const float* x      = (const float*)d_in[1];
    const float* v      = (const float*)d_in[2];
    const int*   pl     = (const int*)d_in[3];
    const float* w_in   = (const float*)d_in[4];
    const float* b_in   = (const float*)d_in[5];
    const float* w_e1   = (const float*)d_in[6];
    const float* b_e1   = (const float*)d_in[7];
    const float* w_e2   = (const float*)d_in[8];
    const float* b_e2   = (const float*)d_in[9];
    const float* w_att  = (const float*)d_in[10];
    const float* b_att  = (const float*)d_in[11];
    const float* w_n1   = (const float*)d_in[12];
    const float* b_n1   = (const float*)d_in[13];
    const float* w_n2   = (const float*)d_in[14];
    const float* b_n2   = (const float*)d_in[15];
    const float* w_pn1  = (const float*)d_in[16];
    const float* b_pn1  = (const float*)d_in[17];
    const float* w_pn2  = (const float*)d_in[18];
    const float* b_pn2  = (const float*)d_in[19];
    const float* w_v1   = (const float*)d_in[20];
    const float* b_v1   = (const float*)d_in[21];
    const float* w_v2   = (const float*)d_in[22];
    const float* w_xmix = (const float*)d_in[23];
    const float* w_vmix = (const float*)d_in[24];

    const int E_ = in_sizes[3] / 2;
    const int N_ = in_sizes[0] / kF;
    const int nblk = (E_ + kM - 1) / kM;

    // Workspace (~104 MB; 16B-aligned segments first)
    char* w = (char*)d_ws;
    u16*   wxT     = (u16*)w;   w += (size_t)kC * kC * 2;
    u16*   W1T     = (u16*)w;   w += (size_t)64 * 64 * 2;
    u16*   W2T     = (u16*)w;   w += (size_t)32 * 128 * 2;
    u16*   W3T     = (u16*)w;   w += (size_t)32 * 32 * 2;
    u16*   W24T    = (u16*)w;   w += (size_t)16 * 32 * 2;
    u16*   Wn1hT   = (u16*)w;   w += (size_t)32 * kC * 2;
    float* b24     = (float*)w; w += 8 * 4;
    u16*   he_g    = (u16*)w;   w += (size_t)E_ * kF * 2;
    float* logit_g = (float*)w; w += (size_t)E_ * kH * 4;
    float* dir_g   = (float*)w; w += (size_t)E_ * 3 * 4;
    float* m_g     = (float*)w; w += (size_t)N_ * kH * 4;
    float* invs_g  = (float*)w; w += (size_t)N_ * kH * 4;
    float* nodeacc = (float*)w; w += (size_t)N_ * 896 * 4;       // [N][4][224] (slot3: U, 32 used)
    float* bpart   = (float*)w; w += (size_t)8 * nblk * 896 * 4; // 4 win x 2 slots / blk
    int*   bid     = (int*)w;   w += (size_t)8 * nblk * 4;
    int* counts    = (int*)w;   w += (size_t)N_ * 4;
    int* offs      = (int*)w;   w += (size_t)(N_ + 1) * 4;
    int* cursor    = (int*)w;   w += (size_t)N_ * 4;
    int* nid       = (int*)w;   w += (size_t)E_ * 4;

    float* out_h = (float*)d_out;
    float* out_x = out_h + (size_t)N_ * kF;
    float* out_v = out_x + (size_t)N_ * 3;

    hipMemsetAsync(counts, 0, (size_t)N_ * 4, stream);
    hipMemsetAsync(cursor, 0, (size_t)N_ * 4, stream);

    init_kernel<<<dim3((kC * kC + 255) / 256), dim3(256), 0, stream>>>(
        w_xmix, w_in, w_e1, w_e2, w_att, b_e2, b_att, w_n1, pl,
        wxT, W1T, W2T, W3T, W24T, Wn1hT, b24, counts, E_);

    scan_kernel<<<dim3(1), dim3(1024), 0, stream>>>(counts, offs, N_);

    edge_kernel<<<dim3((E_ + kEM - 1) / kEM), dim3(256), 0, stream>>>(
        h, x, pl, offs, cursor, nid, E_, b_in, b_e1, b_e2,
        W1T, W2T, W3T, W24T, b24, he_g, logit_g, dir_g);

    stats_kernel<<<dim3((N_ + 7) / 8), dim3(256), 0, stream>>>(
        logit_g, offs, m_g, invs_g, N_);

    xmix_kernel<<<dim3(nblk), dim3(256), 0, stream>>>(
        he_g, logit_g, dir_g, nid, m_g, invs_g, wxT, Wn1hT, E_,
        nodeacc, bpart, bid);

    node_kernel<<<dim3((N_ + 3) / 4), dim3(256), 0, stream>>>(
        h, x, v, nodeacc, bpart, bid, offs,
        w_n1, b_n1, w_n2, b_n2, w_pn1, b_pn1, w_pn2, b_pn2,
        w_v1, b_v1, w_v2, w_vmix, out_h, out_x, out_v, N_);
}

// Round 18
// 319.207 us; speedup vs baseline: 1.1616x; 1.0063x over previous
//
#include <hip/hip_runtime.h>
#include <hip/hip_bf16.h>
#include <math.h>

typedef unsigned short u16;
typedef __attribute__((ext_vector_type(8))) short bf16x8;
typedef __attribute__((ext_vector_type(4))) float f32x4;

// Problem constants (match reference)
constexpr int kF    = 32;    // nr_atom_basis
constexpr int kH    = 7;     // heads
constexpr int kC    = 224;   // F*H
constexpr int kRBF  = 50;
constexpr int kM    = 128;   // edges per xmix tile
constexpr int kStr  = 232;   // xmix LDS row stride (bf16; 464B, 16B-aligned)
constexpr int kUSt  = 36;    // U LDS row stride (u16; 72B, 8B-aligned)
constexpr int kEM   = 128;   // edges per edge-MFMA block
constexpr int kAStr = 136;   // edge A-tile stride (bf16; 272B, 16B-aligned)
constexpr int kBStr = 40;    // t1 tile stride (bf16; 80B, 16B-aligned)
constexpr float kCut = 5.0f;
constexpr float kEps = 1e-8f;

__device__ __forceinline__ float silu_f(float a) { return a / (1.f + __expf(-a)); }
__device__ __forceinline__ float tanh_f(float x) {
    float e = __expf(2.f * x);
    return 1.f - 2.f / (e + 1.f);
}
__device__ __forceinline__ float bf2f(u16 u) {
    union { unsigned int i; float f; } v; v.i = ((unsigned int)u) << 16; return v.f;
}
__device__ __forceinline__ u16 f2bf(float f) {
    union { float f; unsigned int i; } v; v.f = f;
    unsigned int x = v.i;
    unsigned int round = ((x >> 16) & 1u) + 0x7fffu;
    return (u16)((x + round) >> 16);
}
__device__ __forceinline__ unsigned pk2(float a, float b) {
    union { __hip_bfloat162 h; unsigned u; } v;
    v.h = __float22bfloat162_rn(make_float2(a, b));
    return v.u;
}

// ---------------------------------------------------------------------------
// K0: build wxT + edge-MLP B-matrices + Wn1hT; histogram of idx_i
// ---------------------------------------------------------------------------
__global__ __launch_bounds__(256) void init_kernel(
    const float* __restrict__ wx, const float* __restrict__ w_in,
    const float* __restrict__ w_e1, const float* __restrict__ w_e2,
    const float* __restrict__ w_att, const float* __restrict__ b_e2,
    const float* __restrict__ b_att, const float* __restrict__ w_n1,
    const int* __restrict__ pl,
    u16* __restrict__ wxT, u16* __restrict__ W1T, u16* __restrict__ W2T,
    u16* __restrict__ W3T, u16* __restrict__ W24T, u16* __restrict__ Wn1hT,
    float* __restrict__ b24, int* __restrict__ counts, int E_)
{
    int idx = blockIdx.x * 256 + threadIdx.x;
    if (idx < kC * kC) {
        int c = idx / kC, k = idx - c * kC;      // wxT[c][k] = wx[k][c]
        wxT[idx] = f2bf(wx[k * kC + c]);
    }
    for (int e = idx; e < E_; e += gridDim.x * 256) atomicAdd(&counts[pl[e]], 1);

    if (blockIdx.x == 0) {
        int t = threadIdx.x;
        for (int i = t; i < 64 * 64; i += 256) {
            int n = i >> 6, k = i & 63;
            W1T[i] = f2bf((n < kRBF) ? w_in[k * kRBF + n] : 0.f);
        }
        for (int i = t; i < 32 * 128; i += 256) {
            int n = i >> 7, k = i & 127;
            W2T[i] = f2bf((k < 115) ? w_e1[k * kF + n] : 0.f);
        }
        for (int i = t; i < 32 * 32; i += 256) {
            int n = i >> 5, k = i & 31;
            W3T[i] = f2bf(w_e2[k * kF + n]);
        }
        for (int i = t; i < 16 * 32; i += 256) {
            int n = i >> 5, k = i & 31;
            float a = 0.f;
            if (n < kH) for (int o = 0; o < kF; o++) a += w_e2[k * kF + o] * w_att[o * kH + n];
            W24T[i] = f2bf(a);
        }
        if (t < kH) {
            float a = b_att[t];
            for (int o = 0; o < kF; o++) a += b_e2[o] * w_att[o * kH + t];
            b24[t] = a;
        }
    }
    if (blockIdx.x == 1) {
        int t = threadIdx.x;
        for (int i = t; i < 32 * kC; i += 256) {   // Wn1hT[o][k] = w_n1[(kF+k)*kF+o]
            int o = i / kC, k = i - o * kC;
            Wn1hT[i] = f2bf(w_n1[(kF + k) * kF + o]);
        }
    }
}

// ---------------------------------------------------------------------------
// K1: exclusive scan, barrier-light
// ---------------------------------------------------------------------------
__global__ __launch_bounds__(1024) void scan_kernel(
    const int* __restrict__ counts, int* __restrict__ offsets, int n)
{
    __shared__ int buf[1024];
    int t = threadIdx.x;
    int chunk = (n + 1023) >> 10;
    int lo = t * chunk;
    int s = 0;
    for (int i = 0; i < chunk; i++) {
        int g = lo + i;
        if (g < n) s += counts[g];
    }
    buf[t] = s;
    __syncthreads();
    for (int off = 1; off < 1024; off <<= 1) {
        int v = (t >= off) ? buf[t - off] : 0;
        __syncthreads();
        buf[t] += v;
        __syncthreads();
    }
    int run = buf[t] - s;
    for (int i = 0; i < chunk; i++) {
        int g = lo + i;
        if (g < n) { offsets[g] = run; run += counts[g]; }
    }
    if (t == 1023) offsets[n] = buf[1023];
}

// ---------------------------------------------------------------------------
// K2: MFMA edge kernel; does the CSR scatter itself (cursor atomic -> pos),
// writes nid + he(bf16)/logit/dir at CSR position.
// ---------------------------------------------------------------------------
__global__ __launch_bounds__(256) void edge_kernel(
    const float* __restrict__ h, const float* __restrict__ x,
    const int* __restrict__ pl, const int* __restrict__ offs,
    int* __restrict__ cursor, int* __restrict__ nid, int E_,
    const float* __restrict__ b_in, const float* __restrict__ b_e1,
    const float* __restrict__ b_e2,
    const u16* __restrict__ W1T, const u16* __restrict__ W2T,
    const u16* __restrict__ W3T, const u16* __restrict__ W24T,
    const float* __restrict__ b24,
    u16* __restrict__ he_g, float* __restrict__ logit_g,
    float* __restrict__ dir_g)
{
    __shared__ __align__(16) u16 s_A[kEM][kAStr];
    __shared__ __align__(16) u16 s_t1[kEM][kBStr];
    __shared__ float s_d[kEM];
    __shared__ int   s_r[kEM];

    int t = threadIdx.x;
    int T0 = blockIdx.x * kEM;
    int w = t >> 6, lane = t & 63, quad = lane >> 4, l15 = lane & 15;

    {
        int e = t >> 1, half = t & 1;
        int ge = T0 + e;
        bool val = ge < E_;
        int i = 0, j = 0;
        if (val) { i = pl[ge]; j = pl[E_ + ge]; }
        const float4* pi = (const float4*)(h + (size_t)i * kF) + half * 4;
        const float4* pj = (const float4*)(h + (size_t)j * kF) + half * 4;
#pragma unroll
        for (int q = 0; q < 4; q++) {
            float4 a = val ? pi[q] : make_float4(0.f, 0.f, 0.f, 0.f);
            float4 b = val ? pj[q] : make_float4(0.f, 0.f, 0.f, 0.f);
            unsigned* di = (unsigned*)&s_A[e][half * 16 + 4 * q];
            di[0] = pk2(a.x, a.y); di[1] = pk2(a.z, a.w);
            unsigned* dj = (unsigned*)&s_A[e][kF + half * 16 + 4 * q];
            dj[0] = pk2(b.x, b.y); dj[1] = pk2(b.z, b.w);
        }
        if (half == 0) {
            float d = 0.f;
            int r = 0;
            if (val) {
                int p = atomicAdd(&cursor[i], 1);
                r = offs[i] + p;
                nid[r] = i;
                float r0 = x[j * 3 + 0] - x[i * 3 + 0];
                float r1 = x[j * 3 + 1] - x[i * 3 + 1];
                float r2 = x[j * 3 + 2] - x[i * 3 + 2];
                d = sqrtf(r0 * r0 + r1 * r1 + r2 * r2);
                float inv = 1.0f / (d + kEps);
                dir_g[(size_t)r * 3 + 0] = r0 * inv;
                dir_g[(size_t)r * 3 + 1] = r1 * inv;
                dir_g[(size_t)r * 3 + 2] = r2 * inv;
            }
            s_r[e] = r;
            s_d[e] = d;
            s_A[e][114] = f2bf(d);
            s_A[e][115] = 0;
            unsigned* z = (unsigned*)&s_A[e][116];
#pragma unroll
            for (int q = 0; q < 6; q++) z[q] = 0u;
        }
    }
    __syncthreads();

    const float invw = 49.0f / kCut;

    {   // GEMM1: h_cat @ w_in -> rbf -> filt
        bf16x8 a1[2][2];
#pragma unroll
        for (int rt = 0; rt < 2; rt++)
#pragma unroll
            for (int kt = 0; kt < 2; kt++)
                a1[rt][kt] = *(const bf16x8*)&s_A[32 * w + 16 * rt + l15][kt * 32 + quad * 8];
#pragma unroll
        for (int ct = 0; ct < 4; ct++) {
            int c = ct * 16 + l15;
            bf16x8 b0 = *(const bf16x8*)(W1T + (size_t)c * 64 + quad * 8);
            bf16x8 b1 = *(const bf16x8*)(W1T + (size_t)c * 64 + 32 + quad * 8);
            float bin = (c < kRBF) ? b_in[c] : 0.f;
#pragma unroll
            for (int rt = 0; rt < 2; rt++) {
                f32x4 acc = {0.f, 0.f, 0.f, 0.f};
                acc = __builtin_amdgcn_mfma_f32_16x16x32_bf16(a1[rt][0], b0, acc, 0, 0, 0);
                acc = __builtin_amdgcn_mfma_f32_16x16x32_bf16(a1[rt][1], b1, acc, 0, 0, 0);
                if (c < kRBF) {
#pragma unroll
                    for (int r = 0; r < 4; r++) {
                        int row = 32 * w + 16 * rt + quad * 4 + r;
                        float arg = s_d[row] * invw - (float)c;
                        float filt = __expf(-0.5f * arg * arg) * (acc[r] + bin);
                        s_A[row][64 + c] = f2bf(filt);
                    }
                }
            }
        }
    }

    {   // GEMM2: edge_in @ w_e1 -> silu -> t1
        bf16x8 a2[2][4];
#pragma unroll
        for (int rt = 0; rt < 2; rt++)
#pragma unroll
            for (int kt = 0; kt < 4; kt++)
                a2[rt][kt] = *(const bf16x8*)&s_A[32 * w + 16 * rt + l15][kt * 32 + quad * 8];
#pragma unroll
        for (int ct = 0; ct < 2; ct++) {
            int c = ct * 16 + l15;
            bf16x8 bb[4];
#pragma unroll
            for (int kt = 0; kt < 4; kt++)
                bb[kt] = *(const bf16x8*)(W2T + (size_t)c * 128 + kt * 32 + quad * 8);
            float be = b_e1[c];
#pragma unroll
            for (int rt = 0; rt < 2; rt++) {
                f32x4 acc = {0.f, 0.f, 0.f, 0.f};
#pragma unroll
                for (int kt = 0; kt < 4; kt++)
                    acc = __builtin_amdgcn_mfma_f32_16x16x32_bf16(a2[rt][kt], bb[kt], acc, 0, 0, 0);
#pragma unroll
                for (int r = 0; r < 4; r++) {
                    int row = 32 * w + 16 * rt + quad * 4 + r;
                    s_t1[row][c] = f2bf(silu_f(acc[r] + be));
                }
            }
        }
    }

    {   // GEMM3 (he, bf16 out) + GEMM4 (logits)
        bf16x8 a3[2];
#pragma unroll
        for (int rt = 0; rt < 2; rt++)
            a3[rt] = *(const bf16x8*)&s_t1[32 * w + 16 * rt + l15][quad * 8];

#pragma unroll
        for (int ct = 0; ct < 2; ct++) {
            int c = ct * 16 + l15;
            bf16x8 b3 = *(const bf16x8*)(W3T + (size_t)c * 32 + quad * 8);
            float be = b_e2[c];
#pragma unroll
            for (int rt = 0; rt < 2; rt++) {
                f32x4 acc = {0.f, 0.f, 0.f, 0.f};
                acc = __builtin_amdgcn_mfma_f32_16x16x32_bf16(a3[rt], b3, acc, 0, 0, 0);
#pragma unroll
                for (int r = 0; r < 4; r++) {
                    int row = 32 * w + 16 * rt + quad * 4 + r;
                    int ge = T0 + row;
                    if (ge < E_) he_g[(size_t)s_r[row] * kF + c] = f2bf(acc[r] + be);
                }
            }
        }
        {
            bf16x8 b4 = *(const bf16x8*)(W24T + (size_t)l15 * 32 + quad * 8);
            float bb = (l15 < kH) ? b24[l15] : 0.f;
#pragma unroll
            for (int rt = 0; rt < 2; rt++) {
                f32x4 acc = {0.f, 0.f, 0.f, 0.f};
                acc = __builtin_amdgcn_mfma_f32_16x16x32_bf16(a3[rt], b4, acc, 0, 0, 0);
                if (l15 < kH) {
#pragma unroll
                    for (int r = 0; r < 4; r++) {
                        int row = 32 * w + 16 * rt + quad * 4 + r;
                        int ge = T0 + row;
                        if (ge < E_) {
                            float a = acc[r] + bb;
                            a = (a >= 0.f) ? a : 2.f * (__expf(0.5f * a) - 1.f);
                            float dd = s_d[row];
                            float cut = (dd < kCut)
                                ? 0.5f * (__cosf(0.62831853071795864f * dd) + 1.f) : 0.f;
                            logit_g[(size_t)s_r[row] * kH + l15] = a * cut;
                        }
                    }
                }
            }
        }
    }
}

// ---------------------------------------------------------------------------
// K3: per-node softmax stats (32-lane group per node, 8 nodes/block) +
// second L2-hot pass writing normalized att as bf16.
// ---------------------------------------------------------------------------
__global__ __launch_bounds__(256) void stats_kernel(
    const float* __restrict__ logit_g, const int* __restrict__ offsets,
    u16* __restrict__ att_g, int N_)
{
    int grp  = threadIdx.x >> 5;
    int lane = threadIdx.x & 31;
    int node = blockIdx.x * 8 + grp;
    if (node >= N_) return;
    int base = offsets[node];
    int deg  = offsets[node + 1] - base;

    float m[kH], ss[kH];
#pragma unroll
    for (int hh = 0; hh < kH; hh++) { m[hh] = -1e30f; ss[hh] = 0.f; }
    for (int e = lane; e < deg; e += 32) {
        const float* lp = logit_g + (size_t)(base + e) * kH;
#pragma unroll
        for (int hh = 0; hh < kH; hh++) {
            float vv = lp[hh];
            if (vv > m[hh]) { ss[hh] *= __expf(m[hh] - vv); m[hh] = vv; }
            ss[hh] += __expf(vv - m[hh]);
        }
    }
#pragma unroll
    for (int hh = 0; hh < kH; hh++) {
        float mm = m[hh], s2 = ss[hh];
#pragma unroll
        for (int off = 16; off >= 1; off >>= 1) {
            float mo = __shfl_xor(mm, off);
            float so = __shfl_xor(s2, off);
            float mn = fmaxf(mm, mo);
            s2 = s2 * __expf(mm - mn) + so * __expf(mo - mn);
            mm = mn;
        }
        m[hh] = mm;
        ss[hh] = (s2 > 0.f) ? 1.f / s2 : 0.f;
    }
    // second pass (L2-hot): att = exp(logit - m) * invs, bf16
    for (int e = lane; e < deg; e += 32) {
        const float* lp = logit_g + (size_t)(base + e) * kH;
        u16* ap = att_g + (size_t)(base + e) * kH;
#pragma unroll
        for (int hh = 0; hh < kH; hh++)
            ap[hh] = f2bf(__expf(lp[hh] - m[hh]) * ss[hh]);
    }
}

// ---------------------------------------------------------------------------
// K4: MFMA xmix. T = tanh(sem@wx) AND U = sem@Wn1h. att precomputed (bf16);
// he register-prefetched (16 elems/thread) ahead of staging. Depth-2 B
// prefetch; minimal barriers; merged comb+U walk; boundary runs -> bpart.
// ---------------------------------------------------------------------------
__global__ __launch_bounds__(256) void xmix_kernel(
    const u16* __restrict__ he_g, const u16* __restrict__ att_g,
    const float* __restrict__ dir_g, const int* __restrict__ nid,
    const u16* __restrict__ wxT, const u16* __restrict__ Wn1hT, int E_,
    float* __restrict__ nodeacc, float* __restrict__ bpart, int* __restrict__ bid)
{
    __shared__ __align__(16) u16 s_buf[kM][kStr];   // sem, then T
    __shared__ __align__(8)  u16 s_U[kM][kUSt];     // U (bf16)
    __shared__ float s_att[kM][kH];
    __shared__ __align__(16) float s_dir4[kM][4];
    __shared__ int   s_node[kM];
    __shared__ int   s_prev, s_next;

    int t = threadIdx.x;
    int T0 = blockIdx.x * kM;
    int cp = min(kM, E_ - T0);

    if (t < kM) s_node[t] = (T0 + t < E_) ? nid[T0 + t] : -1;
    if (t == 0) {
        s_prev = (T0 > 0) ? nid[T0 - 1] : -2;
        s_next = (T0 + cp < E_) ? nid[T0 + cp] : -2;
    }

    int w    = t >> 6;
    int lane = t & 63;
    int quad = lane >> 4;
    int l15  = lane & 15;

    // ---- he register prefetch: 16 elems/thread (128x32 = 4096 = 16*256) ----
    u16 hv16[16];
#pragma unroll
    for (int p = 0; p < 16; p++) {
        int idx = t + 256 * p;
        int e = idx >> 5, f = idx & 31;
        hv16[p] = (T0 + e < E_) ? he_g[(size_t)(T0 + e) * kF + f] : (u16)0;
    }

    // att copy-convert (bf16 -> f32 LDS) + dir staging
    for (int idx = t; idx < kM * kH; idx += 256) {
        int e = idx / kH;
        s_att[e][idx - e * kH] = (T0 + e < E_) ? bf2f(att_g[(size_t)T0 * kH + idx]) : 0.f;
    }
    for (int idx = t; idx < cp * 3; idx += 256) {
        int e = idx / 3, xx = idx - e * 3;
        s_dir4[e][xx] = dir_g[(size_t)(T0 + e) * 3 + xx];
    }
    __syncthreads();

    // ---- per-wave window params ----
    int ws = 32 * w;
    int we = min(ws + 32, cp);
    bool winvalid = (ws < cp);
    bool contL = false, contR = false;
    if (winvalid) {
        int nfirst = s_node[ws], nlast = s_node[we - 1];
        contL = (w == 0) ? (s_prev == nfirst) : (s_node[ws - 1] == nfirst);
        contR = (we == cp) ? (s_next == nlast) : (s_node[we] == nlast);
    }
    if (lane == 0) {
        int b0 = -1, b1 = -1;
        if (winvalid) {
            int nfirst = s_node[ws], nlast = s_node[we - 1];
            b0 = contL ? nfirst : -1;
            if (contR && !(nfirst == nlast && contL)) b1 = nlast;
        }
        bid[8 * blockIdx.x + 2 * w + 0] = b0;
        bid[8 * blockIdx.x + 2 * w + 1] = b1;
    }
    bool active_w = winvalid && (lane < 56);
    int c0 = 4 * lane;

    // sem build (bf16, hw pack) from prefetched he
#pragma unroll
    for (int p = 0; p < 16; p++) {
        int idx = t + 256 * p;
        int e = idx >> 5, f = idx & 31;
        float hv = bf2f(hv16[p]);
        float sv[7];
#pragma unroll
        for (int hh = 0; hh < kH; hh++) sv[hh] = hv * s_att[e][hh];
        u16* dst = &s_buf[e][f * 7];
        if ((f & 1) == 0) {
            *(unsigned*)(dst)     = pk2(sv[0], sv[1]);
            *(unsigned*)(dst + 2) = pk2(sv[2], sv[3]);
            *(unsigned*)(dst + 4) = pk2(sv[4], sv[5]);
            dst[6] = f2bf(sv[6]);
        } else {
            dst[0] = f2bf(sv[0]);
            *(unsigned*)(dst + 1) = pk2(sv[1], sv[2]);
            *(unsigned*)(dst + 3) = pk2(sv[3], sv[4]);
            *(unsigned*)(dst + 5) = pk2(sv[5], sv[6]);
        }
    }
    __syncthreads();
    // After this barrier all s_buf/s_U traffic is wave-private (rows 32w..32w+32).

    // MFMA fragments: wave w owns rows [32w, 32w+32)
    bf16x8 afr[2][7];
#pragma unroll
    for (int rt = 0; rt < 2; rt++)
#pragma unroll
        for (int kt = 0; kt < 7; kt++)
            afr[rt][kt] = *(const bf16x8*)&s_buf[32 * w + 16 * rt + l15][kt * 32 + quad * 8];

    // triple-buffered B prefetch (depth 2)
    bf16x8 bb[3][7];
#pragma unroll
    for (int kt = 0; kt < 7; kt++)
        bb[0][kt] = *(const bf16x8*)(wxT + (size_t)l15 * kC + kt * 32 + quad * 8);
#pragma unroll
    for (int kt = 0; kt < 7; kt++)
        bb[1][kt] = *(const bf16x8*)(wxT + (size_t)(16 + l15) * kC + kt * 32 + quad * 8);

#pragma unroll
    for (int ct = 0; ct < 14; ct++) {
        const int cur = ct % 3;
        const int nxt = (ct + 2) % 3;
        if (ct < 12) {
            const u16* bp = wxT + (size_t)((ct + 2) * 16 + l15) * kC + quad * 8;
#pragma unroll
            for (int kt = 0; kt < 7; kt++) bb[nxt][kt] = *(const bf16x8*)(bp + kt * 32);
        }
        f32x4 acc0 = {0.f, 0.f, 0.f, 0.f};
        f32x4 acc1 = {0.f, 0.f, 0.f, 0.f};
#pragma unroll
        for (int kt = 0; kt < 7; kt++) {
            acc0 = __builtin_amdgcn_mfma_f32_16x16x32_bf16(afr[0][kt], bb[cur][kt], acc0, 0, 0, 0);
            acc1 = __builtin_amdgcn_mfma_f32_16x16x32_bf16(afr[1][kt], bb[cur][kt], acc1, 0, 0, 0);
        }
        int colg = ct * 16 + l15;
#pragma unroll
        for (int s = 0; s < 2; s++) {
            f32x4 ac = s ? acc1 : acc0;
            int rbase = 32 * w + 16 * s + quad * 4;
            unsigned p01 = pk2(tanh_f(ac[0]), tanh_f(ac[1]));
            unsigned p23 = pk2(tanh_f(ac[2]), tanh_f(ac[3]));
            s_buf[rbase + 0][colg] = (u16)p01;
            s_buf[rbase + 1][colg] = (u16)(p01 >> 16);
            s_buf[rbase + 2][colg] = (u16)p23;
            s_buf[rbase + 3][colg] = (u16)(p23 >> 16);
        }
    }

    // U = sem @ Wn1h  (2 col-tiles, no tanh) -> s_U (wave-private rows)
#pragma unroll
    for (int ut = 0; ut < 2; ut++) {
        bf16x8 ub[7];
        const u16* bp = Wn1hT + (size_t)(ut * 16 + l15) * kC + quad * 8;
#pragma unroll
        for (int kt = 0; kt < 7; kt++) ub[kt] = *(const bf16x8*)(bp + kt * 32);
        f32x4 acc0 = {0.f, 0.f, 0.f, 0.f};
        f32x4 acc1 = {0.f, 0.f, 0.f, 0.f};
#pragma unroll
        for (int kt = 0; kt < 7; kt++) {
            acc0 = __builtin_amdgcn_mfma_f32_16x16x32_bf16(afr[0][kt], ub[kt], acc0, 0, 0, 0);
            acc1 = __builtin_amdgcn_mfma_f32_16x16x32_bf16(afr[1][kt], ub[kt], acc1, 0, 0, 0);
        }
        int ucol = ut * 16 + l15;
#pragma unroll
        for (int s = 0; s < 2; s++) {
            f32x4 ac = s ? acc1 : acc0;
            int rbase = 32 * w + 16 * s + quad * 4;
#pragma unroll
            for (int r = 0; r < 4; r++) s_U[rbase + r][ucol] = f2bf(ac[r]);
        }
    }
    // No barrier needed: walk below reads only this wave's rows.

    // merged comb + U walk (windowed; b64 T reads, b64 U reads on lanes 0-7)
    if (active_w) {
        bool uact = (lane < 8);
        float a0[4] = {0.f, 0.f, 0.f, 0.f};
        float a1[4] = {0.f, 0.f, 0.f, 0.f};
        float a2[4] = {0.f, 0.f, 0.f, 0.f};
        float uu[4] = {0.f, 0.f, 0.f, 0.f};
        int rs = ws;
        for (int e = ws; e < we; e++) {
            if (s_node[e] != s_node[rs]) {
                bool comp = (rs > ws) || !contL;
                float* p = comp ? (nodeacc + (size_t)s_node[rs] * 896)
                                : (bpart + (size_t)(8 * blockIdx.x + 2 * w) * 896);
                *(float4*)&p[c0]       = make_float4(a0[0], a0[1], a0[2], a0[3]);
                *(float4*)&p[224 + c0] = make_float4(a1[0], a1[1], a1[2], a1[3]);
                *(float4*)&p[448 + c0] = make_float4(a2[0], a2[1], a2[2], a2[3]);
                if (uact) *(float4*)&p[672 + c0] = make_float4(uu[0], uu[1], uu[2], uu[3]);
#pragma unroll
                for (int q = 0; q < 4; q++) { a0[q] = 0.f; a1[q] = 0.f; a2[q] = 0.f; uu[q] = 0.f; }
                rs = e;
            }
            float4 dd = *(const float4*)&s_dir4[e][0];
            uint2 pv = *(const uint2*)&s_buf[e][c0];
            float Tv[4];
            Tv[0] = bf2f((u16)pv.x); Tv[1] = bf2f((u16)(pv.x >> 16));
            Tv[2] = bf2f((u16)pv.y); Tv[3] = bf2f((u16)(pv.y >> 16));
#pragma unroll
            for (int q = 0; q < 4; q++) {
                a0[q] += Tv[q] * dd.x;
                a1[q] += Tv[q] * dd.y;
                a2[q] += Tv[q] * dd.z;
            }
            if (uact) {
                uint2 uv = *(const uint2*)&s_U[e][c0];
                uu[0] += bf2f((u16)uv.x); uu[1] += bf2f((u16)(uv.x >> 16));
                uu[2] += bf2f((u16)uv.y); uu[3] += bf2f((u16)(uv.y >> 16));
            }
        }
        bool t0 = (rs == ws);
        bool comp = ((!t0) || !contL) && !contR;
        float* p;
        if (comp) p = nodeacc + (size_t)s_node[rs] * 896;
        else {
            int slot = (t0 && contL) ? 0 : 1;
            p = bpart + (size_t)(8 * blockIdx.x + 2 * w + slot) * 896;
        }
        *(float4*)&p[c0]       = make_float4(a0[0], a0[1], a0[2], a0[3]);
        *(float4*)&p[224 + c0] = make_float4(a1[0], a1[1], a1[2], a1[3]);
        *(float4*)&p[448 + c0] = make_float4(a2[0], a2[1], a2[2], a2[3]);
        if (uact) *(float4*)&p[672 + c0] = make_float4(uu[0], uu[1], uu[2], uu[3]);
    }
}

// ---------------------------------------------------------------------------
// K5: node epilogue. 4 nodes/block; gather nodeacc/bpart; MLPs with
// weight-value reuse; n1 uses folded U (32-wide).
// ---------------------------------------------------------------------------
__global__ __launch_bounds__(256) void node_kernel(
    const float* __restrict__ h, const float* __restrict__ x, const float* __restrict__ v,
    const float* __restrict__ nodeacc, const float* __restrict__ bpart,
    const int* __restrict__ bid, const int* __restrict__ offs,
    const float* __restrict__ w_n1, const float* __restrict__ b_n1,
    const float* __restrict__ w_n2, const float* __restrict__ b_n2,
    const float* __restrict__ w_pn1, const float* __restrict__ b_pn1,
    const float* __restrict__ w_pn2, const float* __restrict__ b_pn2,
    const float* __restrict__ w_v1, const float* __restrict__ b_v1,
    const float* __restrict__ w_v2, const float* __restrict__ w_vmix,
    float* __restrict__ out_h, float* __restrict__ out_x, float* __restrict__ out_v,
    int N_)
{
    __shared__ float s_cm[4][3][kC];
    __shared__ float s_cnsq[4][kC];
    __shared__ float s_ni[4][64];           // [h | spat]
    __shared__ float s_usum[4][kF];
    __shared__ float s_part[8][4][kF];
    __shared__ float s_hn[4][kF], s_sp1[4][kF], s_spat[4][kF], s_n1v[4][kF], s_g1[4][kF];
    __shared__ float s_pdv[4][3][8];
    __shared__ float s_gate[4], s_dv[4][3];

    int t = threadIdx.x;
    int n0 = blockIdx.x * 4;

    if (t < kC) {
        for (int nd = 0; nd < 4; nd++) {
            int node = n0 + nd;
            if (node >= N_) break;
            int base = offs[node], end = offs[node + 1];
            int deg = end - base;
            float a0 = 0.f, a1 = 0.f, a2 = 0.f, hh = 0.f;
            if (deg > 0) {
                int wlo = base >> 5, whi = (end - 1) >> 5;
                if (wlo == whi) {
                    const float* p = nodeacc + (size_t)node * 896;
                    a0 = p[t]; a1 = p[224 + t]; a2 = p[448 + t];
                    if (t < kF) hh = p[672 + t];
                } else {
                    for (int W = wlo; W <= whi; W++) {
#pragma unroll
                        for (int s = 0; s < 2; s++) {
                            if (bid[2 * W + s] == node) {
                                const float* p = bpart + (size_t)(2 * W + s) * 896;
                                a0 += p[t]; a1 += p[224 + t]; a2 += p[448 + t];
                                if (t < kF) hh += p[672 + t];
                            }
                        }
                    }
                }
            }
            float invc = 1.f / fmaxf((float)deg, 1.f);
            float m0 = a0 * invc, m1 = a1 * invc, m2 = a2 * invc;
            s_cm[nd][0][t] = m0; s_cm[nd][1][t] = m1; s_cm[nd][2][t] = m2;
            s_cnsq[nd][t] = m0 * m0 + m1 * m1 + m2 * m2;
            if (t < kF) s_usum[nd][t] = hh;
        }
    } else {
        int ln = t - 224;   // 0..31
        for (int nd = 0; nd < 4; nd++) {
            int node = n0 + nd;
            float hv = (node < N_) ? h[(size_t)node * kF + ln] : 0.f;
            s_hn[nd][ln] = hv;
            s_ni[nd][ln] = hv;
        }
    }
    __syncthreads();

    int o = t & 31, g = t >> 5;
    {   // pn1 partials, 4 nodes per weight load
        float acc[4] = {0.f, 0.f, 0.f, 0.f};
        int cb = g * 28;
        for (int i = 0; i < 28; i++) {
            float wv = w_pn1[(cb + i) * kF + o];
#pragma unroll
            for (int nd = 0; nd < 4; nd++) acc[nd] += s_cnsq[nd][cb + i] * wv;
        }
#pragma unroll
        for (int nd = 0; nd < 4; nd++) s_part[g][nd][o] = acc[nd];
    }
    __syncthreads();
    if (t < 128) {
        int nd = t >> 5;
        float a = b_pn1[o];
#pragma unroll
        for (int g2 = 0; g2 < 8; g2++) a += s_part[g2][nd][o];
        s_sp1[nd][o] = silu_f(a);
    } else {
        int nd = (t - 128) >> 5;
        float a = b_v1[o];
        for (int f = 0; f < kF; f++) a += s_hn[nd][f] * w_v1[f * kF + o];
        s_g1[nd][o] = silu_f(a);
    }
    __syncthreads();
    if (t < 128) {
        int nd = t >> 5;
        float a = b_pn2[o];
        for (int o2 = 0; o2 < kF; o2++) a += s_sp1[nd][o2] * w_pn2[o2 * kF + o];
        s_spat[nd][o] = silu_f(a);
    } else if (t < 132) {
        int nd = t - 128;
        float a = 0.f;
        for (int o2 = 0; o2 < kF; o2++) a += s_g1[nd][o2] * w_v2[o2];
        s_gate[nd] = 2.f / (1.f + __expf(-a));
    } else if (t >= 160) {   // 96 threads: dv partials
        int q = t - 160; int nd = q / 24; int r = q - nd * 24;
        int xx = r >> 3, ln = r & 7;
        float a = 0.f;
        for (int c = ln; c < kC; c += 8) a += w_vmix[c] * s_cm[nd][xx][c];
        s_pdv[nd][xx][ln] = a;
    }
    __syncthreads();
    if (t < 128) {
        int nd = t >> 5;
        s_ni[nd][kF + o] = s_spat[nd][o];
    } else if (t < 140) {
        int q = t - 128; int nd = q / 3; int xx = q - nd * 3;
        float a = 0.f;
#pragma unroll
        for (int ln = 0; ln < 8; ln++) a += s_pdv[nd][xx][ln];
        s_dv[nd][xx] = a;
    }
    __syncthreads();
    {   // n1 partials: 8 groups x 8 rows over [h | spat]
        float acc[4] = {0.f, 0.f, 0.f, 0.f};
        int rb = g * 8;
        for (int i = 0; i < 8; i++) {
            int r = rb + i;
            int wr = (r < kF) ? r : (r + kC);
            float wv = w_n1[wr * kF + o];
#pragma unroll
            for (int nd = 0; nd < 4; nd++) acc[nd] += s_ni[nd][r] * wv;
        }
#pragma unroll
        for (int nd = 0; nd < 4; nd++) s_part[g][nd][o] = acc[nd];
    }
    __syncthreads();
    if (t < 128) {
        int nd = t >> 5;
        float a = b_n1[o] + s_usum[nd][o];
#pragma unroll
        for (int g2 = 0; g2 < 8; g2++) a += s_part[g2][nd][o];
        s_n1v[nd][o] = silu_f(a);
    }
    __syncthreads();
    if (t < 128) {
        int nd = t >> 5; int node = n0 + nd;
        if (node < N_) {
            float a = b_n2[o];
            for (int o2 = 0; o2 < kF; o2++) a += s_n1v[nd][o2] * w_n2[o2 * kF + o];
            out_h[(size_t)node * kF + o] = s_hn[nd][o] + silu_f(a);
        }
    } else if (t < 140) {
        int q = t - 128; int nd = q / 3; int xx = q - nd * 3;
        int node = n0 + nd;
        if (node < N_) {
            float vv = v[(size_t)node * 3 + xx];
            float vu = s_gate[nd] * vv + s_dv[nd][xx];
            out_v[(size_t)node * 3 + xx] = vu;
            out_x[(size_t)node * 3 + xx] = x[(size_t)node * 3 + xx] + vu;
        }
    }
}

// ---------------------------------------------------------------------------
extern "C" void kernel_launch(void* const* d_in, const int* in_sizes, int n_in,
                              void* d_out, int out_size, void* d_ws, size_t ws_size,
                              hipStream_t stream)
{
    const float* h      = (const float*)d_in[0];
    const float* x      = (const float*)d_in[1];
    const float* v      = (const float*)d_in[2];
    const int*   pl     = (const int*)d_in[3];
    const float* w_in   = (const float*)d_in[4];
    const float* b_in   = (const float*)d_in[5];
    const float* w_e1   = (const float*)d_in[6];
    const float* b_e1   = (const float*)d_in[7];
    const float* w_e2   = (const float*)d_in[8];
    const float* b_e2   = (const float*)d_in[9];
    const float* w_att  = (const float*)d_in[10];
    const float* b_att  = (const float*)d_in[11];
    const float* w_n1   = (const float*)d_in[12];
    const float* b_n1   = (const float*)d_in[13];
    const float* w_n2   = (const float*)d_in[14];
    const float* b_n2   = (const float*)d_in[15];
    const float* w_pn1  = (const float*)d_in[16];
    const float* b_pn1  = (const float*)d_in[17];
    const float* w_pn2  = (const float*)d_in[18];
    const float* b_pn2  = (const float*)d_in[19];
    const float* w_v1   = (const float*)d_in[20];
    const float* b_v1   = (const float*)d_in[21];
    const float* w_v2   = (const float*)d_in[22];
    const float* w_xmix = (const float*)d_in[23];
    const float* w_vmix = (const float*)d_in[24];

    const int E_ = in_sizes[3] / 2;
    const int N_ = in_sizes[0] / kF;
    const int nblk = (E_ + kM - 1) / kM;

    // Workspace (~105 MB; 16B-aligned segments first)
    char* w = (char*)d_ws;
    u16*   wxT     = (u16*)w;   w += (size_t)kC * kC * 2;
    u16*   W1T     = (u16*)w;   w += (size_t)64 * 64 * 2;
    u16*   W2T     = (u16*)w;   w += (size_t)32 * 128 * 2;
    u16*   W3T     = (u16*)w;   w += (size_t)32 * 32 * 2;
    u16*   W24T    = (u16*)w;   w += (size_t)16 * 32 * 2;
    u16*   Wn1hT   = (u16*)w;   w += (size_t)32 * kC * 2;
    float* b24     = (float*)w; w += 8 * 4;
    u16*   he_g    = (u16*)w;   w += (size_t)E_ * kF * 2;
    float* logit_g = (float*)w; w += (size_t)E_ * kH * 4;
    u16*   att_g   = (u16*)w;   w += (size_t)E_ * kH * 2;
    float* dir_g   = (float*)w; w += (size_t)E_ * 3 * 4;
    float* nodeacc = (float*)w; w += (size_t)N_ * 896 * 4;       // [N][4][224] (slot3: U)
    float* bpart   = (float*)w; w += (size_t)8 * nblk * 896 * 4; // 4 win x 2 slots / blk
    int*   bid     = (int*)w;   w += (size_t)8 * nblk * 4;
    int* counts    = (int*)w;   w += (size_t)N_ * 4;
    int* offs      = (int*)w;   w += (size_t)(N_ + 1) * 4;
    int* cursor    = (int*)w;   w += (size_t)N_ * 4;
    int* nid       = (int*)w;   w += (size_t)E_ * 4;

    float* out_h = (float*)d_out;
    float* out_x = out_h + (size_t)N_ * kF;
    float* out_v = out_x + (size_t)N_ * 3;

    hipMemsetAsync(counts, 0, (size_t)N_ * 4, stream);
    hipMemsetAsync(cursor, 0, (size_t)N_ * 4, stream);

    init_kernel<<<dim3((kC * kC + 255) / 256), dim3(256), 0, stream>>>(
        w_xmix, w_in, w_e1, w_e2, w_att, b_e2, b_att, w_n1, pl,
        wxT, W1T, W2T, W3T, W24T, Wn1hT, b24, counts, E_);

    scan_kernel<<<dim3(1), dim3(1024), 0, stream>>>(counts, offs, N_);

    edge_kernel<<<dim3((E_ + kEM - 1) / kEM), dim3(256), 0, stream>>>(
        h, x, pl, offs, cursor, nid, E_, b_in, b_e1, b_e2,
        W1T, W2T, W3T, W24T, b24, he_g, logit_g, dir_g);

    stats_kernel<<<dim3((N_ + 7) / 8), dim3(256), 0, stream>>>(
        logit_g, offs, att_g, N_);

    xmix_kernel<<<dim3(nblk), dim3(256), 0, stream>>>(
        he_g, att_g, dir_g, nid, wxT, Wn1hT, E_,
        nodeacc, bpart, bid);

    node_kernel<<<dim3((N_ + 3) / 4), dim3(256), 0, stream>>>(
        h, x, v, nodeacc, bpart, bid, offs,
        w_n1, b_n1, w_n2, b_n2, w_pn1, b_pn1, w_pn2, b_pn2,
        w_v1, b_v1, w_v2, w_vmix, out_h, out_x, out_v, N_);
}

// Round 19
// 312.885 us; speedup vs baseline: 1.1850x; 1.0202x over previous
//
#include <hip/hip_runtime.h>
#include <hip/hip_bf16.h>
#include <math.h>

typedef unsigned short u16;
typedef __attribute__((ext_vector_type(8))) short bf16x8;
typedef __attribute__((ext_vector_type(4))) float f32x4;

// Problem constants (match reference)
constexpr int kF    = 32;    // nr_atom_basis
constexpr int kH    = 7;     // heads
constexpr int kC    = 224;   // F*H
constexpr int kRBF  = 50;
constexpr int kM    = 128;   // edges per xmix tile
constexpr int kStr  = 232;   // xmix LDS row stride (bf16; 464B, 16B-aligned)
constexpr int kUSt  = 36;    // U LDS row stride (u16; 72B, 8B-aligned)
constexpr int kEM   = 128;   // edges per edge-MFMA block
constexpr int kAStr = 136;   // edge A-tile stride (bf16; 272B, 16B-aligned)
constexpr int kBStr = 40;    // t1 tile stride (bf16; 80B, 16B-aligned)
constexpr float kCut = 5.0f;
constexpr float kEps = 1e-8f;

__device__ __forceinline__ float silu_f(float a) { return a / (1.f + __expf(-a)); }
__device__ __forceinline__ float tanh_f(float x) {
    float e = __expf(2.f * x);
    return 1.f - 2.f / (e + 1.f);
}
__device__ __forceinline__ float bf2f(u16 u) {
    union { unsigned int i; float f; } v; v.i = ((unsigned int)u) << 16; return v.f;
}
__device__ __forceinline__ u16 f2bf(float f) {
    union { float f; unsigned int i; } v; v.f = f;
    unsigned int x = v.i;
    unsigned int round = ((x >> 16) & 1u) + 0x7fffu;
    return (u16)((x + round) >> 16);
}
__device__ __forceinline__ unsigned pk2(float a, float b) {
    union { __hip_bfloat162 h; unsigned u; } v;
    v.h = __float22bfloat162_rn(make_float2(a, b));
    return v.u;
}

// ---------------------------------------------------------------------------
// K0: build wxT + edge-MLP B-matrices + Wn1hT; histogram of idx_i
// ---------------------------------------------------------------------------
__global__ __launch_bounds__(256) void init_kernel(
    const float* __restrict__ wx, const float* __restrict__ w_in,
    const float* __restrict__ w_e1, const float* __restrict__ w_e2,
    const float* __restrict__ w_att, const float* __restrict__ b_e2,
    const float* __restrict__ b_att, const float* __restrict__ w_n1,
    const int* __restrict__ pl,
    u16* __restrict__ wxT, u16* __restrict__ W1T, u16* __restrict__ W2T,
    u16* __restrict__ W3T, u16* __restrict__ W24T, u16* __restrict__ Wn1hT,
    float* __restrict__ b24, int* __restrict__ counts, int E_)
{
    int idx = blockIdx.x * 256 + threadIdx.x;
    if (idx < kC * kC) {
        int c = idx / kC, k = idx - c * kC;      // wxT[c][k] = wx[k][c]
        wxT[idx] = f2bf(wx[k * kC + c]);
    }
    for (int e = idx; e < E_; e += gridDim.x * 256) atomicAdd(&counts[pl[e]], 1);

    if (blockIdx.x == 0) {
        int t = threadIdx.x;
        for (int i = t; i < 64 * 64; i += 256) {
            int n = i >> 6, k = i & 63;
            W1T[i] = f2bf((n < kRBF) ? w_in[k * kRBF + n] : 0.f);
        }
        for (int i = t; i < 32 * 128; i += 256) {
            int n = i >> 7, k = i & 127;
            W2T[i] = f2bf((k < 115) ? w_e1[k * kF + n] : 0.f);
        }
        for (int i = t; i < 32 * 32; i += 256) {
            int n = i >> 5, k = i & 31;
            W3T[i] = f2bf(w_e2[k * kF + n]);
        }
        for (int i = t; i < 16 * 32; i += 256) {
            int n = i >> 5, k = i & 31;
            float a = 0.f;
            if (n < kH) for (int o = 0; o < kF; o++) a += w_e2[k * kF + o] * w_att[o * kH + n];
            W24T[i] = f2bf(a);
        }
        if (t < kH) {
            float a = b_att[t];
            for (int o = 0; o < kF; o++) a += b_e2[o] * w_att[o * kH + t];
            b24[t] = a;
        }
    }
    if (blockIdx.x == 1) {
        int t = threadIdx.x;
        for (int i = t; i < 32 * kC; i += 256) {   // Wn1hT[o][k] = w_n1[(kF+k)*kF+o]
            int o = i / kC, k = i - o * kC;
            Wn1hT[i] = f2bf(w_n1[(kF + k) * kF + o]);
        }
    }
}

// ---------------------------------------------------------------------------
// K1: exclusive scan, barrier-light
// ---------------------------------------------------------------------------
__global__ __launch_bounds__(1024) void scan_kernel(
    const int* __restrict__ counts, int* __restrict__ offsets, int n)
{
    __shared__ int buf[1024];
    int t = threadIdx.x;
    int chunk = (n + 1023) >> 10;
    int lo = t * chunk;
    int s = 0;
    for (int i = 0; i < chunk; i++) {
        int g = lo + i;
        if (g < n) s += counts[g];
    }
    buf[t] = s;
    __syncthreads();
    for (int off = 1; off < 1024; off <<= 1) {
        int v = (t >= off) ? buf[t - off] : 0;
        __syncthreads();
        buf[t] += v;
        __syncthreads();
    }
    int run = buf[t] - s;
    for (int i = 0; i < chunk; i++) {
        int g = lo + i;
        if (g < n) { offsets[g] = run; run += counts[g]; }
    }
    if (t == 1023) offsets[n] = buf[1023];
}

// ---------------------------------------------------------------------------
// K2: MFMA edge kernel; does the CSR scatter itself (cursor atomic -> pos),
// writes nid + he(bf16)/logit/dir at CSR position.
// ---------------------------------------------------------------------------
__global__ __launch_bounds__(256) void edge_kernel(
    const float* __restrict__ h, const float* __restrict__ x,
    const int* __restrict__ pl, const int* __restrict__ offs,
    int* __restrict__ cursor, int* __restrict__ nid, int E_,
    const float* __restrict__ b_in, const float* __restrict__ b_e1,
    const float* __restrict__ b_e2,
    const u16* __restrict__ W1T, const u16* __restrict__ W2T,
    const u16* __restrict__ W3T, const u16* __restrict__ W24T,
    const float* __restrict__ b24,
    u16* __restrict__ he_g, float* __restrict__ logit_g,
    float* __restrict__ dir_g)
{
    __shared__ __align__(16) u16 s_A[kEM][kAStr];
    __shared__ __align__(16) u16 s_t1[kEM][kBStr];
    __shared__ float s_d[kEM];
    __shared__ int   s_r[kEM];

    int t = threadIdx.x;
    int T0 = blockIdx.x * kEM;
    int w = t >> 6, lane = t & 63, quad = lane >> 4, l15 = lane & 15;

    {
        int e = t >> 1, half = t & 1;
        int ge = T0 + e;
        bool val = ge < E_;
        int i = 0, j = 0;
        if (val) { i = pl[ge]; j = pl[E_ + ge]; }
        const float4* pi = (const float4*)(h + (size_t)i * kF) + half * 4;
        const float4* pj = (const float4*)(h + (size_t)j * kF) + half * 4;
#pragma unroll
        for (int q = 0; q < 4; q++) {
            float4 a = val ? pi[q] : make_float4(0.f, 0.f, 0.f, 0.f);
            float4 b = val ? pj[q] : make_float4(0.f, 0.f, 0.f, 0.f);
            unsigned* di = (unsigned*)&s_A[e][half * 16 + 4 * q];
            di[0] = pk2(a.x, a.y); di[1] = pk2(a.z, a.w);
            unsigned* dj = (unsigned*)&s_A[e][kF + half * 16 + 4 * q];
            dj[0] = pk2(b.x, b.y); dj[1] = pk2(b.z, b.w);
        }
        if (half == 0) {
            float d = 0.f;
            int r = 0;
            if (val) {
                int p = atomicAdd(&cursor[i], 1);
                r = offs[i] + p;
                nid[r] = i;
                float r0 = x[j * 3 + 0] - x[i * 3 + 0];
                float r1 = x[j * 3 + 1] - x[i * 3 + 1];
                float r2 = x[j * 3 + 2] - x[i * 3 + 2];
                d = sqrtf(r0 * r0 + r1 * r1 + r2 * r2);
                float inv = 1.0f / (d + kEps);
                dir_g[(size_t)r * 3 + 0] = r0 * inv;
                dir_g[(size_t)r * 3 + 1] = r1 * inv;
                dir_g[(size_t)r * 3 + 2] = r2 * inv;
            }
            s_r[e] = r;
            s_d[e] = d;
            s_A[e][114] = f2bf(d);
            s_A[e][115] = 0;
            unsigned* z = (unsigned*)&s_A[e][116];
#pragma unroll
            for (int q = 0; q < 6; q++) z[q] = 0u;
        }
    }
    __syncthreads();

    const float invw = 49.0f / kCut;

    {   // GEMM1: h_cat @ w_in -> rbf -> filt
        bf16x8 a1[2][2];
#pragma unroll
        for (int rt = 0; rt < 2; rt++)
#pragma unroll
            for (int kt = 0; kt < 2; kt++)
                a1[rt][kt] = *(const bf16x8*)&s_A[32 * w + 16 * rt + l15][kt * 32 + quad * 8];
#pragma unroll
        for (int ct = 0; ct < 4; ct++) {
            int c = ct * 16 + l15;
            bf16x8 b0 = *(const bf16x8*)(W1T + (size_t)c * 64 + quad * 8);
            bf16x8 b1 = *(const bf16x8*)(W1T + (size_t)c * 64 + 32 + quad * 8);
            float bin = (c < kRBF) ? b_in[c] : 0.f;
#pragma unroll
            for (int rt = 0; rt < 2; rt++) {
                f32x4 acc = {0.f, 0.f, 0.f, 0.f};
                acc = __builtin_amdgcn_mfma_f32_16x16x32_bf16(a1[rt][0], b0, acc, 0, 0, 0);
                acc = __builtin_amdgcn_mfma_f32_16x16x32_bf16(a1[rt][1], b1, acc, 0, 0, 0);
                if (c < kRBF) {
#pragma unroll
                    for (int r = 0; r < 4; r++) {
                        int row = 32 * w + 16 * rt + quad * 4 + r;
                        float arg = s_d[row] * invw - (float)c;
                        float filt = __expf(-0.5f * arg * arg) * (acc[r] + bin);
                        s_A[row][64 + c] = f2bf(filt);
                    }
                }
            }
        }
    }

    {   // GEMM2: edge_in @ w_e1 -> silu -> t1
        bf16x8 a2[2][4];
#pragma unroll
        for (int rt = 0; rt < 2; rt++)
#pragma unroll
            for (int kt = 0; kt < 4; kt++)
                a2[rt][kt] = *(const bf16x8*)&s_A[32 * w + 16 * rt + l15][kt * 32 + quad * 8];
#pragma unroll
        for (int ct = 0; ct < 2; ct++) {
            int c = ct * 16 + l15;
            bf16x8 bb[4];
#pragma unroll
            for (int kt = 0; kt < 4; kt++)
                bb[kt] = *(const bf16x8*)(W2T + (size_t)c * 128 + kt * 32 + quad * 8);
            float be = b_e1[c];
#pragma unroll
            for (int rt = 0; rt < 2; rt++) {
                f32x4 acc = {0.f, 0.f, 0.f, 0.f};
#pragma unroll
                for (int kt = 0; kt < 4; kt++)
                    acc = __builtin_amdgcn_mfma_f32_16x16x32_bf16(a2[rt][kt], bb[kt], acc, 0, 0, 0);
#pragma unroll
                for (int r = 0; r < 4; r++) {
                    int row = 32 * w + 16 * rt + quad * 4 + r;
                    s_t1[row][c] = f2bf(silu_f(acc[r] + be));
                }
            }
        }
    }

    {   // GEMM3 (he, bf16 out) + GEMM4 (logits)
        bf16x8 a3[2];
#pragma unroll
        for (int rt = 0; rt < 2; rt++)
            a3[rt] = *(const bf16x8*)&s_t1[32 * w + 16 * rt + l15][quad * 8];

#pragma unroll
        for (int ct = 0; ct < 2; ct++) {
            int c = ct * 16 + l15;
            bf16x8 b3 = *(const bf16x8*)(W3T + (size_t)c * 32 + quad * 8);
            float be = b_e2[c];
#pragma unroll
            for (int rt = 0; rt < 2; rt++) {
                f32x4 acc = {0.f, 0.f, 0.f, 0.f};
                acc = __builtin_amdgcn_mfma_f32_16x16x32_bf16(a3[rt], b3, acc, 0, 0, 0);
#pragma unroll
                for (int r = 0; r < 4; r++) {
                    int row = 32 * w + 16 * rt + quad * 4 + r;
                    int ge = T0 + row;
                    if (ge < E_) he_g[(size_t)s_r[row] * kF + c] = f2bf(acc[r] + be);
                }
            }
        }
        {
            bf16x8 b4 = *(const bf16x8*)(W24T + (size_t)l15 * 32 + quad * 8);
            float bb = (l15 < kH) ? b24[l15] : 0.f;
#pragma unroll
            for (int rt = 0; rt < 2; rt++) {
                f32x4 acc = {0.f, 0.f, 0.f, 0.f};
                acc = __builtin_amdgcn_mfma_f32_16x16x32_bf16(a3[rt], b4, acc, 0, 0, 0);
                if (l15 < kH) {
#pragma unroll
                    for (int r = 0; r < 4; r++) {
                        int row = 32 * w + 16 * rt + quad * 4 + r;
                        int ge = T0 + row;
                        if (ge < E_) {
                            float a = acc[r] + bb;
                            a = (a >= 0.f) ? a : 2.f * (__expf(0.5f * a) - 1.f);
                            float dd = s_d[row];
                            float cut = (dd < kCut)
                                ? 0.5f * (__cosf(0.62831853071795864f * dd) + 1.f) : 0.f;
                            logit_g[(size_t)s_r[row] * kH + l15] = a * cut;
                        }
                    }
                }
            }
        }
    }
}

// ---------------------------------------------------------------------------
// K3: per-node softmax (no-max form; logits bounded by construction, clamp
// guards overflow; softmax is shift-invariant so result matches reference).
// First 32-edge chunk's exps kept in registers and reused for the att write.
// ---------------------------------------------------------------------------
__global__ __launch_bounds__(256) void stats_kernel(
    const float* __restrict__ logit_g, const int* __restrict__ offsets,
    u16* __restrict__ att_g, int N_)
{
    int grp  = threadIdx.x >> 5;
    int lane = threadIdx.x & 31;
    int node = blockIdx.x * 8 + grp;
    if (node >= N_) return;
    int base = offsets[node];
    int deg  = offsets[node + 1] - base;
    if (deg <= 0) return;

    float ev[kH], ss[kH];
    bool fv = (lane < deg);
    if (fv) {
        const float* lp = logit_g + (size_t)(base + lane) * kH;
#pragma unroll
        for (int hh = 0; hh < kH; hh++) {
            ev[hh] = __expf(fminf(lp[hh], 30.f));
            ss[hh] = ev[hh];
        }
    } else {
#pragma unroll
        for (int hh = 0; hh < kH; hh++) { ev[hh] = 0.f; ss[hh] = 0.f; }
    }
    for (int e = lane + 32; e < deg; e += 32) {
        const float* lp = logit_g + (size_t)(base + e) * kH;
#pragma unroll
        for (int hh = 0; hh < kH; hh++) ss[hh] += __expf(fminf(lp[hh], 30.f));
    }
#pragma unroll
    for (int hh = 0; hh < kH; hh++) {
        float s2 = ss[hh];
#pragma unroll
        for (int off = 16; off >= 1; off >>= 1) s2 += __shfl_xor(s2, off);
        ss[hh] = (s2 > 0.f) ? 1.f / s2 : 0.f;
    }
    if (fv) {
        u16* ap = att_g + (size_t)(base + lane) * kH;
#pragma unroll
        for (int hh = 0; hh < kH; hh++) ap[hh] = f2bf(ev[hh] * ss[hh]);
    }
    for (int e = lane + 32; e < deg; e += 32) {
        const float* lp = logit_g + (size_t)(base + e) * kH;
        u16* ap = att_g + (size_t)(base + e) * kH;
#pragma unroll
        for (int hh = 0; hh < kH; hh++)
            ap[hh] = f2bf(__expf(fminf(lp[hh], 30.f)) * ss[hh]);
    }
}

// ---------------------------------------------------------------------------
// K4: MFMA xmix. T = tanh(sem@wx) AND U = sem@Wn1h. att precomputed (bf16);
// he register-prefetched (16 elems/thread). Depth-2 B prefetch; minimal
// barriers; merged comb+U walk; boundary runs -> bpart.
// ---------------------------------------------------------------------------
__global__ __launch_bounds__(256) void xmix_kernel(
    const u16* __restrict__ he_g, const u16* __restrict__ att_g,
    const float* __restrict__ dir_g, const int* __restrict__ nid,
    const u16* __restrict__ wxT, const u16* __restrict__ Wn1hT, int E_,
    float* __restrict__ nodeacc, float* __restrict__ bpart, int* __restrict__ bid)
{
    __shared__ __align__(16) u16 s_buf[kM][kStr];   // sem, then T
    __shared__ __align__(8)  u16 s_U[kM][kUSt];     // U (bf16)
    __shared__ float s_att[kM][kH];
    __shared__ __align__(16) float s_dir4[kM][4];
    __shared__ int   s_node[kM];
    __shared__ int   s_prev, s_next;

    int t = threadIdx.x;
    int T0 = blockIdx.x * kM;
    int cp = min(kM, E_ - T0);

    if (t < kM) s_node[t] = (T0 + t < E_) ? nid[T0 + t] : -1;
    if (t == 0) {
        s_prev = (T0 > 0) ? nid[T0 - 1] : -2;
        s_next = (T0 + cp < E_) ? nid[T0 + cp] : -2;
    }

    int w    = t >> 6;
    int lane = t & 63;
    int quad = lane >> 4;
    int l15  = lane & 15;

    // ---- he register prefetch: 16 elems/thread (128x32 = 4096 = 16*256) ----
    u16 hv16[16];
#pragma unroll
    for (int p = 0; p < 16; p++) {
        int idx = t + 256 * p;
        int e = idx >> 5, f = idx & 31;
        hv16[p] = (T0 + e < E_) ? he_g[(size_t)(T0 + e) * kF + f] : (u16)0;
    }

    // att copy-convert (bf16 -> f32 LDS) + dir staging
    for (int idx = t; idx < kM * kH; idx += 256) {
        int e = idx / kH;
        s_att[e][idx - e * kH] = (T0 + e < E_) ? bf2f(att_g[(size_t)T0 * kH + idx]) : 0.f;
    }
    for (int idx = t; idx < cp * 3; idx += 256) {
        int e = idx / 3, xx = idx - e * 3;
        s_dir4[e][xx] = dir_g[(size_t)(T0 + e) * 3 + xx];
    }
    __syncthreads();

    // ---- per-wave window params ----
    int ws = 32 * w;
    int we = min(ws + 32, cp);
    bool winvalid = (ws < cp);
    bool contL = false, contR = false;
    if (winvalid) {
        int nfirst = s_node[ws], nlast = s_node[we - 1];
        contL = (w == 0) ? (s_prev == nfirst) : (s_node[ws - 1] == nfirst);
        contR = (we == cp) ? (s_next == nlast) : (s_node[we] == nlast);
    }
    if (lane == 0) {
        int b0 = -1, b1 = -1;
        if (winvalid) {
            int nfirst = s_node[ws], nlast = s_node[we - 1];
            b0 = contL ? nfirst : -1;
            if (contR && !(nfirst == nlast && contL)) b1 = nlast;
        }
        bid[8 * blockIdx.x + 2 * w + 0] = b0;
        bid[8 * blockIdx.x + 2 * w + 1] = b1;
    }
    bool active_w = winvalid && (lane < 56);
    int c0 = 4 * lane;

    // sem build (bf16, hw pack) from prefetched he
#pragma unroll
    for (int p = 0; p < 16; p++) {
        int idx = t + 256 * p;
        int e = idx >> 5, f = idx & 31;
        float hv = bf2f(hv16[p]);
        float sv[7];
#pragma unroll
        for (int hh = 0; hh < kH; hh++) sv[hh] = hv * s_att[e][hh];
        u16* dst = &s_buf[e][f * 7];
        if ((f & 1) == 0) {
            *(unsigned*)(dst)     = pk2(sv[0], sv[1]);
            *(unsigned*)(dst + 2) = pk2(sv[2], sv[3]);
            *(unsigned*)(dst + 4) = pk2(sv[4], sv[5]);
            dst[6] = f2bf(sv[6]);
        } else {
            dst[0] = f2bf(sv[0]);
            *(unsigned*)(dst + 1) = pk2(sv[1], sv[2]);
            *(unsigned*)(dst + 3) = pk2(sv[3], sv[4]);
            *(unsigned*)(dst + 5) = pk2(sv[5], sv[6]);
        }
    }
    __syncthreads();
    // After this barrier all s_buf/s_U traffic is wave-private (rows 32w..32w+32).

    // MFMA fragments: wave w owns rows [32w, 32w+32)
    bf16x8 afr[2][7];
#pragma unroll
    for (int rt = 0; rt < 2; rt++)
#pragma unroll
        for (int kt = 0; kt < 7; kt++)
            afr[rt][kt] = *(const bf16x8*)&s_buf[32 * w + 16 * rt + l15][kt * 32 + quad * 8];

    // triple-buffered B prefetch (depth 2)
    bf16x8 bb[3][7];
#pragma unroll
    for (int kt = 0; kt < 7; kt++)
        bb[0][kt] = *(const bf16x8*)(wxT + (size_t)l15 * kC + kt * 32 + quad * 8);
#pragma unroll
    for (int kt = 0; kt < 7; kt++)
        bb[1][kt] = *(const bf16x8*)(wxT + (size_t)(16 + l15) * kC + kt * 32 + quad * 8);

#pragma unroll
    for (int ct = 0; ct < 14; ct++) {
        const int cur = ct % 3;
        const int nxt = (ct + 2) % 3;
        if (ct < 12) {
            const u16* bp = wxT + (size_t)((ct + 2) * 16 + l15) * kC + quad * 8;
#pragma unroll
            for (int kt = 0; kt < 7; kt++) bb[nxt][kt] = *(const bf16x8*)(bp + kt * 32);
        }
        f32x4 acc0 = {0.f, 0.f, 0.f, 0.f};
        f32x4 acc1 = {0.f, 0.f, 0.f, 0.f};
#pragma unroll
        for (int kt = 0; kt < 7; kt++) {
            acc0 = __builtin_amdgcn_mfma_f32_16x16x32_bf16(afr[0][kt], bb[cur][kt], acc0, 0, 0, 0);
            acc1 = __builtin_amdgcn_mfma_f32_16x16x32_bf16(afr[1][kt], bb[cur][kt], acc1, 0, 0, 0);
        }
        int colg = ct * 16 + l15;
#pragma unroll
        for (int s = 0; s < 2; s++) {
            f32x4 ac = s ? acc1 : acc0;
            int rbase = 32 * w + 16 * s + quad * 4;
            unsigned p01 = pk2(tanh_f(ac[0]), tanh_f(ac[1]));
            unsigned p23 = pk2(tanh_f(ac[2]), tanh_f(ac[3]));
            s_buf[rbase + 0][colg] = (u16)p01;
            s_buf[rbase + 1][colg] = (u16)(p01 >> 16);
            s_buf[rbase + 2][colg] = (u16)p23;
            s_buf[rbase + 3][colg] = (u16)(p23 >> 16);
        }
    }

    // U = sem @ Wn1h  (2 col-tiles, no tanh) -> s_U (wave-private rows)
#pragma unroll
    for (int ut = 0; ut < 2; ut++) {
        bf16x8 ub[7];
        const u16* bp = Wn1hT + (size_t)(ut * 16 + l15) * kC + quad * 8;
#pragma unroll
        for (int kt = 0; kt < 7; kt++) ub[kt] = *(const bf16x8*)(bp + kt * 32);
        f32x4 acc0 = {0.f, 0.f, 0.f, 0.f};
        f32x4 acc1 = {0.f, 0.f, 0.f, 0.f};
#pragma unroll
        for (int kt = 0; kt < 7; kt++) {
            acc0 = __builtin_amdgcn_mfma_f32_16x16x32_bf16(afr[0][kt], ub[kt], acc0, 0, 0, 0);
            acc1 = __builtin_amdgcn_mfma_f32_16x16x32_bf16(afr[1][kt], ub[kt], acc1, 0, 0, 0);
        }
        int ucol = ut * 16 + l15;
#pragma unroll
        for (int s = 0; s < 2; s++) {
            f32x4 ac = s ? acc1 : acc0;
            int rbase = 32 * w + 16 * s + quad * 4;
#pragma unroll
            for (int r = 0; r < 4; r++) s_U[rbase + r][ucol] = f2bf(ac[r]);
        }
    }
    // No barrier needed: walk below reads only this wave's rows.

    // merged comb + U walk (windowed; b64 T reads, b64 U reads on lanes 0-7)
    if (active_w) {
        bool uact = (lane < 8);
        float a0[4] = {0.f, 0.f, 0.f, 0.f};
        float a1[4] = {0.f, 0.f, 0.f, 0.f};
        float a2[4] = {0.f, 0.f, 0.f, 0.f};
        float uu[4] = {0.f, 0.f, 0.f, 0.f};
        int rs = ws;
        for (int e = ws; e < we; e++) {
            if (s_node[e] != s_node[rs]) {
                bool comp = (rs > ws) || !contL;
                float* p = comp ? (nodeacc + (size_t)s_node[rs] * 896)
                                : (bpart + (size_t)(8 * blockIdx.x + 2 * w) * 896);
                *(float4*)&p[c0]       = make_float4(a0[0], a0[1], a0[2], a0[3]);
                *(float4*)&p[224 + c0] = make_float4(a1[0], a1[1], a1[2], a1[3]);
                *(float4*)&p[448 + c0] = make_float4(a2[0], a2[1], a2[2], a2[3]);
                if (uact) *(float4*)&p[672 + c0] = make_float4(uu[0], uu[1], uu[2], uu[3]);
#pragma unroll
                for (int q = 0; q < 4; q++) { a0[q] = 0.f; a1[q] = 0.f; a2[q] = 0.f; uu[q] = 0.f; }
                rs = e;
            }
            float4 dd = *(const float4*)&s_dir4[e][0];
            uint2 pv = *(const uint2*)&s_buf[e][c0];
            float Tv[4];
            Tv[0] = bf2f((u16)pv.x); Tv[1] = bf2f((u16)(pv.x >> 16));
            Tv[2] = bf2f((u16)pv.y); Tv[3] = bf2f((u16)(pv.y >> 16));
#pragma unroll
            for (int q = 0; q < 4; q++) {
                a0[q] += Tv[q] * dd.x;
                a1[q] += Tv[q] * dd.y;
                a2[q] += Tv[q] * dd.z;
            }
            if (uact) {
                uint2 uv = *(const uint2*)&s_U[e][c0];
                uu[0] += bf2f((u16)uv.x); uu[1] += bf2f((u16)(uv.x >> 16));
                uu[2] += bf2f((u16)uv.y); uu[3] += bf2f((u16)(uv.y >> 16));
            }
        }
        bool t0 = (rs == ws);
        bool comp = ((!t0) || !contL) && !contR;
        float* p;
        if (comp) p = nodeacc + (size_t)s_node[rs] * 896;
        else {
            int slot = (t0 && contL) ? 0 : 1;
            p = bpart + (size_t)(8 * blockIdx.x + 2 * w + slot) * 896;
        }
        *(float4*)&p[c0]       = make_float4(a0[0], a0[1], a0[2], a0[3]);
        *(float4*)&p[224 + c0] = make_float4(a1[0], a1[1], a1[2], a1[3]);
        *(float4*)&p[448 + c0] = make_float4(a2[0], a2[1], a2[2], a2[3]);
        if (uact) *(float4*)&p[672 + c0] = make_float4(uu[0], uu[1], uu[2], uu[3]);
    }
}

// ---------------------------------------------------------------------------
// K5: node epilogue. 4 nodes/block; gather nodeacc/bpart; MLPs with
// weight-value reuse; n1 uses folded U (32-wide).
// ---------------------------------------------------------------------------
__global__ __launch_bounds__(256) void node_kernel(
    const float* __restrict__ h, const float* __restrict__ x, const float* __restrict__ v,
    const float* __restrict__ nodeacc, const float* __restrict__ bpart,
    const int* __restrict__ bid, const int* __restrict__ offs,
    const float* __restrict__ w_n1, const float* __restrict__ b_n1,
    const float* __restrict__ w_n2, const float* __restrict__ b_n2,
    const float* __restrict__ w_pn1, const float* __restrict__ b_pn1,
    const float* __restrict__ w_pn2, const float* __restrict__ b_pn2,
    const float* __restrict__ w_v1, const float* __restrict__ b_v1,
    const float* __restrict__ w_v2, const float* __restrict__ w_vmix,
    float* __restrict__ out_h, float* __restrict__ out_x, float* __restrict__ out_v,
    int N_)
{
    __shared__ float s_cm[4][3][kC];
    __shared__ float s_cnsq[4][kC];
    __shared__ float s_ni[4][64];           // [h | spat]
    __shared__ float s_usum[4][kF];
    __shared__ float s_part[8][4][kF];
    __shared__ float s_hn[4][kF], s_sp1[4][kF], s_spat[4][kF], s_n1v[4][kF], s_g1[4][kF];
    __shared__ float s_pdv[4][3][8];
    __shared__ float s_gate[4], s_dv[4][3];

    int t = threadIdx.x;
    int n0 = blockIdx.x * 4;

    if (t < kC) {
        for (int nd = 0; nd < 4; nd++) {
            int node = n0 + nd;
            if (node >= N_) break;
            int base = offs[node], end = offs[node + 1];
            int deg = end - base;
            float a0 = 0.f, a1 = 0.f, a2 = 0.f, hh = 0.f;
            if (deg > 0) {
                int wlo = base >> 5, whi = (end - 1) >> 5;
                if (wlo == whi) {
                    const float* p = nodeacc + (size_t)node * 896;
                    a0 = p[t]; a1 = p[224 + t]; a2 = p[448 + t];
                    if (t < kF) hh = p[672 + t];
                } else {
                    for (int W = wlo; W <= whi; W++) {
#pragma unroll
                        for (int s = 0; s < 2; s++) {
                            if (bid[2 * W + s] == node) {
                                const float* p = bpart + (size_t)(2 * W + s) * 896;
                                a0 += p[t]; a1 += p[224 + t]; a2 += p[448 + t];
                                if (t < kF) hh += p[672 + t];
                            }
                        }
                    }
                }
            }
            float invc = 1.f / fmaxf((float)deg, 1.f);
            float m0 = a0 * invc, m1 = a1 * invc, m2 = a2 * invc;
            s_cm[nd][0][t] = m0; s_cm[nd][1][t] = m1; s_cm[nd][2][t] = m2;
            s_cnsq[nd][t] = m0 * m0 + m1 * m1 + m2 * m2;
            if (t < kF) s_usum[nd][t] = hh;
        }
    } else {
        int ln = t - 224;   // 0..31
        for (int nd = 0; nd < 4; nd++) {
            int node = n0 + nd;
            float hv = (node < N_) ? h[(size_t)node * kF + ln] : 0.f;
            s_hn[nd][ln] = hv;
            s_ni[nd][ln] = hv;
        }
    }
    __syncthreads();

    int o = t & 31, g = t >> 5;
    {   // pn1 partials, 4 nodes per weight load
        float acc[4] = {0.f, 0.f, 0.f, 0.f};
        int cb = g * 28;
        for (int i = 0; i < 28; i++) {
            float wv = w_pn1[(cb + i) * kF + o];
#pragma unroll
            for (int nd = 0; nd < 4; nd++) acc[nd] += s_cnsq[nd][cb + i] * wv;
        }
#pragma unroll
        for (int nd = 0; nd < 4; nd++) s_part[g][nd][o] = acc[nd];
    }
    __syncthreads();
    if (t < 128) {
        int nd = t >> 5;
        float a = b_pn1[o];
#pragma unroll
        for (int g2 = 0; g2 < 8; g2++) a += s_part[g2][nd][o];
        s_sp1[nd][o] = silu_f(a);
    } else {
        int nd = (t - 128) >> 5;
        float a = b_v1[o];
        for (int f = 0; f < kF; f++) a += s_hn[nd][f] * w_v1[f * kF + o];
        s_g1[nd][o] = silu_f(a);
    }
    __syncthreads();
    if (t < 128) {
        int nd = t >> 5;
        float a = b_pn2[o];
        for (int o2 = 0; o2 < kF; o2++) a += s_sp1[nd][o2] * w_pn2[o2 * kF + o];
        s_spat[nd][o] = silu_f(a);
    } else if (t < 132) {
        int nd = t - 128;
        float a = 0.f;
        for (int o2 = 0; o2 < kF; o2++) a += s_g1[nd][o2] * w_v2[o2];
        s_gate[nd] = 2.f / (1.f + __expf(-a));
    } else if (t >= 160) {   // 96 threads: dv partials
        int q = t - 160; int nd = q / 24; int r = q - nd * 24;
        int xx = r >> 3, ln = r & 7;
        float a = 0.f;
        for (int c = ln; c < kC; c += 8) a += w_vmix[c] * s_cm[nd][xx][c];
        s_pdv[nd][xx][ln] = a;
    }
    __syncthreads();
    if (t < 128) {
        int nd = t >> 5;
        s_ni[nd][kF + o] = s_spat[nd][o];
    } else if (t < 140) {
        int q = t - 128; int nd = q / 3; int xx = q - nd * 3;
        float a = 0.f;
#pragma unroll
        for (int ln = 0; ln < 8; ln++) a += s_pdv[nd][xx][ln];
        s_dv[nd][xx] = a;
    }
    __syncthreads();
    {   // n1 partials: 8 groups x 8 rows over [h | spat]
        float acc[4] = {0.f, 0.f, 0.f, 0.f};
        int rb = g * 8;
        for (int i = 0; i < 8; i++) {
            int r = rb + i;
            int wr = (r < kF) ? r : (r + kC);
            float wv = w_n1[wr * kF + o];
#pragma unroll
            for (int nd = 0; nd < 4; nd++) acc[nd] += s_ni[nd][r] * wv;
        }
#pragma unroll
        for (int nd = 0; nd < 4; nd++) s_part[g][nd][o] = acc[nd];
    }
    __syncthreads();
    if (t < 128) {
        int nd = t >> 5;
        float a = b_n1[o] + s_usum[nd][o];
#pragma unroll
        for (int g2 = 0; g2 < 8; g2++) a += s_part[g2][nd][o];
        s_n1v[nd][o] = silu_f(a);
    }
    __syncthreads();
    if (t < 128) {
        int nd = t >> 5; int node = n0 + nd;
        if (node < N_) {
            float a = b_n2[o];
            for (int o2 = 0; o2 < kF; o2++) a += s_n1v[nd][o2] * w_n2[o2 * kF + o];
            out_h[(size_t)node * kF + o] = s_hn[nd][o] + silu_f(a);
        }
    } else if (t < 140) {
        int q = t - 128; int nd = q / 3; int xx = q - nd * 3;
        int node = n0 + nd;
        if (node < N_) {
            float vv = v[(size_t)node * 3 + xx];
            float vu = s_gate[nd] * vv + s_dv[nd][xx];
            out_v[(size_t)node * 3 + xx] = vu;
            out_x[(size_t)node * 3 + xx] = x[(size_t)node * 3 + xx] + vu;
        }
    }
}

// ---------------------------------------------------------------------------
extern "C" void kernel_launch(void* const* d_in, const int* in_sizes, int n_in,
                              void* d_out, int out_size, void* d_ws, size_t ws_size,
                              hipStream_t stream)
{
    const float* h      = (const float*)d_in[0];
    const float* x      = (const float*)d_in[1];
    const float* v      = (const float*)d_in[2];
    const int*   pl     = (const int*)d_in[3];
    const float* w_in   = (const float*)d_in[4];
    const float* b_in   = (const float*)d_in[5];
    const float* w_e1   = (const float*)d_in[6];
    const float* b_e1   = (const float*)d_in[7];
    const float* w_e2   = (const float*)d_in[8];
    const float* b_e2   = (const float*)d_in[9];
    const float* w_att  = (const float*)d_in[10];
    const float* b_att  = (const float*)d_in[11];
    const float* w_n1   = (const float*)d_in[12];
    const float* b_n1   = (const float*)d_in[13];
    const float* w_n2   = (const float*)d_in[14];
    const float* b_n2   = (const float*)d_in[15];
    const float* w_pn1  = (const float*)d_in[16];
    const float* b_pn1  = (const float*)d_in[17];
    const float* w_pn2  = (const float*)d_in[18];
    const float* b_pn2  = (const float*)d_in[19];
    const float* w_v1   = (const float*)d_in[20];
    const float* b_v1   = (const float*)d_in[21];
    const float* w_v2   = (const float*)d_in[22];
    const float* w_xmix = (const float*)d_in[23];
    const float* w_vmix = (const float*)d_in[24];

    const int E_ = in_sizes[3] / 2;
    const int N_ = in_sizes[0] / kF;
    const int nblk = (E_ + kM - 1) / kM;

    // Workspace (~105 MB; 16B-aligned segments first)
    char* w = (char*)d_ws;
    u16*   wxT     = (u16*)w;   w += (size_t)kC * kC * 2;
    u16*   W1T     = (u16*)w;   w += (size_t)64 * 64 * 2;
    u16*   W2T     = (u16*)w;   w += (size_t)32 * 128 * 2;
    u16*   W3T     = (u16*)w;   w += (size_t)32 * 32 * 2;
    u16*   W24T    = (u16*)w;   w += (size_t)16 * 32 * 2;
    u16*   Wn1hT   = (u16*)w;   w += (size_t)32 * kC * 2;
    float* b24     = (float*)w; w += 8 * 4;
    u16*   he_g    = (u16*)w;   w += (size_t)E_ * kF * 2;
    float* logit_g = (float*)w; w += (size_t)E_ * kH * 4;
    u16*   att_g   = (u16*)w;   w += (size_t)E_ * kH * 2;
    float* dir_g   = (float*)w; w += (size_t)E_ * 3 * 4;
    float* nodeacc = (float*)w; w += (size_t)N_ * 896 * 4;       // [N][4][224] (slot3: U)
    float* bpart   = (float*)w; w += (size_t)8 * nblk * 896 * 4; // 4 win x 2 slots / blk
    int*   bid     = (int*)w;   w += (size_t)8 * nblk * 4;
    int* counts    = (int*)w;   w += (size_t)N_ * 4;             // adjacent to cursor:
    int* cursor    = (int*)w;   w += (size_t)N_ * 4;             // one combined memset
    int* offs      = (int*)w;   w += (size_t)(N_ + 1) * 4;
    int* nid       = (int*)w;   w += (size_t)E_ * 4;

    float* out_h = (float*)d_out;
    float* out_x = out_h + (size_t)N_ * kF;
    float* out_v = out_x + (size_t)N_ * 3;

    hipMemsetAsync(counts, 0, (size_t)2 * N_ * 4, stream);   // counts + cursor

    init_kernel<<<dim3((kC * kC + 255) / 256), dim3(256), 0, stream>>>(
        w_xmix, w_in, w_e1, w_e2, w_att, b_e2, b_att, w_n1, pl,
        wxT, W1T, W2T, W3T, W24T, Wn1hT, b24, counts, E_);

    scan_kernel<<<dim3(1), dim3(1024), 0, stream>>>(counts, offs, N_);

    edge_kernel<<<dim3((E_ + kEM - 1) / kEM), dim3(256), 0, stream>>>(
        h, x, pl, offs, cursor, nid, E_, b_in, b_e1, b_e2,
        W1T, W2T, W3T, W24T, b24, he_g, logit_g, dir_g);

    stats_kernel<<<dim3((N_ + 7) / 8), dim3(256), 0, stream>>>(
        logit_g, offs, att_g, N_);

    xmix_kernel<<<dim3(nblk), dim3(256), 0, stream>>>(
        he_g, att_g, dir_g, nid, wxT, Wn1hT, E_,
        nodeacc, bpart, bid);

    node_kernel<<<dim3((N_ + 3) / 4), dim3(256), 0, stream>>>(
        h, x, v, nodeacc, bpart, bid, offs,
        w_n1, b_n1, w_n2, b_n2, w_pn1, b_pn1, w_pn2, b_pn2,
        w_v1, b_v1, w_v2, w_vmix, out_h, out_x, out_v, N_);
}